// Round 13
// baseline (397.905 us; speedup 1.0000x reference)
//
#include <hip/hip_runtime.h>
#include <math.h>

#define B_      4
#define L_      2048
#define IN_DIM  128
#define D_MODEL 256
#define OUT_DIM 128
#define D_STATE 16
#define D_INNER 768
#define NHEADS  256
#define HEADDIM 3
#define CONV_DIM 800
#define D_IN_PROJ 1824

#define SCAN_NC 32
#define SCAN_CL 64
#define LPAD    2051        // L_ + 3 padded rows

typedef short  short8 __attribute__((ext_vector_type(8)));
typedef float  f32x4  __attribute__((ext_vector_type(4)));

__device__ __forceinline__ unsigned short f2bf(float f) {
    unsigned int u = __float_as_uint(f);
    u = (u + 0x7fffu + ((u >> 16) & 1u)) >> 16;     // RN-to-even
    return (unsigned short)u;
}
__device__ __forceinline__ float bf2f(unsigned short h) {
    return __uint_as_float(((unsigned int)h) << 16);
}

// ---------------------------------------------------------------------------
// prep_early: blocks 0..5 zero xT pads; blocks 6..517 reindex+split conv_w
// ---------------------------------------------------------------------------
__global__ __launch_bounds__(256) void prep_early_kernel(
    unsigned short* __restrict__ xh, unsigned short* __restrict__ xl,
    const float* __restrict__ cw, unsigned short* __restrict__ cwh,
    unsigned short* __restrict__ cwl)
{
    if (blockIdx.x < 6) {
        int t = blockIdx.x * 256 + threadIdx.x;
        int n = B_ * 3 * IN_DIM;
        if (t < n) {
            int ch = t % IN_DIM, rb = t / IN_DIM;
            int b = rb / 3, ri = rb % 3;
            int row = (ri == 0) ? 0 : (ri == 1) ? (L_ + 1) : (L_ + 2);
            size_t off = ((size_t)b * LPAD + row) * IN_DIM + ch;
            xh[off] = 0; xl[off] = 0;
        }
    } else {
        int t = (blockIdx.x - 6) * 256 + threadIdx.x;   // 256*512
        if (t < D_MODEL * 512) {
            int o = t >> 9, kk = t & 511;
            int k = kk >> 7, i = kk & 127;
            float v = cw[((size_t)o * IN_DIM + i) * 4 + k];
            unsigned short h = f2bf(v);
            cwh[t] = h; cwl[t] = f2bf(v - bf2f(h));
        }
    }
}

// ---------------------------------------------------------------------------
// prep_late: blocks 0..511 reindex+split out_conv_w; blocks 512..523 zero tmpP
// ---------------------------------------------------------------------------
__global__ __launch_bounds__(256) void prep_late_kernel(
    const float* __restrict__ cow, unsigned short* __restrict__ cowh,
    unsigned short* __restrict__ cowl,
    unsigned short* __restrict__ th, unsigned short* __restrict__ tl)
{
    if (blockIdx.x < 512) {
        int t = blockIdx.x * 256 + threadIdx.x;          // 128*1024
        if (t < OUT_DIM * 1024) {
            int o = t >> 10, kk = t & 1023;
            int k = kk >> 8, c = kk & 255;
            float v = cow[((size_t)o * D_MODEL + c) * 4 + k];
            unsigned short h = f2bf(v);
            cowh[t] = h; cowl[t] = f2bf(v - bf2f(h));
        }
    } else {
        int t = (blockIdx.x - 512) * 256 + threadIdx.x;
        int n = B_ * 3 * D_MODEL;
        if (t < n) {
            int ch = t % D_MODEL, rb = t / D_MODEL;
            int b = rb / 3, ri = rb % 3;
            int row = (ri == 0) ? 0 : (ri == 1) ? (L_ + 1) : (L_ + 2);
            size_t off = ((size_t)b * LPAD + row) * D_MODEL + ch;
            th[off] = 0; tl[off] = 0;
        }
    }
}

// ---------------------------------------------------------------------------
// transpose x [b][i][L] fp32 -> padded split-bf16 xT [b][LPAD][128], row l+1
// ---------------------------------------------------------------------------
__global__ __launch_bounds__(256) void transpose_x_kernel(
    const float* __restrict__ x, unsigned short* __restrict__ xh,
    unsigned short* __restrict__ xl)
{
    __shared__ float tile[32][33];
    int b = blockIdx.z;
    int l0 = blockIdx.x * 32, i0 = blockIdx.y * 32;
    int tx = threadIdx.x & 31, ty = threadIdx.x >> 5;
    const float* xb = x + (size_t)b * IN_DIM * L_;
    #pragma unroll
    for (int r = 0; r < 4; ++r)
        tile[ty + r * 8][tx] = xb[(size_t)(i0 + ty + r * 8) * L_ + l0 + tx];
    __syncthreads();
    #pragma unroll
    for (int r = 0; r < 4; ++r) {
        int l = l0 + ty + r * 8;
        float v = tile[tx][ty + r * 8];
        size_t off = ((size_t)b * LPAD + l + 1) * IN_DIM + i0 + tx;
        unsigned short h = f2bf(v);
        xh[off] = h;
        xl[off] = f2bf(v - bf2f(h));
    }
}

// ---------------------------------------------------------------------------
// transpose + split: src[K][N] fp32 -> dh/dl [N][K] bf16  (weight prep)
// ---------------------------------------------------------------------------
__global__ __launch_bounds__(256) void tconv_kernel(
    const float* __restrict__ src, unsigned short* __restrict__ dh,
    unsigned short* __restrict__ dl, int K, int N)
{
    __shared__ float tile[32][33];
    int k0 = blockIdx.y * 32, n0 = blockIdx.x * 32;
    int tx = threadIdx.x & 31, ty = threadIdx.x >> 5;
    #pragma unroll
    for (int r = 0; r < 4; ++r)
        tile[ty + r * 8][tx] = src[(size_t)(k0 + ty + r * 8) * N + n0 + tx];
    __syncthreads();
    #pragma unroll
    for (int r = 0; r < 4; ++r) {
        int n = n0 + ty + r * 8;
        float v = tile[tx][ty + r * 8];
        unsigned short h = f2bf(v);
        dh[(size_t)n * K + k0 + tx] = h;
        dl[(size_t)n * K + k0 + tx] = f2bf(v - bf2f(h));
    }
}

// ---------------------------------------------------------------------------
// in_proj GEMM with fused dt-softplus epilogue. C[M,N] fp32 for cc<1568;
// cc in [1568,1824) -> dtb = softplus(v + dt_bias).
// ---------------------------------------------------------------------------
__global__ __launch_bounds__(256) void gemm_ip_kernel(
    const unsigned short* __restrict__ Ah, const unsigned short* __restrict__ Al,
    const unsigned short* __restrict__ Bh, const unsigned short* __restrict__ Bl,
    const float* __restrict__ dt_bias,
    float* __restrict__ C, float* __restrict__ dtb, int M, int N, int K)
{
    __shared__ __align__(16) unsigned short AsH[128][40];
    __shared__ __align__(16) unsigned short AsL[128][40];
    __shared__ __align__(16) unsigned short BsH[128][40];
    __shared__ __align__(16) unsigned short BsL[128][40];

    int m0 = blockIdx.y * 128, n0 = blockIdx.x * 128;
    int t = threadIdx.x;
    int wid = t >> 6, lane = t & 63;
    int wm = (wid >> 1) * 64, wn = (wid & 1) * 64;
    int fr = lane & 15, fq = lane >> 4;

    f32x4 z4 = {0.f, 0.f, 0.f, 0.f};
    f32x4 acc[4][4];
    #pragma unroll
    for (int i = 0; i < 4; ++i)
        #pragma unroll
        for (int j = 0; j < 4; ++j) acc[i][j] = z4;

    for (int k0 = 0; k0 < K; k0 += 32) {
        __syncthreads();
        #pragma unroll
        for (int p = 0; p < 2; ++p) {
            int idx = p * 256 + t;
            int row = idx >> 2, q = idx & 3;
            int koff = k0 + q * 8;
            *(float4*)&AsH[row][q * 8] =
                *(const float4*)(Ah + (size_t)(m0 + row) * K + koff);
            *(float4*)&AsL[row][q * 8] =
                *(const float4*)(Al + (size_t)(m0 + row) * K + koff);
            int n = n0 + row;
            float4 vbh = make_float4(0.f, 0.f, 0.f, 0.f), vbl = vbh;
            if (n < N) {
                vbh = *(const float4*)(Bh + (size_t)n * K + koff);
                vbl = *(const float4*)(Bl + (size_t)n * K + koff);
            }
            *(float4*)&BsH[row][q * 8] = vbh;
            *(float4*)&BsL[row][q * 8] = vbl;
        }
        __syncthreads();

        short8 ah[4], al[4], bh[4], bl[4];
        #pragma unroll
        for (int i = 0; i < 4; ++i) {
            ah[i] = *(const short8*)&AsH[wm + i * 16 + fr][fq * 8];
            al[i] = *(const short8*)&AsL[wm + i * 16 + fr][fq * 8];
            bh[i] = *(const short8*)&BsH[wn + i * 16 + fr][fq * 8];
            bl[i] = *(const short8*)&BsL[wn + i * 16 + fr][fq * 8];
        }
        #pragma unroll
        for (int i = 0; i < 4; ++i)
            #pragma unroll
            for (int j = 0; j < 4; ++j) {
                acc[i][j] = __builtin_amdgcn_mfma_f32_16x16x32_bf16(
                    ah[i], bh[j], acc[i][j], 0, 0, 0);
                acc[i][j] = __builtin_amdgcn_mfma_f32_16x16x32_bf16(
                    ah[i], bl[j], acc[i][j], 0, 0, 0);
                acc[i][j] = __builtin_amdgcn_mfma_f32_16x16x32_bf16(
                    al[i], bh[j], acc[i][j], 0, 0, 0);
            }
    }

    #pragma unroll
    for (int i = 0; i < 4; ++i) {
        int r0 = m0 + wm + i * 16 + fq * 4;
        #pragma unroll
        for (int j = 0; j < 4; ++j) {
            int cc = n0 + wn + j * 16 + fr;
            if (cc < N) {
                if (cc < D_INNER + CONV_DIM) {
                    #pragma unroll
                    for (int r = 0; r < 4; ++r)
                        C[(size_t)(r0 + r) * N + cc] = acc[i][j][r];
                } else {
                    int h = cc - (D_INNER + CONV_DIM);
                    float db = dt_bias[h];
                    #pragma unroll
                    for (int r = 0; r < 4; ++r) {
                        float v = acc[i][j][r] + db;
                        float sp = (v > 20.f) ? v : log1pf(expf(v));
                        dtb[(size_t)(r0 + r) * NHEADS + h] = sp;
                    }
                }
            }
        }
    }
}

// ---------------------------------------------------------------------------
// conv_in as GEMM: A = xT window, B = cw [256][512]. Epilogue: + conv_b,
// write split-bf16 u [8192][256].
// ---------------------------------------------------------------------------
__global__ __launch_bounds__(256) void gemm_ci_kernel(
    const unsigned short* __restrict__ Ah, const unsigned short* __restrict__ Al,
    const unsigned short* __restrict__ Bh, const unsigned short* __restrict__ Bl,
    const float* __restrict__ bias,
    unsigned short* __restrict__ Ch, unsigned short* __restrict__ Cl)
{
    const int K = 512;
    __shared__ __align__(16) unsigned short AsH[128][40];
    __shared__ __align__(16) unsigned short AsL[128][40];
    __shared__ __align__(16) unsigned short BsH[128][40];
    __shared__ __align__(16) unsigned short BsL[128][40];

    int m0 = blockIdx.y * 128, n0 = blockIdx.x * 128;
    int b = m0 >> 11;
    size_t abase = ((size_t)b * LPAD + (m0 & 2047)) * IN_DIM;
    int t = threadIdx.x;
    int wid = t >> 6, lane = t & 63;
    int wm = (wid >> 1) * 64, wn = (wid & 1) * 64;
    int fr = lane & 15, fq = lane >> 4;

    f32x4 z4 = {0.f, 0.f, 0.f, 0.f};
    f32x4 acc[4][4];
    #pragma unroll
    for (int i = 0; i < 4; ++i)
        #pragma unroll
        for (int j = 0; j < 4; ++j) acc[i][j] = z4;

    for (int k0 = 0; k0 < K; k0 += 32) {
        __syncthreads();
        #pragma unroll
        for (int p = 0; p < 2; ++p) {
            int idx = p * 256 + t;
            int row = idx >> 2, q = idx & 3;
            int koff = k0 + q * 8;
            *(float4*)&AsH[row][q * 8] =
                *(const float4*)(Ah + abase + (size_t)row * IN_DIM + koff);
            *(float4*)&AsL[row][q * 8] =
                *(const float4*)(Al + abase + (size_t)row * IN_DIM + koff);
            int n = n0 + row;
            *(float4*)&BsH[row][q * 8] = *(const float4*)(Bh + (size_t)n * K + koff);
            *(float4*)&BsL[row][q * 8] = *(const float4*)(Bl + (size_t)n * K + koff);
        }
        __syncthreads();

        short8 ah[4], al[4], bh[4], bl[4];
        #pragma unroll
        for (int i = 0; i < 4; ++i) {
            ah[i] = *(const short8*)&AsH[wm + i * 16 + fr][fq * 8];
            al[i] = *(const short8*)&AsL[wm + i * 16 + fr][fq * 8];
            bh[i] = *(const short8*)&BsH[wn + i * 16 + fr][fq * 8];
            bl[i] = *(const short8*)&BsL[wn + i * 16 + fr][fq * 8];
        }
        #pragma unroll
        for (int i = 0; i < 4; ++i)
            #pragma unroll
            for (int j = 0; j < 4; ++j) {
                acc[i][j] = __builtin_amdgcn_mfma_f32_16x16x32_bf16(
                    ah[i], bh[j], acc[i][j], 0, 0, 0);
                acc[i][j] = __builtin_amdgcn_mfma_f32_16x16x32_bf16(
                    ah[i], bl[j], acc[i][j], 0, 0, 0);
                acc[i][j] = __builtin_amdgcn_mfma_f32_16x16x32_bf16(
                    al[i], bh[j], acc[i][j], 0, 0, 0);
            }
    }

    #pragma unroll
    for (int i = 0; i < 4; ++i) {
        int r0 = m0 + wm + i * 16 + fq * 4;
        #pragma unroll
        for (int j = 0; j < 4; ++j) {
            int cc = n0 + wn + j * 16 + fr;
            float bc = bias[cc];
            #pragma unroll
            for (int r = 0; r < 4; ++r) {
                float v = acc[i][j][r] + bc;
                unsigned short h = f2bf(v);
                size_t off = (size_t)(r0 + r) * D_MODEL + cc;
                Ch[off] = h;
                Cl[off] = f2bf(v - bf2f(h));
            }
        }
    }
}

// ---------------------------------------------------------------------------
// gemm2 (mamba_out) with split-bf16 PADDED output
// ---------------------------------------------------------------------------
__global__ __launch_bounds__(256) void gemm_mo_kernel(
    const unsigned short* __restrict__ Ah, const unsigned short* __restrict__ Al,
    const unsigned short* __restrict__ Bh, const unsigned short* __restrict__ Bl,
    unsigned short* __restrict__ Ch, unsigned short* __restrict__ Cl)
{
    const int K = D_INNER, N = D_MODEL;
    __shared__ __align__(16) unsigned short AsH[128][40];
    __shared__ __align__(16) unsigned short AsL[128][40];
    __shared__ __align__(16) unsigned short BsH[128][40];
    __shared__ __align__(16) unsigned short BsL[128][40];

    int m0 = blockIdx.y * 128, n0 = blockIdx.x * 128;
    int t = threadIdx.x;
    int wid = t >> 6, lane = t & 63;
    int wm = (wid >> 1) * 64, wn = (wid & 1) * 64;
    int fr = lane & 15, fq = lane >> 4;

    f32x4 z4 = {0.f, 0.f, 0.f, 0.f};
    f32x4 acc[4][4];
    #pragma unroll
    for (int i = 0; i < 4; ++i)
        #pragma unroll
        for (int j = 0; j < 4; ++j) acc[i][j] = z4;

    for (int k0 = 0; k0 < K; k0 += 32) {
        __syncthreads();
        #pragma unroll
        for (int p = 0; p < 2; ++p) {
            int idx = p * 256 + t;
            int row = idx >> 2, q = idx & 3;
            int koff = k0 + q * 8;
            *(float4*)&AsH[row][q * 8] =
                *(const float4*)(Ah + (size_t)(m0 + row) * K + koff);
            *(float4*)&AsL[row][q * 8] =
                *(const float4*)(Al + (size_t)(m0 + row) * K + koff);
            int n = n0 + row;
            *(float4*)&BsH[row][q * 8] = *(const float4*)(Bh + (size_t)n * K + koff);
            *(float4*)&BsL[row][q * 8] = *(const float4*)(Bl + (size_t)n * K + koff);
        }
        __syncthreads();

        short8 ah[4], al[4], bh[4], bl[4];
        #pragma unroll
        for (int i = 0; i < 4; ++i) {
            ah[i] = *(const short8*)&AsH[wm + i * 16 + fr][fq * 8];
            al[i] = *(const short8*)&AsL[wm + i * 16 + fr][fq * 8];
            bh[i] = *(const short8*)&BsH[wn + i * 16 + fr][fq * 8];
            bl[i] = *(const short8*)&BsL[wn + i * 16 + fr][fq * 8];
        }
        #pragma unroll
        for (int i = 0; i < 4; ++i)
            #pragma unroll
            for (int j = 0; j < 4; ++j) {
                acc[i][j] = __builtin_amdgcn_mfma_f32_16x16x32_bf16(
                    ah[i], bh[j], acc[i][j], 0, 0, 0);
                acc[i][j] = __builtin_amdgcn_mfma_f32_16x16x32_bf16(
                    ah[i], bl[j], acc[i][j], 0, 0, 0);
                acc[i][j] = __builtin_amdgcn_mfma_f32_16x16x32_bf16(
                    al[i], bh[j], acc[i][j], 0, 0, 0);
            }
    }

    int b = m0 >> 11;
    #pragma unroll
    for (int i = 0; i < 4; ++i) {
        int r0 = m0 + wm + i * 16 + fq * 4;
        #pragma unroll
        for (int j = 0; j < 4; ++j) {
            int cc = n0 + wn + j * 16 + fr;
            #pragma unroll
            for (int r = 0; r < 4; ++r) {
                int l = (r0 + r) & 2047;
                float v = acc[i][j][r];
                unsigned short h = f2bf(v);
                size_t off = ((size_t)b * LPAD + l + 1) * D_MODEL + cc;
                Ch[off] = h;
                Cl[off] = f2bf(v - bf2f(h));
            }
        }
    }
}

// ---------------------------------------------------------------------------
// conv_out as full-K GEMM (64 blocks, regular stores)
// ---------------------------------------------------------------------------
__global__ __launch_bounds__(256) void gemm_co_kernel(
    const unsigned short* __restrict__ Ah, const unsigned short* __restrict__ Al,
    const unsigned short* __restrict__ Bh, const unsigned short* __restrict__ Bl,
    float* __restrict__ out)
{
    const int K = 1024;
    __shared__ __align__(16) unsigned short AsH[128][40];
    __shared__ __align__(16) unsigned short AsL[128][40];
    __shared__ __align__(16) unsigned short BsH[128][40];
    __shared__ __align__(16) unsigned short BsL[128][40];

    int m0 = blockIdx.y * 128;
    int b = m0 >> 11, l0t = m0 & 2047;
    size_t abase = ((size_t)b * LPAD + l0t) * D_MODEL;
    int t = threadIdx.x;
    int wid = t >> 6, lane = t & 63;
    int wm = (wid >> 1) * 64, wn = (wid & 1) * 64;
    int fr = lane & 15, fq = lane >> 4;

    f32x4 z4 = {0.f, 0.f, 0.f, 0.f};
    f32x4 acc[4][4];
    #pragma unroll
    for (int i = 0; i < 4; ++i)
        #pragma unroll
        for (int j = 0; j < 4; ++j) acc[i][j] = z4;

    for (int k0 = 0; k0 < K; k0 += 32) {
        __syncthreads();
        #pragma unroll
        for (int p = 0; p < 2; ++p) {
            int idx = p * 256 + t;
            int row = idx >> 2, q = idx & 3;
            int koff = k0 + q * 8;
            *(float4*)&AsH[row][q * 8] =
                *(const float4*)(Ah + abase + (size_t)row * D_MODEL + koff);
            *(float4*)&AsL[row][q * 8] =
                *(const float4*)(Al + abase + (size_t)row * D_MODEL + koff);
            *(float4*)&BsH[row][q * 8] = *(const float4*)(Bh + (size_t)row * K + koff);
            *(float4*)&BsL[row][q * 8] = *(const float4*)(Bl + (size_t)row * K + koff);
        }
        __syncthreads();

        short8 ah[4], al[4], bh[4], bl[4];
        #pragma unroll
        for (int i = 0; i < 4; ++i) {
            ah[i] = *(const short8*)&AsH[wm + i * 16 + fr][fq * 8];
            al[i] = *(const short8*)&AsL[wm + i * 16 + fr][fq * 8];
            bh[i] = *(const short8*)&BsH[wn + i * 16 + fr][fq * 8];
            bl[i] = *(const short8*)&BsL[wn + i * 16 + fr][fq * 8];
        }
        #pragma unroll
        for (int i = 0; i < 4; ++i)
            #pragma unroll
            for (int j = 0; j < 4; ++j) {
                acc[i][j] = __builtin_amdgcn_mfma_f32_16x16x32_bf16(
                    ah[i], bh[j], acc[i][j], 0, 0, 0);
                acc[i][j] = __builtin_amdgcn_mfma_f32_16x16x32_bf16(
                    ah[i], bl[j], acc[i][j], 0, 0, 0);
                acc[i][j] = __builtin_amdgcn_mfma_f32_16x16x32_bf16(
                    al[i], bh[j], acc[i][j], 0, 0, 0);
            }
    }

    #pragma unroll
    for (int i = 0; i < 4; ++i) {
        int lr = l0t + wm + i * 16 + fq * 4;
        #pragma unroll
        for (int j = 0; j < 4; ++j) {
            int cc = wn + j * 16 + fr;
            float* dst = out + ((size_t)(b * OUT_DIM + cc)) * L_ + lr;
            float4 ov = make_float4(acc[i][j][0], acc[i][j][1],
                                    acc[i][j][2], acc[i][j][3]);
            *(float4*)dst = ov;
        }
    }
}

// ---------------------------------------------------------------------------
// K4: causal depthwise conv + bias + SiLU. 8 l-values per thread.
// ---------------------------------------------------------------------------
__global__ __launch_bounds__(256) void dwconv_kernel(
    const float* __restrict__ zx, const float* __restrict__ w,
    const float* __restrict__ bias, float* __restrict__ xBCs)
{
    int idx = blockIdx.x * 256 + threadIdx.x;   // over B * L/8 * 800
    int c   = idx % CONV_DIM;
    int bl8 = idx / CONV_DIM;
    int b  = bl8 >> 8;
    int l0 = (bl8 & 255) * 8;
    float4 wv = *(const float4*)&w[c * 4];
    float bi = bias[c];
    const float* base = zx + ((size_t)(b * L_ + l0)) * D_IN_PROJ + D_INNER + c;
    float r[11];
    #pragma unroll
    for (int k = 0; k < 11; ++k) {
        int l = l0 - 3 + k;
        r[k] = (l >= 0) ? base[(ptrdiff_t)(k - 3) * D_IN_PROJ] : 0.f;
    }
    #pragma unroll
    for (int i = 0; i < 8; ++i) {
        float acc = bi;
        acc = fmaf(r[i + 0], wv.x, acc);
        acc = fmaf(r[i + 1], wv.y, acc);
        acc = fmaf(r[i + 2], wv.z, acc);
        acc = fmaf(r[i + 3], wv.w, acc);
        float s = acc / (1.f + expf(-acc));
        xBCs[((size_t)(b * L_ + l0 + i)) * CONV_DIM + c] = s;
    }
}

// ---------------------------------------------------------------------------
// K5g: G[i][j] = C_i . B_j  per (b,chunk)
// ---------------------------------------------------------------------------
__global__ __launch_bounds__(256) void gmat_kernel(
    const float* __restrict__ xBCs, float* __restrict__ G)
{
    __shared__ float Bs[64][16];
    __shared__ float Cs[64][16];
    int c = blockIdx.x & 31, b = blockIdx.x >> 5;
    int t = threadIdx.x;
    int row0 = b * L_ + c * SCAN_CL;
    {
        int j = t >> 2, q = t & 3;
        const float* r = xBCs + (size_t)(row0 + j) * CONV_DIM + D_INNER;
        *(float4*)&Bs[j][q * 4] = *(const float4*)(r + q * 4);
        *(float4*)&Cs[j][q * 4] = *(const float4*)(r + D_STATE + q * 4);
    }
    __syncthreads();
    int i = t >> 2, jq = t & 3;
    float4 c0 = *(const float4*)&Cs[i][0];
    float4 c1 = *(const float4*)&Cs[i][4];
    float4 c2 = *(const float4*)&Cs[i][8];
    float4 c3 = *(const float4*)&Cs[i][12];
    float dot[16];
    #pragma unroll
    for (int jj = 0; jj < 16; ++jj) {
        int j = jq * 16 + jj;
        float4 b0 = *(const float4*)&Bs[j][0];
        float4 b1 = *(const float4*)&Bs[j][4];
        float4 b2 = *(const float4*)&Bs[j][8];
        float4 b3 = *(const float4*)&Bs[j][12];
        float d = c0.x * b0.x + c0.y * b0.y + c0.z * b0.z + c0.w * b0.w;
        d = fmaf(c1.x, b1.x, d); d = fmaf(c1.y, b1.y, d);
        d = fmaf(c1.z, b1.z, d); d = fmaf(c1.w, b1.w, d);
        d = fmaf(c2.x, b2.x, d); d = fmaf(c2.y, b2.y, d);
        d = fmaf(c2.z, b2.z, d); d = fmaf(c2.w, b2.w, d);
        d = fmaf(c3.x, b3.x, d); d = fmaf(c3.y, b3.y, d);
        d = fmaf(c3.z, b3.z, d); d = fmaf(c3.w, b3.w, d);
        dot[jj] = d;
    }
    float* gout = G + ((size_t)blockIdx.x * 64 + i) * 64 + jq * 16;
    #pragma unroll
    for (int q = 0; q < 4; ++q)
        *(float4*)(gout + q * 4) = make_float4(dot[q*4], dot[q*4+1], dot[q*4+2], dot[q*4+3]);
}

// ---------------------------------------------------------------------------
// XCD-locality swizzle (8-head blocks): all 32 hg blocks of one (b,c) share
// bid%8 -> same XCD. bid = (bc>>3)<<8 | hg<<3 | (bc&7);  bc = b*32+c.
// ---------------------------------------------------------------------------
__device__ __forceinline__ void scan_decode(int bid, int& b, int& c, int& hg)
{
    int bcl = bid & 7;
    hg = (bid >> 3) & 31;
    int bc = ((bid >> 8) << 3) | bcl;
    c = bc & 31;
    b = bc >> 5;
}

// ---------------------------------------------------------------------------
// K5a: chunk-local state build. 512 threads = 8 waves; ONE head per wave.
// ---------------------------------------------------------------------------
__global__ __launch_bounds__(512) void scan_local2(
    const float* __restrict__ xBCs, const float* __restrict__ dtb,
    const float* __restrict__ A_log,
    float* __restrict__ Sloc, float* __restrict__ prodA)
{
    __shared__ float  BsT[16][68];          // [n][row], padded
    __shared__ float4 Pk[8][64];            // [head][row] {dtx0,dtx1,dtx2,dt}
    __shared__ float  UT[8][3][64];
    int b, c, hg;
    scan_decode(blockIdx.x, b, c, hg);
    int h0 = hg * 8;
    int t = threadIdx.x;
    int row0 = b * L_ + c * SCAN_CL;

    if (t < 256) {   // B tile (coalesced)
        int j = t >> 2, q = t & 3;
        const float* r = xBCs + (size_t)(row0 + j) * CONV_DIM;
        float4 bv = *(const float4*)(r + D_INNER + q * 4);
        BsT[q*4+0][j] = bv.x; BsT[q*4+1][j] = bv.y;
        BsT[q*4+2][j] = bv.z; BsT[q*4+3][j] = bv.w;
    }
    {   // Pk: 8 heads x 64 rows, one entry per thread (dense per row)
        int hh = t & 7, j = t >> 3;
        float dtv = dtb[(size_t)(row0 + j) * NHEADS + h0 + hh];
        const float* xr = xBCs + (size_t)(row0 + j) * CONV_DIM + (h0 + hh) * 3;
        Pk[hh][j] = make_float4(dtv * xr[0], dtv * xr[1], dtv * xr[2], dtv);
    }
    __syncthreads();

    int wv = t >> 6, lane = t & 63;
    int hh = wv;
    int h = h0 + hh;
    int p = lane >> 4, n = lane & 15;
    int pc = (p < 3) ? p : 2;

    float4 pk = Pk[hh][lane];
    float A = -__expf(A_log[h]);
    float cum = pk.w * A;
    #pragma unroll
    for (int off = 1; off < 64; off <<= 1) {
        float sv = __shfl_up(cum, off);
        if (lane >= off) cum += sv;
    }
    float cum63 = __shfl(cum, 63);
    float wf = __expf(cum63 - cum);
    UT[hh][0][lane] = wf * pk.x;
    UT[hh][1][lane] = wf * pk.y;
    UT[hh][2][lane] = wf * pk.z;
    float state = 0.f;
    #pragma unroll
    for (int q = 0; q < 16; ++q) {
        float4 Bv = *(const float4*)&BsT[n][q * 4];
        float4 Uv = *(const float4*)&UT[hh][pc][q * 4];
        state = fmaf(Uv.x, Bv.x, state);
        state = fmaf(Uv.y, Bv.y, state);
        state = fmaf(Uv.z, Bv.z, state);
        state = fmaf(Uv.w, Bv.w, state);
    }
    size_t bh = (size_t)(b * NHEADS + h);
    if (p < 3) Sloc[(bh * SCAN_NC + c) * 48 + p * 16 + n] = state;
    if (lane == 0) prodA[bh * SCAN_NC + c] = __expf(cum63);
}

// ---------------------------------------------------------------------------
// K5b: sequential prefix over chunks, in place on Sloc
// ---------------------------------------------------------------------------
__global__ __launch_bounds__(256) void scan_prefix_kernel(
    float* __restrict__ Sloc, const float* __restrict__ prodA)
{
    int wv   = blockIdx.x * 4 + (threadIdx.x >> 6);
    int lane = threadIdx.x & 63;
    int p = lane >> 4, n = lane & 15;
    bool act = (p < 3);
    int l48 = ((p < 3) ? p : 2) * 16 + n;
    size_t base = (size_t)wv * SCAN_NC;

    float cur = 0.f;
    for (int c = 0; c < SCAN_NC; ++c) {
        float s  = Sloc[(base + c) * 48 + l48];
        float pa = prodA[base + c];
        if (act) Sloc[(base + c) * 48 + l48] = cur;
        cur = fmaf(pa, cur, s);
    }
}

// ---------------------------------------------------------------------------
// K5c: chunk-matmul final scan. 512 threads = 8 waves; ONE head per wave.
// G staged once per block in LDS (coalesced), shared by all 8 waves.
// ---------------------------------------------------------------------------
__global__ __launch_bounds__(512) void scan_final2(
    const float* __restrict__ xBCs, const float* __restrict__ dtb,
    const float* __restrict__ A_log, const float* __restrict__ Dp,
    const float* __restrict__ Sinit, const float* __restrict__ G,
    float* __restrict__ y)
{
    __shared__ float4 Pk[8][64];            // {dtx0,dtx1,dtx2, dt -> cum}
    __shared__ float4 XW[8][64];
    __shared__ float  Sin[8][48];
    __shared__ float  CsT[16][66];          // [n][row]
    __shared__ float  ysr[64][25];          // [row][24 ch] padded (stride 25)
    __shared__ float  Gs[64][65];           // G tile, odd stride
    int b, c, hg;
    scan_decode(blockIdx.x, b, c, hg);
    int h0 = hg * 8;
    int t = threadIdx.x;
    int row0 = b * L_ + c * SCAN_CL;

    if (t < 256) {   // C tile (coalesced)
        int j = t >> 2, q = t & 3;
        const float* r = xBCs + (size_t)(row0 + j) * CONV_DIM + D_INNER + D_STATE;
        float4 cv = *(const float4*)(r + q * 4);
        CsT[q*4+0][j] = cv.x; CsT[q*4+1][j] = cv.y;
        CsT[q*4+2][j] = cv.z; CsT[q*4+3][j] = cv.w;
    }
    {   // Pk staging: one entry per thread
        int hh = t & 7, j = t >> 3;
        float dtv = dtb[(size_t)(row0 + j) * NHEADS + h0 + hh];
        const float* xr = xBCs + (size_t)(row0 + j) * CONV_DIM + (h0 + hh) * 3;
        Pk[hh][j] = make_float4(dtv * xr[0], dtv * xr[1], dtv * xr[2], dtv);
    }
    if (t < 384) {   // Sin staging: 8 heads x 48
        int hh = t / 48, k = t % 48;
        Sin[hh][k] = Sinit[((size_t)(b * NHEADS + h0 + hh) * SCAN_NC + c) * 48 + k];
    }
    {   // G staging: 4096 floats, coalesced float4 global reads
        const float* Gsrc = G + (size_t)(b * SCAN_NC + c) * 4096;
        #pragma unroll
        for (int e = 0; e < 2; ++e) {
            int idx = e * 512 + t;              // float4 index 0..1023
            int row = idx >> 4, cq = (idx & 15) * 4;
            float4 gv = *(const float4*)(Gsrc + (size_t)idx * 4);
            Gs[row][cq + 0] = gv.x;
            Gs[row][cq + 1] = gv.y;
            Gs[row][cq + 2] = gv.z;
            Gs[row][cq + 3] = gv.w;
        }
    }
    __syncthreads();

    int wv = t >> 6, lane = t & 63;
    int hh = wv;
    int h = h0 + hh;
    int I = lane >> 4;

    float4 pk = Pk[hh][lane];
    float A = -__expf(A_log[h]);
    float cum = pk.w * A;
    #pragma unroll
    for (int off = 1; off < 64; off <<= 1) {
        float sv = __shfl_up(cum, off);
        if (lane >= off) cum += sv;
    }
    float e0 = __shfl(cum, 15);
    float e1 = __shfl(cum, 31);
    float e2 = __shfl(cum, 47);
    float e3 = __shfl(cum, 63);
    int ia = (I << 4) - 1;
    float AIr = __shfl(cum, ia < 0 ? 0 : ia);
    float AI = (I == 0) ? 0.f : AIr;
    float ri = __expf(cum - AI);
    float Eo = (I == 0) ? e0 : (I == 1) ? e1 : (I == 2) ? e2 : e3;
    float wj = __expf(Eo - cum);
    XW[hh][lane] = make_float4(wj * pk.x, wj * pk.y, wj * pk.z, 0.f);
    Pk[hh][lane].w = cum;                   // publish cum_j (wave-local)
    float S0 = (I > 0) ? __expf(AI - e0) : 0.f;
    float S1 = (I > 1) ? __expf(AI - e1) : 0.f;
    float S2 = (I > 2) ? __expf(AI - e2) : 0.f;
    float ecum = __expf(cum);

    float acc0 = 0.f, acc1 = 0.f, acc2 = 0.f;
    #pragma unroll
    for (int J = 0; J < 3; ++J) {
        float SJ = (J == 0) ? S0 : (J == 1) ? S1 : S2;
        float t0 = 0.f, t1 = 0.f, t2 = 0.f;
        #pragma unroll
        for (int kk = 0; kk < 16; ++kk) {
            float gk = Gs[lane][J * 16 + kk];
            float4 u = XW[hh][J * 16 + kk];
            t0 = fmaf(gk, u.x, t0);
            t1 = fmaf(gk, u.y, t1);
            t2 = fmaf(gk, u.z, t2);
        }
        acc0 = fmaf(SJ, t0, acc0);
        acc1 = fmaf(SJ, t1, acc1);
        acc2 = fmaf(SJ, t2, acc2);
    }

    float d0 = 0.f, d1 = 0.f, d2 = 0.f;
    #pragma unroll
    for (int kk = 0; kk < 16; ++kk) {
        int j = (I << 4) + kk;
        float gk = Gs[lane][j];
        float4 pd = Pk[hh][j];
        float e = __expf(cum - pd.w);
        float m = (j <= lane) ? e : 0.f;
        float mg = m * gk;
        d0 = fmaf(mg, pd.x, d0);
        d1 = fmaf(mg, pd.y, d1);
        d2 = fmaf(mg, pd.z, d2);
    }

    float s0 = 0.f, s1 = 0.f, s2 = 0.f;
    #pragma unroll
    for (int nq = 0; nq < 16; ++nq) {
        float Cv = CsT[nq][lane];
        s0 = fmaf(Cv, Sin[hh][nq],      s0);
        s1 = fmaf(Cv, Sin[hh][16 + nq], s1);
        s2 = fmaf(Cv, Sin[hh][32 + nq], s2);
    }

    float rdt = 1.0f / pk.w;
    float Dh = Dp[h];
    float* yr = &ysr[lane][hh * 3];
    yr[0] = fmaf(ri, acc0, d0) + fmaf(ecum, s0, Dh * (pk.x * rdt));
    yr[1] = fmaf(ri, acc1, d1) + fmaf(ecum, s1, Dh * (pk.y * rdt));
    yr[2] = fmaf(ri, acc2, d2) + fmaf(ecum, s2, Dh * (pk.z * rdt));
    __syncthreads();

    {   // coalesced epilogue: 24 contiguous channels per row
        int i2 = t >> 3, q2 = t & 7;
        float* dst = y + (size_t)(row0 + i2) * D_INNER + hg * 24 + q2 * 3;
        dst[0] = ysr[i2][q2 * 3 + 0];
        dst[1] = ysr[i2][q2 * 3 + 1];
        dst[2] = ysr[i2][q2 * 3 + 2];
    }
}

// ---------------------------------------------------------------------------
// K6: y = y * silu(z); RMSNorm over 768; * norm_w.  Writes split-bf16 output.
// ---------------------------------------------------------------------------
__global__ __launch_bounds__(256) void gate_norm_kernel(
    const float* __restrict__ zx, const float* __restrict__ norm_w,
    const float* __restrict__ y,
    unsigned short* __restrict__ yh, unsigned short* __restrict__ yl)
{
    int bl = blockIdx.x;
    int t  = threadIdx.x;
    const float* zrow = zx + (size_t)bl * D_IN_PROJ;
    const float* yrow = y + (size_t)bl * D_INNER;

    float v[3];
    float ss = 0.f;
    #pragma unroll
    for (int j = 0; j < 3; ++j) {
        int i = t + j * 256;
        float z = zrow[i];
        float s = z / (1.f + expf(-z));
        float val = yrow[i] * s;
        v[j] = val;
        ss += val * val;
    }
    ss += __shfl_xor(ss, 32);
    ss += __shfl_xor(ss, 16);
    ss += __shfl_xor(ss, 8);
    ss += __shfl_xor(ss, 4);
    ss += __shfl_xor(ss, 2);
    ss += __shfl_xor(ss, 1);
    __shared__ float red[4];
    int lane = t & 63, wid = t >> 6;
    if (lane == 0) red[wid] = ss;
    __syncthreads();
    float tot = red[0] + red[1] + red[2] + red[3];
    float rs = rsqrtf(tot * (1.f / D_INNER) + 1e-5f);
    #pragma unroll
    for (int j = 0; j < 3; ++j) {
        int i = t + j * 256;
        float o = v[j] * rs * norm_w[i];
        unsigned short h = f2bf(o);
        yh[(size_t)bl * D_INNER + i] = h;
        yl[(size_t)bl * D_INNER + i] = f2bf(o - bf2f(h));
    }
}

// ---------------------------------------------------------------------------
extern "C" void kernel_launch(void* const* d_in, const int* in_sizes, int n_in,
                              void* d_out, int out_size, void* d_ws, size_t ws_size,
                              hipStream_t stream)
{
    const float* x           = (const float*)d_in[0];
    const float* conv_w      = (const float*)d_in[1];
    const float* conv_b      = (const float*)d_in[2];
    const float* in_proj_w   = (const float*)d_in[3];
    const float* dw_conv_w   = (const float*)d_in[4];
    const float* dw_conv_b   = (const float*)d_in[5];
    const float* dt_bias     = (const float*)d_in[6];
    const float* A_log       = (const float*)d_in[7];
    const float* Dp          = (const float*)d_in[8];
    const float* norm_w      = (const float*)d_in[9];
    const float* mamba_out_w = (const float*)d_in[10];
    const float* out_conv_w  = (const float*)d_in[11];
    float* out = (float*)d_out;
    float* ws  = (float*)d_ws;

    // ---- workspace layout (floats) ----
    float* S0   = ws;                        //  2,097,152  Gbuf+Sloc / late: cow
    float* zx   = S0 + 2097152;              // 14,942,208  early: xT+cw / late: tmpP+mow
    float* xBCs = zx + 14942208;             //  6,553,600  early: ipw / late: yb
    float* dtb  = xBCs + 6553600;            //  2,097,152
    float* ybuf = dtb + 2097152;             //  6,291,456  early: prodA+u

    float* Gbuf = S0;                        // 524,288
    float* Sloc = S0 + 524288;               // 1,572,864
    unsigned short* cow_hi = (unsigned short*)S0;
    unsigned short* cow_lo = (unsigned short*)(S0 + 65536);

    unsigned short* xT_hi = (unsigned short*)zx;
    unsigned short* xT_lo = (unsigned short*)(zx + 525056);
    unsigned short* cw_hi = (unsigned short*)(zx + 1050112);
    unsigned short* cw_lo = (unsigned short*)(zx + 1115648);
    unsigned short* tmpP_hi = (unsigned short*)zx;
    unsigned short* tmpP_lo = (unsigned short*)(zx + 1050112);
    unsigned short* mow_hi  = (unsigned short*)(zx + 2100224);
    unsigned short* mow_lo  = (unsigned short*)(zx + 2198528);

    unsigned short* ipw_hi = (unsigned short*)xBCs;
    unsigned short* ipw_lo = (unsigned short*)(xBCs + 233472);
    unsigned short* yb_hi  = (unsigned short*)xBCs;
    unsigned short* yb_lo  = (unsigned short*)(xBCs + 3145728);

    float* prodA = ybuf;
    unsigned short* u_hi = (unsigned short*)(ybuf + 32768);
    unsigned short* u_lo = (unsigned short*)(ybuf + 32768 + 1048576);

    // ---- 1. conv_in as GEMM ----
    prep_early_kernel<<<518, 256, 0, stream>>>(xT_hi, xT_lo, conv_w, cw_hi, cw_lo);
    transpose_x_kernel<<<dim3(L_ / 32, IN_DIM / 32, B_), 256, 0, stream>>>(
        x, xT_hi, xT_lo);
    gemm_ci_kernel<<<dim3(2, (B_ * L_) / 128), 256, 0, stream>>>(
        xT_hi, xT_lo, cw_hi, cw_lo, conv_b, u_hi, u_lo);

    // ---- 2. in_proj GEMM with fused dt-softplus ----
    tconv_kernel<<<dim3(D_IN_PROJ / 32, D_MODEL / 32), 256, 0, stream>>>(
        in_proj_w, ipw_hi, ipw_lo, D_MODEL, D_IN_PROJ);
    gemm_ip_kernel<<<dim3((D_IN_PROJ + 127) / 128, (B_ * L_) / 128), 256, 0, stream>>>(
        u_hi, u_lo, ipw_hi, ipw_lo, dt_bias, zx, dtb, B_ * L_, D_IN_PROJ, D_MODEL);

    // ---- 3. elementwise + scan ----
    dwconv_kernel<<<(B_ * (L_ / 8) * CONV_DIM) / 256, 256, 0, stream>>>(
        zx, dw_conv_w, dw_conv_b, xBCs);
    gmat_kernel<<<B_ * SCAN_NC, 256, 0, stream>>>(xBCs, Gbuf);
    scan_local2<<<B_ * SCAN_NC * (NHEADS / 8), 512, 0, stream>>>(
        xBCs, dtb, A_log, Sloc, prodA);
    scan_prefix_kernel<<<(B_ * NHEADS) / 4, 256, 0, stream>>>(Sloc, prodA);
    scan_final2<<<B_ * SCAN_NC * (NHEADS / 8), 512, 0, stream>>>(
        xBCs, dtb, A_log, Dp, Sloc, Gbuf, ybuf);

    // ---- 4. gate + norm (last use of zx) ----
    gate_norm_kernel<<<B_ * L_, 256, 0, stream>>>(zx, norm_w, ybuf, yb_hi, yb_lo);

    // ---- 5. mamba_out GEMM -> padded split tmpP ----
    prep_late_kernel<<<524, 256, 0, stream>>>(out_conv_w, cow_hi, cow_lo,
                                              tmpP_hi, tmpP_lo);
    tconv_kernel<<<dim3(D_MODEL / 32, D_INNER / 32), 256, 0, stream>>>(
        mamba_out_w, mow_hi, mow_lo, D_INNER, D_MODEL);
    gemm_mo_kernel<<<dim3(2, (B_ * L_) / 128), 256, 0, stream>>>(
        yb_hi, yb_lo, mow_hi, mow_lo, tmpP_hi, tmpP_lo);

    // ---- 6. conv_out as full-K GEMM ----
    gemm_co_kernel<<<dim3(1, (B_ * L_) / 128), 256, 0, stream>>>(
        tmpP_hi, tmpP_lo, cow_hi, cow_lo, out);
}

// Round 14
// 352.981 us; speedup vs baseline: 1.1273x; 1.1273x over previous
//
#include <hip/hip_runtime.h>
#include <math.h>

#define B_      4
#define L_      2048
#define IN_DIM  128
#define D_MODEL 256
#define OUT_DIM 128
#define D_STATE 16
#define D_INNER 768
#define NHEADS  256
#define HEADDIM 3
#define CONV_DIM 800
#define D_IN_PROJ 1824

#define SCAN_NC 32
#define SCAN_CL 64
#define LPAD    2051        // L_ + 3 padded rows (row0 = left pad, rows 2049/2050 = right pad)

typedef short  short8 __attribute__((ext_vector_type(8)));
typedef float  f32x4  __attribute__((ext_vector_type(4)));

__device__ __forceinline__ unsigned short f2bf(float f) {
    unsigned int u = __float_as_uint(f);
    u = (u + 0x7fffu + ((u >> 16) & 1u)) >> 16;     // RN-to-even
    return (unsigned short)u;
}
__device__ __forceinline__ float bf2f(unsigned short h) {
    return __uint_as_float(((unsigned int)h) << 16);
}

// ---------------------------------------------------------------------------
// zero the 3 pad rows per batch of a padded split-bf16 tensor [B][LPAD][pitch]
// ---------------------------------------------------------------------------
__global__ __launch_bounds__(256) void zero_pads_kernel(
    unsigned short* __restrict__ ph, unsigned short* __restrict__ pl, int pitch)
{
    int t = blockIdx.x * 256 + threadIdx.x;
    int n = B_ * 3 * pitch;
    if (t < n) {
        int ch = t % pitch, rb = t / pitch;
        int b = rb / 3, ri = rb % 3;
        int row = (ri == 0) ? 0 : (ri == 1) ? (L_ + 1) : (L_ + 2);
        size_t off = ((size_t)b * LPAD + row) * pitch + ch;
        ph[off] = 0; pl[off] = 0;
    }
}

// ---------------------------------------------------------------------------
// transpose x [b][i][L] fp32 -> padded split-bf16 xT [b][LPAD][128], row l+1
// ---------------------------------------------------------------------------
__global__ __launch_bounds__(256) void transpose_x_kernel(
    const float* __restrict__ x, unsigned short* __restrict__ xh,
    unsigned short* __restrict__ xl)
{
    __shared__ float tile[32][33];
    int b = blockIdx.z;
    int l0 = blockIdx.x * 32, i0 = blockIdx.y * 32;
    int tx = threadIdx.x & 31, ty = threadIdx.x >> 5;   // ty 0..7
    const float* xb = x + (size_t)b * IN_DIM * L_;
    #pragma unroll
    for (int r = 0; r < 4; ++r)
        tile[ty + r * 8][tx] = xb[(size_t)(i0 + ty + r * 8) * L_ + l0 + tx];
    __syncthreads();
    #pragma unroll
    for (int r = 0; r < 4; ++r) {
        int l = l0 + ty + r * 8;
        float v = tile[tx][ty + r * 8];                  // x[b][i0+tx][l]
        size_t off = ((size_t)b * LPAD + l + 1) * IN_DIM + i0 + tx;
        unsigned short h = f2bf(v);
        xh[off] = h;
        xl[off] = f2bf(v - bf2f(h));
    }
}

// ---------------------------------------------------------------------------
// reindex+split conv_w [256][128][4] -> cw [256][512], kk = k*128+i
// ---------------------------------------------------------------------------
__global__ __launch_bounds__(256) void prep_cw_kernel(
    const float* __restrict__ w, unsigned short* __restrict__ wh,
    unsigned short* __restrict__ wl)
{
    int t = blockIdx.x * 256 + threadIdx.x;              // 256*512
    if (t < D_MODEL * 512) {
        int o = t >> 9, kk = t & 511;
        int k = kk >> 7, i = kk & 127;
        float v = w[((size_t)o * IN_DIM + i) * 4 + k];
        unsigned short h = f2bf(v);
        wh[t] = h; wl[t] = f2bf(v - bf2f(h));
    }
}

// ---------------------------------------------------------------------------
// reindex+split out_conv_w [128][256][4] -> cow [128][1024], kk = k*256+c
// ---------------------------------------------------------------------------
__global__ __launch_bounds__(256) void prep_cow_kernel(
    const float* __restrict__ w, unsigned short* __restrict__ wh,
    unsigned short* __restrict__ wl)
{
    int t = blockIdx.x * 256 + threadIdx.x;              // 128*1024
    if (t < OUT_DIM * 1024) {
        int o = t >> 10, kk = t & 1023;
        int k = kk >> 8, c = kk & 255;
        float v = w[((size_t)o * D_MODEL + c) * 4 + k];
        unsigned short h = f2bf(v);
        wh[t] = h; wl[t] = f2bf(v - bf2f(h));
    }
}

// ---------------------------------------------------------------------------
// transpose + split: src[K][N] fp32 -> dh/dl [N][K] bf16  (weight prep)
// ---------------------------------------------------------------------------
__global__ __launch_bounds__(256) void tconv_kernel(
    const float* __restrict__ src, unsigned short* __restrict__ dh,
    unsigned short* __restrict__ dl, int K, int N)
{
    __shared__ float tile[32][33];
    int k0 = blockIdx.y * 32, n0 = blockIdx.x * 32;
    int tx = threadIdx.x & 31, ty = threadIdx.x >> 5;
    #pragma unroll
    for (int r = 0; r < 4; ++r)
        tile[ty + r * 8][tx] = src[(size_t)(k0 + ty + r * 8) * N + n0 + tx];
    __syncthreads();
    #pragma unroll
    for (int r = 0; r < 4; ++r) {
        int n = n0 + ty + r * 8;
        float v = tile[tx][ty + r * 8];
        unsigned short h = f2bf(v);
        dh[(size_t)n * K + k0 + tx] = h;
        dl[(size_t)n * K + k0 + tx] = f2bf(v - bf2f(h));
    }
}

// ---------------------------------------------------------------------------
// K2: split-bf16 MFMA GEMM (generic).  C[M,N] fp32 = (Ah+Al)[M,K]*(Bh+Bl)^T
// ---------------------------------------------------------------------------
__global__ __launch_bounds__(256) void gemm_bf16s_kernel(
    const unsigned short* __restrict__ Ah, const unsigned short* __restrict__ Al,
    const unsigned short* __restrict__ Bh, const unsigned short* __restrict__ Bl,
    float* __restrict__ C, int M, int N, int K)
{
    __shared__ __align__(16) unsigned short AsH[128][40];
    __shared__ __align__(16) unsigned short AsL[128][40];
    __shared__ __align__(16) unsigned short BsH[128][40];
    __shared__ __align__(16) unsigned short BsL[128][40];

    int m0 = blockIdx.y * 128, n0 = blockIdx.x * 128;
    int t = threadIdx.x;
    int wid = t >> 6, lane = t & 63;
    int wm = (wid >> 1) * 64, wn = (wid & 1) * 64;
    int fr = lane & 15, fq = lane >> 4;

    f32x4 z4 = {0.f, 0.f, 0.f, 0.f};
    f32x4 acc[4][4];
    #pragma unroll
    for (int i = 0; i < 4; ++i)
        #pragma unroll
        for (int j = 0; j < 4; ++j) acc[i][j] = z4;

    for (int k0 = 0; k0 < K; k0 += 32) {
        __syncthreads();
        #pragma unroll
        for (int p = 0; p < 2; ++p) {
            int idx = p * 256 + t;
            int row = idx >> 2, q = idx & 3;
            int koff = k0 + q * 8;
            *(float4*)&AsH[row][q * 8] =
                *(const float4*)(Ah + (size_t)(m0 + row) * K + koff);
            *(float4*)&AsL[row][q * 8] =
                *(const float4*)(Al + (size_t)(m0 + row) * K + koff);
            int n = n0 + row;
            float4 vbh = make_float4(0.f, 0.f, 0.f, 0.f), vbl = vbh;
            if (n < N) {
                vbh = *(const float4*)(Bh + (size_t)n * K + koff);
                vbl = *(const float4*)(Bl + (size_t)n * K + koff);
            }
            *(float4*)&BsH[row][q * 8] = vbh;
            *(float4*)&BsL[row][q * 8] = vbl;
        }
        __syncthreads();

        short8 ah[4], al[4], bh[4], bl[4];
        #pragma unroll
        for (int i = 0; i < 4; ++i) {
            ah[i] = *(const short8*)&AsH[wm + i * 16 + fr][fq * 8];
            al[i] = *(const short8*)&AsL[wm + i * 16 + fr][fq * 8];
            bh[i] = *(const short8*)&BsH[wn + i * 16 + fr][fq * 8];
            bl[i] = *(const short8*)&BsL[wn + i * 16 + fr][fq * 8];
        }
        #pragma unroll
        for (int i = 0; i < 4; ++i)
            #pragma unroll
            for (int j = 0; j < 4; ++j) {
                acc[i][j] = __builtin_amdgcn_mfma_f32_16x16x32_bf16(
                    ah[i], bh[j], acc[i][j], 0, 0, 0);
                acc[i][j] = __builtin_amdgcn_mfma_f32_16x16x32_bf16(
                    ah[i], bl[j], acc[i][j], 0, 0, 0);
                acc[i][j] = __builtin_amdgcn_mfma_f32_16x16x32_bf16(
                    al[i], bh[j], acc[i][j], 0, 0, 0);
            }
    }

    #pragma unroll
    for (int i = 0; i < 4; ++i) {
        int r0 = m0 + wm + i * 16 + fq * 4;
        #pragma unroll
        for (int j = 0; j < 4; ++j) {
            int cc = n0 + wn + j * 16 + fr;
            if (cc < N) {
                #pragma unroll
                for (int r = 0; r < 4; ++r)
                    C[(size_t)(r0 + r) * N + cc] = acc[i][j][r];
            }
        }
    }
}

// ---------------------------------------------------------------------------
// conv_in as GEMM: A = xT window, B = cw [256][512]. Epilogue: + conv_b,
// write split-bf16 u [8192][256].
// ---------------------------------------------------------------------------
__global__ __launch_bounds__(256) void gemm_ci_kernel(
    const unsigned short* __restrict__ Ah, const unsigned short* __restrict__ Al,
    const unsigned short* __restrict__ Bh, const unsigned short* __restrict__ Bl,
    const float* __restrict__ bias,
    unsigned short* __restrict__ Ch, unsigned short* __restrict__ Cl)
{
    const int K = 512;
    __shared__ __align__(16) unsigned short AsH[128][40];
    __shared__ __align__(16) unsigned short AsL[128][40];
    __shared__ __align__(16) unsigned short BsH[128][40];
    __shared__ __align__(16) unsigned short BsL[128][40];

    int m0 = blockIdx.y * 128, n0 = blockIdx.x * 128;
    int b = m0 >> 11;
    size_t abase = ((size_t)b * LPAD + (m0 & 2047)) * IN_DIM;
    int t = threadIdx.x;
    int wid = t >> 6, lane = t & 63;
    int wm = (wid >> 1) * 64, wn = (wid & 1) * 64;
    int fr = lane & 15, fq = lane >> 4;

    f32x4 z4 = {0.f, 0.f, 0.f, 0.f};
    f32x4 acc[4][4];
    #pragma unroll
    for (int i = 0; i < 4; ++i)
        #pragma unroll
        for (int j = 0; j < 4; ++j) acc[i][j] = z4;

    for (int k0 = 0; k0 < K; k0 += 32) {
        __syncthreads();
        #pragma unroll
        for (int p = 0; p < 2; ++p) {
            int idx = p * 256 + t;
            int row = idx >> 2, q = idx & 3;
            int koff = k0 + q * 8;
            *(float4*)&AsH[row][q * 8] =
                *(const float4*)(Ah + abase + (size_t)row * IN_DIM + koff);
            *(float4*)&AsL[row][q * 8] =
                *(const float4*)(Al + abase + (size_t)row * IN_DIM + koff);
            int n = n0 + row;
            *(float4*)&BsH[row][q * 8] = *(const float4*)(Bh + (size_t)n * K + koff);
            *(float4*)&BsL[row][q * 8] = *(const float4*)(Bl + (size_t)n * K + koff);
        }
        __syncthreads();

        short8 ah[4], al[4], bh[4], bl[4];
        #pragma unroll
        for (int i = 0; i < 4; ++i) {
            ah[i] = *(const short8*)&AsH[wm + i * 16 + fr][fq * 8];
            al[i] = *(const short8*)&AsL[wm + i * 16 + fr][fq * 8];
            bh[i] = *(const short8*)&BsH[wn + i * 16 + fr][fq * 8];
            bl[i] = *(const short8*)&BsL[wn + i * 16 + fr][fq * 8];
        }
        #pragma unroll
        for (int i = 0; i < 4; ++i)
            #pragma unroll
            for (int j = 0; j < 4; ++j) {
                acc[i][j] = __builtin_amdgcn_mfma_f32_16x16x32_bf16(
                    ah[i], bh[j], acc[i][j], 0, 0, 0);
                acc[i][j] = __builtin_amdgcn_mfma_f32_16x16x32_bf16(
                    ah[i], bl[j], acc[i][j], 0, 0, 0);
                acc[i][j] = __builtin_amdgcn_mfma_f32_16x16x32_bf16(
                    al[i], bh[j], acc[i][j], 0, 0, 0);
            }
    }

    #pragma unroll
    for (int i = 0; i < 4; ++i) {
        int r0 = m0 + wm + i * 16 + fq * 4;
        #pragma unroll
        for (int j = 0; j < 4; ++j) {
            int cc = n0 + wn + j * 16 + fr;
            float bc = bias[cc];
            #pragma unroll
            for (int r = 0; r < 4; ++r) {
                float v = acc[i][j][r] + bc;
                unsigned short h = f2bf(v);
                size_t off = (size_t)(r0 + r) * D_MODEL + cc;
                Ch[off] = h;
                Cl[off] = f2bf(v - bf2f(h));
            }
        }
    }
}

// ---------------------------------------------------------------------------
// gemm2 (mamba_out) with split-bf16 PADDED output: row m=(b,l) -> padded row
// b*LPAD + l + 1 of tmpP [.][256].
// ---------------------------------------------------------------------------
__global__ __launch_bounds__(256) void gemm_mo_kernel(
    const unsigned short* __restrict__ Ah, const unsigned short* __restrict__ Al,
    const unsigned short* __restrict__ Bh, const unsigned short* __restrict__ Bl,
    unsigned short* __restrict__ Ch, unsigned short* __restrict__ Cl)
{
    const int K = D_INNER, N = D_MODEL;
    __shared__ __align__(16) unsigned short AsH[128][40];
    __shared__ __align__(16) unsigned short AsL[128][40];
    __shared__ __align__(16) unsigned short BsH[128][40];
    __shared__ __align__(16) unsigned short BsL[128][40];

    int m0 = blockIdx.y * 128, n0 = blockIdx.x * 128;
    int t = threadIdx.x;
    int wid = t >> 6, lane = t & 63;
    int wm = (wid >> 1) * 64, wn = (wid & 1) * 64;
    int fr = lane & 15, fq = lane >> 4;

    f32x4 z4 = {0.f, 0.f, 0.f, 0.f};
    f32x4 acc[4][4];
    #pragma unroll
    for (int i = 0; i < 4; ++i)
        #pragma unroll
        for (int j = 0; j < 4; ++j) acc[i][j] = z4;

    for (int k0 = 0; k0 < K; k0 += 32) {
        __syncthreads();
        #pragma unroll
        for (int p = 0; p < 2; ++p) {
            int idx = p * 256 + t;
            int row = idx >> 2, q = idx & 3;
            int koff = k0 + q * 8;
            *(float4*)&AsH[row][q * 8] =
                *(const float4*)(Ah + (size_t)(m0 + row) * K + koff);
            *(float4*)&AsL[row][q * 8] =
                *(const float4*)(Al + (size_t)(m0 + row) * K + koff);
            int n = n0 + row;
            *(float4*)&BsH[row][q * 8] = *(const float4*)(Bh + (size_t)n * K + koff);
            *(float4*)&BsL[row][q * 8] = *(const float4*)(Bl + (size_t)n * K + koff);
        }
        __syncthreads();

        short8 ah[4], al[4], bh[4], bl[4];
        #pragma unroll
        for (int i = 0; i < 4; ++i) {
            ah[i] = *(const short8*)&AsH[wm + i * 16 + fr][fq * 8];
            al[i] = *(const short8*)&AsL[wm + i * 16 + fr][fq * 8];
            bh[i] = *(const short8*)&BsH[wn + i * 16 + fr][fq * 8];
            bl[i] = *(const short8*)&BsL[wn + i * 16 + fr][fq * 8];
        }
        #pragma unroll
        for (int i = 0; i < 4; ++i)
            #pragma unroll
            for (int j = 0; j < 4; ++j) {
                acc[i][j] = __builtin_amdgcn_mfma_f32_16x16x32_bf16(
                    ah[i], bh[j], acc[i][j], 0, 0, 0);
                acc[i][j] = __builtin_amdgcn_mfma_f32_16x16x32_bf16(
                    ah[i], bl[j], acc[i][j], 0, 0, 0);
                acc[i][j] = __builtin_amdgcn_mfma_f32_16x16x32_bf16(
                    al[i], bh[j], acc[i][j], 0, 0, 0);
            }
    }

    int b = m0 >> 11;
    #pragma unroll
    for (int i = 0; i < 4; ++i) {
        int r0 = m0 + wm + i * 16 + fq * 4;
        #pragma unroll
        for (int j = 0; j < 4; ++j) {
            int cc = n0 + wn + j * 16 + fr;
            #pragma unroll
            for (int r = 0; r < 4; ++r) {
                int l = (r0 + r) & 2047;
                float v = acc[i][j][r];
                unsigned short h = f2bf(v);
                size_t off = ((size_t)b * LPAD + l + 1) * D_MODEL + cc;
                Ch[off] = h;
                Cl[off] = f2bf(v - bf2f(h));
            }
        }
    }
}

// ---------------------------------------------------------------------------
// conv_out as GEMM, full-K (no split, no atomics): A = tmpP window
// [(b*LPAD+l)*256, 1024 contiguous], B = cow [128][1024]. 64 blocks.
// ---------------------------------------------------------------------------
__global__ __launch_bounds__(256) void gemm_co_kernel(
    const unsigned short* __restrict__ Ah, const unsigned short* __restrict__ Al,
    const unsigned short* __restrict__ Bh, const unsigned short* __restrict__ Bl,
    float* __restrict__ out)
{
    const int K = 1024;
    __shared__ __align__(16) unsigned short AsH[128][40];
    __shared__ __align__(16) unsigned short AsL[128][40];
    __shared__ __align__(16) unsigned short BsH[128][40];
    __shared__ __align__(16) unsigned short BsL[128][40];

    int m0 = blockIdx.y * 128;
    int b = m0 >> 11, l0t = m0 & 2047;
    size_t abase = ((size_t)b * LPAD + l0t) * D_MODEL;
    int t = threadIdx.x;
    int wid = t >> 6, lane = t & 63;
    int wm = (wid >> 1) * 64, wn = (wid & 1) * 64;
    int fr = lane & 15, fq = lane >> 4;

    f32x4 z4 = {0.f, 0.f, 0.f, 0.f};
    f32x4 acc[4][4];
    #pragma unroll
    for (int i = 0; i < 4; ++i)
        #pragma unroll
        for (int j = 0; j < 4; ++j) acc[i][j] = z4;

    for (int k0 = 0; k0 < K; k0 += 32) {
        __syncthreads();
        #pragma unroll
        for (int p = 0; p < 2; ++p) {
            int idx = p * 256 + t;
            int row = idx >> 2, q = idx & 3;
            int koff = k0 + q * 8;
            *(float4*)&AsH[row][q * 8] =
                *(const float4*)(Ah + abase + (size_t)row * D_MODEL + koff);
            *(float4*)&AsL[row][q * 8] =
                *(const float4*)(Al + abase + (size_t)row * D_MODEL + koff);
            *(float4*)&BsH[row][q * 8] = *(const float4*)(Bh + (size_t)row * K + koff);
            *(float4*)&BsL[row][q * 8] = *(const float4*)(Bl + (size_t)row * K + koff);
        }
        __syncthreads();

        short8 ah[4], al[4], bh[4], bl[4];
        #pragma unroll
        for (int i = 0; i < 4; ++i) {
            ah[i] = *(const short8*)&AsH[wm + i * 16 + fr][fq * 8];
            al[i] = *(const short8*)&AsL[wm + i * 16 + fr][fq * 8];
            bh[i] = *(const short8*)&BsH[wn + i * 16 + fr][fq * 8];
            bl[i] = *(const short8*)&BsL[wn + i * 16 + fr][fq * 8];
        }
        #pragma unroll
        for (int i = 0; i < 4; ++i)
            #pragma unroll
            for (int j = 0; j < 4; ++j) {
                acc[i][j] = __builtin_amdgcn_mfma_f32_16x16x32_bf16(
                    ah[i], bh[j], acc[i][j], 0, 0, 0);
                acc[i][j] = __builtin_amdgcn_mfma_f32_16x16x32_bf16(
                    ah[i], bl[j], acc[i][j], 0, 0, 0);
                acc[i][j] = __builtin_amdgcn_mfma_f32_16x16x32_bf16(
                    al[i], bh[j], acc[i][j], 0, 0, 0);
            }
    }

    #pragma unroll
    for (int i = 0; i < 4; ++i) {
        int lr = l0t + wm + i * 16 + fq * 4;
        #pragma unroll
        for (int j = 0; j < 4; ++j) {
            int cc = wn + j * 16 + fr;                  // o in 0..127
            float* dst = out + ((size_t)(b * OUT_DIM + cc)) * L_ + lr;
            float4 ov = make_float4(acc[i][j][0], acc[i][j][1],
                                    acc[i][j][2], acc[i][j][3]);
            *(float4*)dst = ov;
        }
    }
}

// ---------------------------------------------------------------------------
// K3: dt = softplus(dt_raw + dt_bias)    [B*L, 256]
// ---------------------------------------------------------------------------
__global__ __launch_bounds__(256) void dt_kernel(
    const float* __restrict__ zx, const float* __restrict__ dt_bias,
    float* __restrict__ dtb)
{
    int idx = blockIdx.x * 256 + threadIdx.x;
    int h  = idx & 255;
    int bl = idx >> 8;
    float v = zx[(size_t)bl * D_IN_PROJ + (D_INNER + CONV_DIM) + h] + dt_bias[h];
    float sp = (v > 20.f) ? v : log1pf(expf(v));
    dtb[idx] = sp;
}

// ---------------------------------------------------------------------------
// K4: causal depthwise conv + bias + SiLU. 8 l-values per thread.
// ---------------------------------------------------------------------------
__global__ __launch_bounds__(256) void dwconv_kernel(
    const float* __restrict__ zx, const float* __restrict__ w,
    const float* __restrict__ bias, float* __restrict__ xBCs)
{
    int idx = blockIdx.x * 256 + threadIdx.x;   // over B * L/8 * 800
    int c   = idx % CONV_DIM;
    int bl8 = idx / CONV_DIM;
    int b  = bl8 >> 8;               // L/8 = 256
    int l0 = (bl8 & 255) * 8;
    float4 wv = *(const float4*)&w[c * 4];
    float bi = bias[c];
    const float* base = zx + ((size_t)(b * L_ + l0)) * D_IN_PROJ + D_INNER + c;
    float r[11];
    #pragma unroll
    for (int k = 0; k < 11; ++k) {
        int l = l0 - 3 + k;
        r[k] = (l >= 0) ? base[(ptrdiff_t)(k - 3) * D_IN_PROJ] : 0.f;
    }
    #pragma unroll
    for (int i = 0; i < 8; ++i) {
        float acc = bi;
        acc = fmaf(r[i + 0], wv.x, acc);
        acc = fmaf(r[i + 1], wv.y, acc);
        acc = fmaf(r[i + 2], wv.z, acc);
        acc = fmaf(r[i + 3], wv.w, acc);
        float s = acc / (1.f + expf(-acc));
        xBCs[((size_t)(b * L_ + l0 + i)) * CONV_DIM + c] = s;
    }
}

// ---------------------------------------------------------------------------
// K5g: G[i][j] = C_i . B_j  per (b,chunk).  bid = b*32+c -> XCD = c%8,
// matching the scan swizzle (bc & 7) so G stays in the producing XCD's L2.
// ---------------------------------------------------------------------------
__global__ __launch_bounds__(256) void gmat_kernel(
    const float* __restrict__ xBCs, float* __restrict__ G)
{
    __shared__ float Bs[64][16];
    __shared__ float Cs[64][16];
    int c = blockIdx.x & 31, b = blockIdx.x >> 5;
    int t = threadIdx.x;
    int row0 = b * L_ + c * SCAN_CL;
    {
        int j = t >> 2, q = t & 3;
        const float* r = xBCs + (size_t)(row0 + j) * CONV_DIM + D_INNER;
        *(float4*)&Bs[j][q * 4] = *(const float4*)(r + q * 4);
        *(float4*)&Cs[j][q * 4] = *(const float4*)(r + D_STATE + q * 4);
    }
    __syncthreads();
    int i = t >> 2, jq = t & 3;
    float4 c0 = *(const float4*)&Cs[i][0];
    float4 c1 = *(const float4*)&Cs[i][4];
    float4 c2 = *(const float4*)&Cs[i][8];
    float4 c3 = *(const float4*)&Cs[i][12];
    float dot[16];
    #pragma unroll
    for (int jj = 0; jj < 16; ++jj) {
        int j = jq * 16 + jj;
        float4 b0 = *(const float4*)&Bs[j][0];
        float4 b1 = *(const float4*)&Bs[j][4];
        float4 b2 = *(const float4*)&Bs[j][8];
        float4 b3 = *(const float4*)&Bs[j][12];
        float d = c0.x * b0.x + c0.y * b0.y + c0.z * b0.z + c0.w * b0.w;
        d = fmaf(c1.x, b1.x, d); d = fmaf(c1.y, b1.y, d);
        d = fmaf(c1.z, b1.z, d); d = fmaf(c1.w, b1.w, d);
        d = fmaf(c2.x, b2.x, d); d = fmaf(c2.y, b2.y, d);
        d = fmaf(c2.z, b2.z, d); d = fmaf(c2.w, b2.w, d);
        d = fmaf(c3.x, b3.x, d); d = fmaf(c3.y, b3.y, d);
        d = fmaf(c3.z, b3.z, d); d = fmaf(c3.w, b3.w, d);
        dot[jj] = d;
    }
    float* gout = G + ((size_t)blockIdx.x * 64 + i) * 64 + jq * 16;
    #pragma unroll
    for (int q = 0; q < 4; ++q)
        *(float4*)(gout + q * 4) = make_float4(dot[q*4], dot[q*4+1], dot[q*4+2], dot[q*4+3]);
}

// ---------------------------------------------------------------------------
// XCD-locality swizzle: all 32 hg blocks of one (b,c) share bid%8 -> same XCD
// bid = (bc>>3)<<8 | hg<<3 | (bc&7);  bc = b*32+c.
// ---------------------------------------------------------------------------
__device__ __forceinline__ void scan_decode(int bid, int& b, int& c, int& hg)
{
    int bcl = bid & 7;
    hg = (bid >> 3) & 31;
    int bc = ((bid >> 8) << 3) | bcl;
    c = bc & 31;
    b = bc >> 5;
}

// ---------------------------------------------------------------------------
// K5a: chunk-local state build. 512 threads = 8 waves; ONE head per wave.
// ---------------------------------------------------------------------------
__global__ __launch_bounds__(512) void scan_local2(
    const float* __restrict__ xBCs, const float* __restrict__ dtb,
    const float* __restrict__ A_log,
    float* __restrict__ Sloc, float* __restrict__ prodA)
{
    __shared__ float  BsT[16][68];          // [n][row], padded
    __shared__ float4 Pk[8][64];            // [head][row] {dtx0,dtx1,dtx2,dt}
    __shared__ float  UT[8][3][64];
    int b, c, hg;
    scan_decode(blockIdx.x, b, c, hg);
    int h0 = hg * 8;
    int t = threadIdx.x;
    int row0 = b * L_ + c * SCAN_CL;

    if (t < 256) {   // B tile (coalesced)
        int j = t >> 2, q = t & 3;
        const float* r = xBCs + (size_t)(row0 + j) * CONV_DIM;
        float4 bv = *(const float4*)(r + D_INNER + q * 4);
        BsT[q*4+0][j] = bv.x; BsT[q*4+1][j] = bv.y;
        BsT[q*4+2][j] = bv.z; BsT[q*4+3][j] = bv.w;
    }
    {   // Pk: 8 heads x 64 rows, one entry per thread (dense per row)
        int hh = t & 7, j = t >> 3;
        float dtv = dtb[(size_t)(row0 + j) * NHEADS + h0 + hh];
        const float* xr = xBCs + (size_t)(row0 + j) * CONV_DIM + (h0 + hh) * 3;
        Pk[hh][j] = make_float4(dtv * xr[0], dtv * xr[1], dtv * xr[2], dtv);
    }
    __syncthreads();

    int wv = t >> 6, lane = t & 63;
    int hh = wv;
    int h = h0 + hh;
    int p = lane >> 4, n = lane & 15;
    int pc = (p < 3) ? p : 2;

    float4 pk = Pk[hh][lane];
    float A = -__expf(A_log[h]);
    float cum = pk.w * A;
    #pragma unroll
    for (int off = 1; off < 64; off <<= 1) {
        float sv = __shfl_up(cum, off);
        if (lane >= off) cum += sv;
    }
    float cum63 = __shfl(cum, 63);
    float wf = __expf(cum63 - cum);
    UT[hh][0][lane] = wf * pk.x;
    UT[hh][1][lane] = wf * pk.y;
    UT[hh][2][lane] = wf * pk.z;
    float state = 0.f;
    #pragma unroll
    for (int q = 0; q < 16; ++q) {
        float4 Bv = *(const float4*)&BsT[n][q * 4];
        float4 Uv = *(const float4*)&UT[hh][pc][q * 4];
        state = fmaf(Uv.x, Bv.x, state);
        state = fmaf(Uv.y, Bv.y, state);
        state = fmaf(Uv.z, Bv.z, state);
        state = fmaf(Uv.w, Bv.w, state);
    }
    size_t bh = (size_t)(b * NHEADS + h);
    if (p < 3) Sloc[(bh * SCAN_NC + c) * 48 + p * 16 + n] = state;
    if (lane == 0) prodA[bh * SCAN_NC + c] = __expf(cum63);
}

// ---------------------------------------------------------------------------
// K5b: sequential prefix over chunks, in place on Sloc
// ---------------------------------------------------------------------------
__global__ __launch_bounds__(256) void scan_prefix_kernel(
    float* __restrict__ Sloc, const float* __restrict__ prodA)
{
    int wv   = blockIdx.x * 4 + (threadIdx.x >> 6);
    int lane = threadIdx.x & 63;
    int p = lane >> 4, n = lane & 15;
    bool act = (p < 3);
    int l48 = ((p < 3) ? p : 2) * 16 + n;
    size_t base = (size_t)wv * SCAN_NC;

    float cur = 0.f;
    for (int c = 0; c < SCAN_NC; ++c) {
        float s  = Sloc[(base + c) * 48 + l48];
        float pa = prodA[base + c];
        if (act) Sloc[(base + c) * 48 + l48] = cur;
        cur = fmaf(pa, cur, s);
    }
}

// ---------------------------------------------------------------------------
// K5c: chunk-matmul final scan. 512 threads = 8 waves; ONE head per wave.
// G staged in LDS once per block (coalesced), shared by all 8 waves.
// ---------------------------------------------------------------------------
__global__ __launch_bounds__(512) void scan_final2(
    const float* __restrict__ xBCs, const float* __restrict__ dtb,
    const float* __restrict__ A_log, const float* __restrict__ Dp,
    const float* __restrict__ Sinit, const float* __restrict__ G,
    float* __restrict__ y)
{
    __shared__ float4 Pk[8][64];            // {dtx0,dtx1,dtx2, dt -> cum}
    __shared__ float4 XW[8][64];
    __shared__ float  Sin[8][48];
    __shared__ float  CsT[16][66];          // [n][row]
    __shared__ float  ysr[64][25];          // [row][24 ch] padded (stride 25)
    __shared__ float  Gs[64][65];           // G tile, odd stride
    int b, c, hg;
    scan_decode(blockIdx.x, b, c, hg);
    int h0 = hg * 8;
    int t = threadIdx.x;
    int row0 = b * L_ + c * SCAN_CL;

    if (t < 256) {   // C tile (coalesced)
        int j = t >> 2, q = t & 3;
        const float* r = xBCs + (size_t)(row0 + j) * CONV_DIM + D_INNER + D_STATE;
        float4 cv = *(const float4*)(r + q * 4);
        CsT[q*4+0][j] = cv.x; CsT[q*4+1][j] = cv.y;
        CsT[q*4+2][j] = cv.z; CsT[q*4+3][j] = cv.w;
    }
    {   // Pk staging: one entry per thread
        int hh = t & 7, j = t >> 3;
        float dtv = dtb[(size_t)(row0 + j) * NHEADS + h0 + hh];
        const float* xr = xBCs + (size_t)(row0 + j) * CONV_DIM + (h0 + hh) * 3;
        Pk[hh][j] = make_float4(dtv * xr[0], dtv * xr[1], dtv * xr[2], dtv);
    }
    if (t < 384) {   // Sin staging: 8 heads x 48
        int hh = t / 48, k = t % 48;
        Sin[hh][k] = Sinit[((size_t)(b * NHEADS + h0 + hh) * SCAN_NC + c) * 48 + k];
    }
    {   // G staging: 4096 floats, coalesced float4 global reads
        const float* Gsrc = G + (size_t)(b * SCAN_NC + c) * 4096;
        #pragma unroll
        for (int e = 0; e < 2; ++e) {
            int idx = e * 512 + t;              // float4 index 0..1023
            int row = idx >> 4, cq = (idx & 15) * 4;
            float4 gv = *(const float4*)(Gsrc + (size_t)idx * 4);
            Gs[row][cq + 0] = gv.x;
            Gs[row][cq + 1] = gv.y;
            Gs[row][cq + 2] = gv.z;
            Gs[row][cq + 3] = gv.w;
        }
    }
    __syncthreads();

    int wv = t >> 6, lane = t & 63;
    int hh = wv;
    int h = h0 + hh;
    int I = lane >> 4;

    float4 pk = Pk[hh][lane];
    float A = -__expf(A_log[h]);
    float cum = pk.w * A;
    #pragma unroll
    for (int off = 1; off < 64; off <<= 1) {
        float sv = __shfl_up(cum, off);
        if (lane >= off) cum += sv;
    }
    float e0 = __shfl(cum, 15);
    float e1 = __shfl(cum, 31);
    float e2 = __shfl(cum, 47);
    float e3 = __shfl(cum, 63);
    int ia = (I << 4) - 1;
    float AIr = __shfl(cum, ia < 0 ? 0 : ia);
    float AI = (I == 0) ? 0.f : AIr;
    float ri = __expf(cum - AI);
    float Eo = (I == 0) ? e0 : (I == 1) ? e1 : (I == 2) ? e2 : e3;
    float wj = __expf(Eo - cum);
    XW[hh][lane] = make_float4(wj * pk.x, wj * pk.y, wj * pk.z, 0.f);
    Pk[hh][lane].w = cum;                   // publish cum_j (wave-local)
    float S0 = (I > 0) ? __expf(AI - e0) : 0.f;
    float S1 = (I > 1) ? __expf(AI - e1) : 0.f;
    float S2 = (I > 2) ? __expf(AI - e2) : 0.f;
    float ecum = __expf(cum);

    float acc0 = 0.f, acc1 = 0.f, acc2 = 0.f;
    #pragma unroll
    for (int J = 0; J < 3; ++J) {
        float SJ = (J == 0) ? S0 : (J == 1) ? S1 : S2;
        float t0 = 0.f, t1 = 0.f, t2 = 0.f;
        #pragma unroll
        for (int kk = 0; kk < 16; ++kk) {
            float gk = Gs[lane][J * 16 + kk];
            float4 u = XW[hh][J * 16 + kk];
            t0 = fmaf(gk, u.x, t0);
            t1 = fmaf(gk, u.y, t1);
            t2 = fmaf(gk, u.z, t2);
        }
        acc0 = fmaf(SJ, t0, acc0);
        acc1 = fmaf(SJ, t1, acc1);
        acc2 = fmaf(SJ, t2, acc2);
    }

    float d0 = 0.f, d1 = 0.f, d2 = 0.f;
    #pragma unroll
    for (int kk = 0; kk < 16; ++kk) {
        int j = (I << 4) + kk;
        float gk = Gs[lane][j];
        float4 pd = Pk[hh][j];
        float e = __expf(cum - pd.w);
        float m = (j <= lane) ? e : 0.f;
        float mg = m * gk;
        d0 = fmaf(mg, pd.x, d0);
        d1 = fmaf(mg, pd.y, d1);
        d2 = fmaf(mg, pd.z, d2);
    }

    float s0 = 0.f, s1 = 0.f, s2 = 0.f;
    #pragma unroll
    for (int nq = 0; nq < 16; ++nq) {
        float Cv = CsT[nq][lane];
        s0 = fmaf(Cv, Sin[hh][nq],      s0);
        s1 = fmaf(Cv, Sin[hh][16 + nq], s1);
        s2 = fmaf(Cv, Sin[hh][32 + nq], s2);
    }

    float rdt = 1.0f / pk.w;
    float Dh = Dp[h];
    float* yr = &ysr[lane][hh * 3];
    yr[0] = fmaf(ri, acc0, d0) + fmaf(ecum, s0, Dh * (pk.x * rdt));
    yr[1] = fmaf(ri, acc1, d1) + fmaf(ecum, s1, Dh * (pk.y * rdt));
    yr[2] = fmaf(ri, acc2, d2) + fmaf(ecum, s2, Dh * (pk.z * rdt));
    __syncthreads();

    {   // coalesced epilogue: 24 contiguous channels per row
        int i2 = t >> 3, q2 = t & 7;
        float* dst = y + (size_t)(row0 + i2) * D_INNER + hg * 24 + q2 * 3;
        dst[0] = ysr[i2][q2 * 3 + 0];
        dst[1] = ysr[i2][q2 * 3 + 1];
        dst[2] = ysr[i2][q2 * 3 + 2];
    }
}

// ---------------------------------------------------------------------------
// K6: y = y * silu(z); RMSNorm over 768; * norm_w.  Writes split-bf16 output.
// ---------------------------------------------------------------------------
__global__ __launch_bounds__(256) void gate_norm_kernel(
    const float* __restrict__ zx, const float* __restrict__ norm_w,
    const float* __restrict__ y,
    unsigned short* __restrict__ yh, unsigned short* __restrict__ yl)
{
    int bl = blockIdx.x;
    int t  = threadIdx.x;
    const float* zrow = zx + (size_t)bl * D_IN_PROJ;
    const float* yrow = y + (size_t)bl * D_INNER;

    float v[3];
    float ss = 0.f;
    #pragma unroll
    for (int j = 0; j < 3; ++j) {
        int i = t + j * 256;
        float z = zrow[i];
        float s = z / (1.f + expf(-z));
        float val = yrow[i] * s;
        v[j] = val;
        ss += val * val;
    }
    ss += __shfl_xor(ss, 32);
    ss += __shfl_xor(ss, 16);
    ss += __shfl_xor(ss, 8);
    ss += __shfl_xor(ss, 4);
    ss += __shfl_xor(ss, 2);
    ss += __shfl_xor(ss, 1);
    __shared__ float red[4];
    int lane = t & 63, wid = t >> 6;
    if (lane == 0) red[wid] = ss;
    __syncthreads();
    float tot = red[0] + red[1] + red[2] + red[3];
    float rs = rsqrtf(tot * (1.f / D_INNER) + 1e-5f);
    #pragma unroll
    for (int j = 0; j < 3; ++j) {
        int i = t + j * 256;
        float o = v[j] * rs * norm_w[i];
        unsigned short h = f2bf(o);
        yh[(size_t)bl * D_INNER + i] = h;
        yl[(size_t)bl * D_INNER + i] = f2bf(o - bf2f(h));
    }
}

// ---------------------------------------------------------------------------
extern "C" void kernel_launch(void* const* d_in, const int* in_sizes, int n_in,
                              void* d_out, int out_size, void* d_ws, size_t ws_size,
                              hipStream_t stream)
{
    const float* x           = (const float*)d_in[0];
    const float* conv_w      = (const float*)d_in[1];
    const float* conv_b      = (const float*)d_in[2];
    const float* in_proj_w   = (const float*)d_in[3];
    const float* dw_conv_w   = (const float*)d_in[4];
    const float* dw_conv_b   = (const float*)d_in[5];
    const float* dt_bias     = (const float*)d_in[6];
    const float* A_log       = (const float*)d_in[7];
    const float* Dp          = (const float*)d_in[8];
    const float* norm_w      = (const float*)d_in[9];
    const float* mamba_out_w = (const float*)d_in[10];
    const float* out_conv_w  = (const float*)d_in[11];
    float* out = (float*)d_out;
    float* ws  = (float*)d_ws;

    // ---- workspace layout (floats) ----
    float* S0   = ws;                        //  2,097,152  Gbuf+Sloc / late: cow
    float* zx   = S0 + 2097152;              // 14,942,208  early: xT+cw / late: tmpP+mow
    float* xBCs = zx + 14942208;             //  6,553,600  early: ipw / late: yb
    float* dtb  = xBCs + 6553600;            //  2,097,152
    float* ybuf = dtb + 2097152;             //  6,291,456  early: prodA+u

    float* Gbuf = S0;                        // 524,288
    float* Sloc = S0 + 524288;               // 1,572,864
    unsigned short* cow_hi = (unsigned short*)S0;
    unsigned short* cow_lo = (unsigned short*)(S0 + 65536);

    unsigned short* xT_hi = (unsigned short*)zx;
    unsigned short* xT_lo = (unsigned short*)(zx + 525056);
    unsigned short* cw_hi = (unsigned short*)(zx + 1050112);
    unsigned short* cw_lo = (unsigned short*)(zx + 1115648);
    unsigned short* tmpP_hi = (unsigned short*)zx;
    unsigned short* tmpP_lo = (unsigned short*)(zx + 1050112);
    unsigned short* mow_hi  = (unsigned short*)(zx + 2100224);
    unsigned short* mow_lo  = (unsigned short*)(zx + 2198528);

    unsigned short* ipw_hi = (unsigned short*)xBCs;
    unsigned short* ipw_lo = (unsigned short*)(xBCs + 233472);
    unsigned short* yb_hi  = (unsigned short*)xBCs;
    unsigned short* yb_lo  = (unsigned short*)(xBCs + 3145728);

    float* prodA = ybuf;
    unsigned short* u_hi = (unsigned short*)(ybuf + 32768);
    unsigned short* u_lo = (unsigned short*)(ybuf + 32768 + 1048576);

    // ---- 1. conv_in as GEMM ----
    zero_pads_kernel<<<6, 256, 0, stream>>>(xT_hi, xT_lo, IN_DIM);
    transpose_x_kernel<<<dim3(L_ / 32, IN_DIM / 32, B_), 256, 0, stream>>>(
        x, xT_hi, xT_lo);
    prep_cw_kernel<<<512, 256, 0, stream>>>(conv_w, cw_hi, cw_lo);
    gemm_ci_kernel<<<dim3(2, (B_ * L_) / 128), 256, 0, stream>>>(
        xT_hi, xT_lo, cw_hi, cw_lo, conv_b, u_hi, u_lo);

    // ---- 2. in_proj GEMM ----
    tconv_kernel<<<dim3(D_IN_PROJ / 32, D_MODEL / 32), 256, 0, stream>>>(
        in_proj_w, ipw_hi, ipw_lo, D_MODEL, D_IN_PROJ);
    gemm_bf16s_kernel<<<dim3((D_IN_PROJ + 127) / 128, (B_ * L_) / 128), 256, 0, stream>>>(
        u_hi, u_lo, ipw_hi, ipw_lo, zx, B_ * L_, D_IN_PROJ, D_MODEL);

    // ---- 3. elementwise + scan ----
    dt_kernel<<<(B_ * L_ * NHEADS) / 256, 256, 0, stream>>>(zx, dt_bias, dtb);
    dwconv_kernel<<<(B_ * (L_ / 8) * CONV_DIM) / 256, 256, 0, stream>>>(
        zx, dw_conv_w, dw_conv_b, xBCs);
    gmat_kernel<<<B_ * SCAN_NC, 256, 0, stream>>>(xBCs, Gbuf);
    scan_local2<<<B_ * SCAN_NC * (NHEADS / 8), 512, 0, stream>>>(
        xBCs, dtb, A_log, Sloc, prodA);
    scan_prefix_kernel<<<(B_ * NHEADS) / 4, 256, 0, stream>>>(Sloc, prodA);
    scan_final2<<<B_ * SCAN_NC * (NHEADS / 8), 512, 0, stream>>>(
        xBCs, dtb, A_log, Dp, Sloc, Gbuf, ybuf);

    // ---- 4. gate + norm (reads zx z-cols; last use of zx) ----
    gate_norm_kernel<<<B_ * L_, 256, 0, stream>>>(zx, norm_w, ybuf, yb_hi, yb_lo);

    // ---- 5. mamba_out GEMM -> padded split tmpP ----
    zero_pads_kernel<<<12, 256, 0, stream>>>(tmpP_hi, tmpP_lo, D_MODEL);
    prep_cow_kernel<<<512, 256, 0, stream>>>(out_conv_w, cow_hi, cow_lo);
    tconv_kernel<<<dim3(D_MODEL / 32, D_INNER / 32), 256, 0, stream>>>(
        mamba_out_w, mow_hi, mow_lo, D_INNER, D_MODEL);
    gemm_mo_kernel<<<dim3(2, (B_ * L_) / 128), 256, 0, stream>>>(
        yb_hi, yb_lo, mow_hi, mow_lo, tmpP_hi, tmpP_lo);

    // ---- 6. conv_out as full-K GEMM (64 blocks, regular stores) ----
    gemm_co_kernel<<<dim3(1, (B_ * L_) / 128), 256, 0, stream>>>(
        tmpP_hi, tmpP_lo, cow_hi, cow_lo, out);
}

// Round 15
// 350.053 us; speedup vs baseline: 1.1367x; 1.0084x over previous
//
#include <hip/hip_runtime.h>
#include <math.h>

#define B_      4
#define L_      2048
#define IN_DIM  128
#define D_MODEL 256
#define OUT_DIM 128
#define D_STATE 16
#define D_INNER 768
#define NHEADS  256
#define HEADDIM 3
#define CONV_DIM 800
#define D_IN_PROJ 1824

#define SCAN_NC 32
#define SCAN_CL 64
#define LPAD    2051        // L_ + 3 padded rows (row0 = left pad, rows 2049/2050 = right pad)

typedef short  short8 __attribute__((ext_vector_type(8)));
typedef float  f32x4  __attribute__((ext_vector_type(4)));

__device__ __forceinline__ unsigned short f2bf(float f) {
    unsigned int u = __float_as_uint(f);
    u = (u + 0x7fffu + ((u >> 16) & 1u)) >> 16;     // RN-to-even
    return (unsigned short)u;
}
__device__ __forceinline__ float bf2f(unsigned short h) {
    return __uint_as_float(((unsigned int)h) << 16);
}

// ---------------------------------------------------------------------------
// zero the 3 pad rows per batch of a padded split-bf16 tensor [B][LPAD][pitch]
// ---------------------------------------------------------------------------
__global__ __launch_bounds__(256) void zero_pads_kernel(
    unsigned short* __restrict__ ph, unsigned short* __restrict__ pl, int pitch)
{
    int t = blockIdx.x * 256 + threadIdx.x;
    int n = B_ * 3 * pitch;
    if (t < n) {
        int ch = t % pitch, rb = t / pitch;
        int b = rb / 3, ri = rb % 3;
        int row = (ri == 0) ? 0 : (ri == 1) ? (L_ + 1) : (L_ + 2);
        size_t off = ((size_t)b * LPAD + row) * pitch + ch;
        ph[off] = 0; pl[off] = 0;
    }
}

// ---------------------------------------------------------------------------
// transpose x [b][i][L] fp32 -> padded split-bf16 xT [b][LPAD][128], row l+1
// ---------------------------------------------------------------------------
__global__ __launch_bounds__(256) void transpose_x_kernel(
    const float* __restrict__ x, unsigned short* __restrict__ xh,
    unsigned short* __restrict__ xl)
{
    __shared__ float tile[32][33];
    int b = blockIdx.z;
    int l0 = blockIdx.x * 32, i0 = blockIdx.y * 32;
    int tx = threadIdx.x & 31, ty = threadIdx.x >> 5;   // ty 0..7
    const float* xb = x + (size_t)b * IN_DIM * L_;
    #pragma unroll
    for (int r = 0; r < 4; ++r)
        tile[ty + r * 8][tx] = xb[(size_t)(i0 + ty + r * 8) * L_ + l0 + tx];
    __syncthreads();
    #pragma unroll
    for (int r = 0; r < 4; ++r) {
        int l = l0 + ty + r * 8;
        float v = tile[tx][ty + r * 8];                  // x[b][i0+tx][l]
        size_t off = ((size_t)b * LPAD + l + 1) * IN_DIM + i0 + tx;
        unsigned short h = f2bf(v);
        xh[off] = h;
        xl[off] = f2bf(v - bf2f(h));
    }
}

// ---------------------------------------------------------------------------
// reindex+split conv_w [256][128][4] -> cw [256][512], kk = k*128+i
// ---------------------------------------------------------------------------
__global__ __launch_bounds__(256) void prep_cw_kernel(
    const float* __restrict__ w, unsigned short* __restrict__ wh,
    unsigned short* __restrict__ wl)
{
    int t = blockIdx.x * 256 + threadIdx.x;              // 256*512
    if (t < D_MODEL * 512) {
        int o = t >> 9, kk = t & 511;
        int k = kk >> 7, i = kk & 127;
        float v = w[((size_t)o * IN_DIM + i) * 4 + k];
        unsigned short h = f2bf(v);
        wh[t] = h; wl[t] = f2bf(v - bf2f(h));
    }
}

// ---------------------------------------------------------------------------
// reindex+split out_conv_w [128][256][4] -> cow [128][1024], kk = k*256+c
// ---------------------------------------------------------------------------
__global__ __launch_bounds__(256) void prep_cow_kernel(
    const float* __restrict__ w, unsigned short* __restrict__ wh,
    unsigned short* __restrict__ wl)
{
    int t = blockIdx.x * 256 + threadIdx.x;              // 128*1024
    if (t < OUT_DIM * 1024) {
        int o = t >> 10, kk = t & 1023;
        int k = kk >> 8, c = kk & 255;
        float v = w[((size_t)o * D_MODEL + c) * 4 + k];
        unsigned short h = f2bf(v);
        wh[t] = h; wl[t] = f2bf(v - bf2f(h));
    }
}

// ---------------------------------------------------------------------------
// transpose + split: src[K][N] fp32 -> dh/dl [N][K] bf16  (weight prep)
// ---------------------------------------------------------------------------
__global__ __launch_bounds__(256) void tconv_kernel(
    const float* __restrict__ src, unsigned short* __restrict__ dh,
    unsigned short* __restrict__ dl, int K, int N)
{
    __shared__ float tile[32][33];
    int k0 = blockIdx.y * 32, n0 = blockIdx.x * 32;
    int tx = threadIdx.x & 31, ty = threadIdx.x >> 5;
    #pragma unroll
    for (int r = 0; r < 4; ++r)
        tile[ty + r * 8][tx] = src[(size_t)(k0 + ty + r * 8) * N + n0 + tx];
    __syncthreads();
    #pragma unroll
    for (int r = 0; r < 4; ++r) {
        int n = n0 + ty + r * 8;
        float v = tile[tx][ty + r * 8];
        unsigned short h = f2bf(v);
        dh[(size_t)n * K + k0 + tx] = h;
        dl[(size_t)n * K + k0 + tx] = f2bf(v - bf2f(h));
    }
}

// ---------------------------------------------------------------------------
// K2: split-bf16 MFMA GEMM (generic).  C[M,N] fp32 = (Ah+Al)[M,K]*(Bh+Bl)^T
// ---------------------------------------------------------------------------
__global__ __launch_bounds__(256) void gemm_bf16s_kernel(
    const unsigned short* __restrict__ Ah, const unsigned short* __restrict__ Al,
    const unsigned short* __restrict__ Bh, const unsigned short* __restrict__ Bl,
    float* __restrict__ C, int M, int N, int K)
{
    __shared__ __align__(16) unsigned short AsH[128][40];
    __shared__ __align__(16) unsigned short AsL[128][40];
    __shared__ __align__(16) unsigned short BsH[128][40];
    __shared__ __align__(16) unsigned short BsL[128][40];

    int m0 = blockIdx.y * 128, n0 = blockIdx.x * 128;
    int t = threadIdx.x;
    int wid = t >> 6, lane = t & 63;
    int wm = (wid >> 1) * 64, wn = (wid & 1) * 64;
    int fr = lane & 15, fq = lane >> 4;

    f32x4 z4 = {0.f, 0.f, 0.f, 0.f};
    f32x4 acc[4][4];
    #pragma unroll
    for (int i = 0; i < 4; ++i)
        #pragma unroll
        for (int j = 0; j < 4; ++j) acc[i][j] = z4;

    for (int k0 = 0; k0 < K; k0 += 32) {
        __syncthreads();
        #pragma unroll
        for (int p = 0; p < 2; ++p) {
            int idx = p * 256 + t;
            int row = idx >> 2, q = idx & 3;
            int koff = k0 + q * 8;
            *(float4*)&AsH[row][q * 8] =
                *(const float4*)(Ah + (size_t)(m0 + row) * K + koff);
            *(float4*)&AsL[row][q * 8] =
                *(const float4*)(Al + (size_t)(m0 + row) * K + koff);
            int n = n0 + row;
            float4 vbh = make_float4(0.f, 0.f, 0.f, 0.f), vbl = vbh;
            if (n < N) {
                vbh = *(const float4*)(Bh + (size_t)n * K + koff);
                vbl = *(const float4*)(Bl + (size_t)n * K + koff);
            }
            *(float4*)&BsH[row][q * 8] = vbh;
            *(float4*)&BsL[row][q * 8] = vbl;
        }
        __syncthreads();

        short8 ah[4], al[4], bh[4], bl[4];
        #pragma unroll
        for (int i = 0; i < 4; ++i) {
            ah[i] = *(const short8*)&AsH[wm + i * 16 + fr][fq * 8];
            al[i] = *(const short8*)&AsL[wm + i * 16 + fr][fq * 8];
            bh[i] = *(const short8*)&BsH[wn + i * 16 + fr][fq * 8];
            bl[i] = *(const short8*)&BsL[wn + i * 16 + fr][fq * 8];
        }
        #pragma unroll
        for (int i = 0; i < 4; ++i)
            #pragma unroll
            for (int j = 0; j < 4; ++j) {
                acc[i][j] = __builtin_amdgcn_mfma_f32_16x16x32_bf16(
                    ah[i], bh[j], acc[i][j], 0, 0, 0);
                acc[i][j] = __builtin_amdgcn_mfma_f32_16x16x32_bf16(
                    ah[i], bl[j], acc[i][j], 0, 0, 0);
                acc[i][j] = __builtin_amdgcn_mfma_f32_16x16x32_bf16(
                    al[i], bh[j], acc[i][j], 0, 0, 0);
            }
    }

    #pragma unroll
    for (int i = 0; i < 4; ++i) {
        int r0 = m0 + wm + i * 16 + fq * 4;
        #pragma unroll
        for (int j = 0; j < 4; ++j) {
            int cc = n0 + wn + j * 16 + fr;
            if (cc < N) {
                #pragma unroll
                for (int r = 0; r < 4; ++r)
                    C[(size_t)(r0 + r) * N + cc] = acc[i][j][r];
            }
        }
    }
}

// ---------------------------------------------------------------------------
// conv_in as GEMM: A = xT window, B = cw [256][512]. Epilogue: + conv_b,
// write split-bf16 u [8192][256].
// ---------------------------------------------------------------------------
__global__ __launch_bounds__(256) void gemm_ci_kernel(
    const unsigned short* __restrict__ Ah, const unsigned short* __restrict__ Al,
    const unsigned short* __restrict__ Bh, const unsigned short* __restrict__ Bl,
    const float* __restrict__ bias,
    unsigned short* __restrict__ Ch, unsigned short* __restrict__ Cl)
{
    const int K = 512;
    __shared__ __align__(16) unsigned short AsH[128][40];
    __shared__ __align__(16) unsigned short AsL[128][40];
    __shared__ __align__(16) unsigned short BsH[128][40];
    __shared__ __align__(16) unsigned short BsL[128][40];

    int m0 = blockIdx.y * 128, n0 = blockIdx.x * 128;
    int b = m0 >> 11;
    size_t abase = ((size_t)b * LPAD + (m0 & 2047)) * IN_DIM;
    int t = threadIdx.x;
    int wid = t >> 6, lane = t & 63;
    int wm = (wid >> 1) * 64, wn = (wid & 1) * 64;
    int fr = lane & 15, fq = lane >> 4;

    f32x4 z4 = {0.f, 0.f, 0.f, 0.f};
    f32x4 acc[4][4];
    #pragma unroll
    for (int i = 0; i < 4; ++i)
        #pragma unroll
        for (int j = 0; j < 4; ++j) acc[i][j] = z4;

    for (int k0 = 0; k0 < K; k0 += 32) {
        __syncthreads();
        #pragma unroll
        for (int p = 0; p < 2; ++p) {
            int idx = p * 256 + t;
            int row = idx >> 2, q = idx & 3;
            int koff = k0 + q * 8;
            *(float4*)&AsH[row][q * 8] =
                *(const float4*)(Ah + abase + (size_t)row * IN_DIM + koff);
            *(float4*)&AsL[row][q * 8] =
                *(const float4*)(Al + abase + (size_t)row * IN_DIM + koff);
            int n = n0 + row;
            *(float4*)&BsH[row][q * 8] = *(const float4*)(Bh + (size_t)n * K + koff);
            *(float4*)&BsL[row][q * 8] = *(const float4*)(Bl + (size_t)n * K + koff);
        }
        __syncthreads();

        short8 ah[4], al[4], bh[4], bl[4];
        #pragma unroll
        for (int i = 0; i < 4; ++i) {
            ah[i] = *(const short8*)&AsH[wm + i * 16 + fr][fq * 8];
            al[i] = *(const short8*)&AsL[wm + i * 16 + fr][fq * 8];
            bh[i] = *(const short8*)&BsH[wn + i * 16 + fr][fq * 8];
            bl[i] = *(const short8*)&BsL[wn + i * 16 + fr][fq * 8];
        }
        #pragma unroll
        for (int i = 0; i < 4; ++i)
            #pragma unroll
            for (int j = 0; j < 4; ++j) {
                acc[i][j] = __builtin_amdgcn_mfma_f32_16x16x32_bf16(
                    ah[i], bh[j], acc[i][j], 0, 0, 0);
                acc[i][j] = __builtin_amdgcn_mfma_f32_16x16x32_bf16(
                    ah[i], bl[j], acc[i][j], 0, 0, 0);
                acc[i][j] = __builtin_amdgcn_mfma_f32_16x16x32_bf16(
                    al[i], bh[j], acc[i][j], 0, 0, 0);
            }
    }

    #pragma unroll
    for (int i = 0; i < 4; ++i) {
        int r0 = m0 + wm + i * 16 + fq * 4;
        #pragma unroll
        for (int j = 0; j < 4; ++j) {
            int cc = n0 + wn + j * 16 + fr;
            float bc = bias[cc];
            #pragma unroll
            for (int r = 0; r < 4; ++r) {
                float v = acc[i][j][r] + bc;
                unsigned short h = f2bf(v);
                size_t off = (size_t)(r0 + r) * D_MODEL + cc;
                Ch[off] = h;
                Cl[off] = f2bf(v - bf2f(h));
            }
        }
    }
}

// ---------------------------------------------------------------------------
// gemm2 (mamba_out) with split-bf16 PADDED output: row m=(b,l) -> padded row
// b*LPAD + l + 1 of tmpP [.][256].
// ---------------------------------------------------------------------------
__global__ __launch_bounds__(256) void gemm_mo_kernel(
    const unsigned short* __restrict__ Ah, const unsigned short* __restrict__ Al,
    const unsigned short* __restrict__ Bh, const unsigned short* __restrict__ Bl,
    unsigned short* __restrict__ Ch, unsigned short* __restrict__ Cl)
{
    const int K = D_INNER, N = D_MODEL;
    __shared__ __align__(16) unsigned short AsH[128][40];
    __shared__ __align__(16) unsigned short AsL[128][40];
    __shared__ __align__(16) unsigned short BsH[128][40];
    __shared__ __align__(16) unsigned short BsL[128][40];

    int m0 = blockIdx.y * 128, n0 = blockIdx.x * 128;
    int t = threadIdx.x;
    int wid = t >> 6, lane = t & 63;
    int wm = (wid >> 1) * 64, wn = (wid & 1) * 64;
    int fr = lane & 15, fq = lane >> 4;

    f32x4 z4 = {0.f, 0.f, 0.f, 0.f};
    f32x4 acc[4][4];
    #pragma unroll
    for (int i = 0; i < 4; ++i)
        #pragma unroll
        for (int j = 0; j < 4; ++j) acc[i][j] = z4;

    for (int k0 = 0; k0 < K; k0 += 32) {
        __syncthreads();
        #pragma unroll
        for (int p = 0; p < 2; ++p) {
            int idx = p * 256 + t;
            int row = idx >> 2, q = idx & 3;
            int koff = k0 + q * 8;
            *(float4*)&AsH[row][q * 8] =
                *(const float4*)(Ah + (size_t)(m0 + row) * K + koff);
            *(float4*)&AsL[row][q * 8] =
                *(const float4*)(Al + (size_t)(m0 + row) * K + koff);
            int n = n0 + row;
            *(float4*)&BsH[row][q * 8] = *(const float4*)(Bh + (size_t)n * K + koff);
            *(float4*)&BsL[row][q * 8] = *(const float4*)(Bl + (size_t)n * K + koff);
        }
        __syncthreads();

        short8 ah[4], al[4], bh[4], bl[4];
        #pragma unroll
        for (int i = 0; i < 4; ++i) {
            ah[i] = *(const short8*)&AsH[wm + i * 16 + fr][fq * 8];
            al[i] = *(const short8*)&AsL[wm + i * 16 + fr][fq * 8];
            bh[i] = *(const short8*)&BsH[wn + i * 16 + fr][fq * 8];
            bl[i] = *(const short8*)&BsL[wn + i * 16 + fr][fq * 8];
        }
        #pragma unroll
        for (int i = 0; i < 4; ++i)
            #pragma unroll
            for (int j = 0; j < 4; ++j) {
                acc[i][j] = __builtin_amdgcn_mfma_f32_16x16x32_bf16(
                    ah[i], bh[j], acc[i][j], 0, 0, 0);
                acc[i][j] = __builtin_amdgcn_mfma_f32_16x16x32_bf16(
                    ah[i], bl[j], acc[i][j], 0, 0, 0);
                acc[i][j] = __builtin_amdgcn_mfma_f32_16x16x32_bf16(
                    al[i], bh[j], acc[i][j], 0, 0, 0);
            }
    }

    int b = m0 >> 11;
    #pragma unroll
    for (int i = 0; i < 4; ++i) {
        int r0 = m0 + wm + i * 16 + fq * 4;
        #pragma unroll
        for (int j = 0; j < 4; ++j) {
            int cc = n0 + wn + j * 16 + fr;
            #pragma unroll
            for (int r = 0; r < 4; ++r) {
                int l = (r0 + r) & 2047;
                float v = acc[i][j][r];
                unsigned short h = f2bf(v);
                size_t off = ((size_t)b * LPAD + l + 1) * D_MODEL + cc;
                Ch[off] = h;
                Cl[off] = f2bf(v - bf2f(h));
            }
        }
    }
}

// ---------------------------------------------------------------------------
// conv_out as GEMM, full-K (no split, no atomics): A = tmpP window
// [(b*LPAD+l)*256, 1024 contiguous], B = cow [128][1024]. 64 blocks.
// ---------------------------------------------------------------------------
__global__ __launch_bounds__(256) void gemm_co_kernel(
    const unsigned short* __restrict__ Ah, const unsigned short* __restrict__ Al,
    const unsigned short* __restrict__ Bh, const unsigned short* __restrict__ Bl,
    float* __restrict__ out)
{
    const int K = 1024;
    __shared__ __align__(16) unsigned short AsH[128][40];
    __shared__ __align__(16) unsigned short AsL[128][40];
    __shared__ __align__(16) unsigned short BsH[128][40];
    __shared__ __align__(16) unsigned short BsL[128][40];

    int m0 = blockIdx.y * 128;
    int b = m0 >> 11, l0t = m0 & 2047;
    size_t abase = ((size_t)b * LPAD + l0t) * D_MODEL;
    int t = threadIdx.x;
    int wid = t >> 6, lane = t & 63;
    int wm = (wid >> 1) * 64, wn = (wid & 1) * 64;
    int fr = lane & 15, fq = lane >> 4;

    f32x4 z4 = {0.f, 0.f, 0.f, 0.f};
    f32x4 acc[4][4];
    #pragma unroll
    for (int i = 0; i < 4; ++i)
        #pragma unroll
        for (int j = 0; j < 4; ++j) acc[i][j] = z4;

    for (int k0 = 0; k0 < K; k0 += 32) {
        __syncthreads();
        #pragma unroll
        for (int p = 0; p < 2; ++p) {
            int idx = p * 256 + t;
            int row = idx >> 2, q = idx & 3;
            int koff = k0 + q * 8;
            *(float4*)&AsH[row][q * 8] =
                *(const float4*)(Ah + abase + (size_t)row * D_MODEL + koff);
            *(float4*)&AsL[row][q * 8] =
                *(const float4*)(Al + abase + (size_t)row * D_MODEL + koff);
            *(float4*)&BsH[row][q * 8] = *(const float4*)(Bh + (size_t)row * K + koff);
            *(float4*)&BsL[row][q * 8] = *(const float4*)(Bl + (size_t)row * K + koff);
        }
        __syncthreads();

        short8 ah[4], al[4], bh[4], bl[4];
        #pragma unroll
        for (int i = 0; i < 4; ++i) {
            ah[i] = *(const short8*)&AsH[wm + i * 16 + fr][fq * 8];
            al[i] = *(const short8*)&AsL[wm + i * 16 + fr][fq * 8];
            bh[i] = *(const short8*)&BsH[wn + i * 16 + fr][fq * 8];
            bl[i] = *(const short8*)&BsL[wn + i * 16 + fr][fq * 8];
        }
        #pragma unroll
        for (int i = 0; i < 4; ++i)
            #pragma unroll
            for (int j = 0; j < 4; ++j) {
                acc[i][j] = __builtin_amdgcn_mfma_f32_16x16x32_bf16(
                    ah[i], bh[j], acc[i][j], 0, 0, 0);
                acc[i][j] = __builtin_amdgcn_mfma_f32_16x16x32_bf16(
                    ah[i], bl[j], acc[i][j], 0, 0, 0);
                acc[i][j] = __builtin_amdgcn_mfma_f32_16x16x32_bf16(
                    al[i], bh[j], acc[i][j], 0, 0, 0);
            }
    }

    #pragma unroll
    for (int i = 0; i < 4; ++i) {
        int lr = l0t + wm + i * 16 + fq * 4;
        #pragma unroll
        for (int j = 0; j < 4; ++j) {
            int cc = wn + j * 16 + fr;                  // o in 0..127
            float* dst = out + ((size_t)(b * OUT_DIM + cc)) * L_ + lr;
            float4 ov = make_float4(acc[i][j][0], acc[i][j][1],
                                    acc[i][j][2], acc[i][j][3]);
            *(float4*)dst = ov;
        }
    }
}

// ---------------------------------------------------------------------------
// K3: dt = softplus(dt_raw + dt_bias)    [B*L, 256]
// ---------------------------------------------------------------------------
__global__ __launch_bounds__(256) void dt_kernel(
    const float* __restrict__ zx, const float* __restrict__ dt_bias,
    float* __restrict__ dtb)
{
    int idx = blockIdx.x * 256 + threadIdx.x;
    int h  = idx & 255;
    int bl = idx >> 8;
    float v = zx[(size_t)bl * D_IN_PROJ + (D_INNER + CONV_DIM) + h] + dt_bias[h];
    float sp = (v > 20.f) ? v : log1pf(expf(v));
    dtb[idx] = sp;
}

// ---------------------------------------------------------------------------
// K4: causal depthwise conv + bias + SiLU. 8 l-values per thread.
// ---------------------------------------------------------------------------
__global__ __launch_bounds__(256) void dwconv_kernel(
    const float* __restrict__ zx, const float* __restrict__ w,
    const float* __restrict__ bias, float* __restrict__ xBCs)
{
    int idx = blockIdx.x * 256 + threadIdx.x;   // over B * L/8 * 800
    int c   = idx % CONV_DIM;
    int bl8 = idx / CONV_DIM;
    int b  = bl8 >> 8;               // L/8 = 256
    int l0 = (bl8 & 255) * 8;
    float4 wv = *(const float4*)&w[c * 4];
    float bi = bias[c];
    const float* base = zx + ((size_t)(b * L_ + l0)) * D_IN_PROJ + D_INNER + c;
    float r[11];
    #pragma unroll
    for (int k = 0; k < 11; ++k) {
        int l = l0 - 3 + k;
        r[k] = (l >= 0) ? base[(ptrdiff_t)(k - 3) * D_IN_PROJ] : 0.f;
    }
    #pragma unroll
    for (int i = 0; i < 8; ++i) {
        float acc = bi;
        acc = fmaf(r[i + 0], wv.x, acc);
        acc = fmaf(r[i + 1], wv.y, acc);
        acc = fmaf(r[i + 2], wv.z, acc);
        acc = fmaf(r[i + 3], wv.w, acc);
        float s = acc / (1.f + expf(-acc));
        xBCs[((size_t)(b * L_ + l0 + i)) * CONV_DIM + c] = s;
    }
}

// ---------------------------------------------------------------------------
// K5g: G[i][j] = C_i . B_j  per (b,chunk).  bid = b*32+c -> XCD = c%8,
// matching the scan swizzle (bc & 7) so G stays in the producing XCD's L2.
// ---------------------------------------------------------------------------
__global__ __launch_bounds__(256) void gmat_kernel(
    const float* __restrict__ xBCs, float* __restrict__ G)
{
    __shared__ float Bs[64][16];
    __shared__ float Cs[64][16];
    int c = blockIdx.x & 31, b = blockIdx.x >> 5;
    int t = threadIdx.x;
    int row0 = b * L_ + c * SCAN_CL;
    {
        int j = t >> 2, q = t & 3;
        const float* r = xBCs + (size_t)(row0 + j) * CONV_DIM + D_INNER;
        *(float4*)&Bs[j][q * 4] = *(const float4*)(r + q * 4);
        *(float4*)&Cs[j][q * 4] = *(const float4*)(r + D_STATE + q * 4);
    }
    __syncthreads();
    int i = t >> 2, jq = t & 3;
    float4 c0 = *(const float4*)&Cs[i][0];
    float4 c1 = *(const float4*)&Cs[i][4];
    float4 c2 = *(const float4*)&Cs[i][8];
    float4 c3 = *(const float4*)&Cs[i][12];
    float dot[16];
    #pragma unroll
    for (int jj = 0; jj < 16; ++jj) {
        int j = jq * 16 + jj;
        float4 b0 = *(const float4*)&Bs[j][0];
        float4 b1 = *(const float4*)&Bs[j][4];
        float4 b2 = *(const float4*)&Bs[j][8];
        float4 b3 = *(const float4*)&Bs[j][12];
        float d = c0.x * b0.x + c0.y * b0.y + c0.z * b0.z + c0.w * b0.w;
        d = fmaf(c1.x, b1.x, d); d = fmaf(c1.y, b1.y, d);
        d = fmaf(c1.z, b1.z, d); d = fmaf(c1.w, b1.w, d);
        d = fmaf(c2.x, b2.x, d); d = fmaf(c2.y, b2.y, d);
        d = fmaf(c2.z, b2.z, d); d = fmaf(c2.w, b2.w, d);
        d = fmaf(c3.x, b3.x, d); d = fmaf(c3.y, b3.y, d);
        d = fmaf(c3.z, b3.z, d); d = fmaf(c3.w, b3.w, d);
        dot[jj] = d;
    }
    float* gout = G + ((size_t)blockIdx.x * 64 + i) * 64 + jq * 16;
    #pragma unroll
    for (int q = 0; q < 4; ++q)
        *(float4*)(gout + q * 4) = make_float4(dot[q*4], dot[q*4+1], dot[q*4+2], dot[q*4+3]);
}

// ---------------------------------------------------------------------------
// XCD-locality swizzle: all 32 hg blocks of one (b,c) share bid%8 -> same XCD
// bid = (bc>>3)<<8 | hg<<3 | (bc&7);  bc = b*32+c.
// ---------------------------------------------------------------------------
__device__ __forceinline__ void scan_decode(int bid, int& b, int& c, int& hg)
{
    int bcl = bid & 7;
    hg = (bid >> 3) & 31;
    int bc = ((bid >> 8) << 3) | bcl;
    c = bc & 31;
    b = bc >> 5;
}

// ---------------------------------------------------------------------------
// K5a: chunk-local state build. 512 threads = 8 waves; ONE head per wave.
// Pk in SoA (stride 66) to avoid LDS bank conflicts.
// ---------------------------------------------------------------------------
__global__ __launch_bounds__(512) void scan_local2(
    const float* __restrict__ xBCs, const float* __restrict__ dtb,
    const float* __restrict__ A_log,
    float* __restrict__ Sloc, float* __restrict__ prodA)
{
    __shared__ float  BsT[16][68];          // [n][row], padded
    __shared__ float  Pk0[8][66], Pk1[8][66], Pk2[8][66], Pkw[8][66];
    __shared__ float  UT[8][3][64];
    int b, c, hg;
    scan_decode(blockIdx.x, b, c, hg);
    int h0 = hg * 8;
    int t = threadIdx.x;
    int row0 = b * L_ + c * SCAN_CL;

    if (t < 256) {   // B tile (coalesced)
        int j = t >> 2, q = t & 3;
        const float* r = xBCs + (size_t)(row0 + j) * CONV_DIM;
        float4 bv = *(const float4*)(r + D_INNER + q * 4);
        BsT[q*4+0][j] = bv.x; BsT[q*4+1][j] = bv.y;
        BsT[q*4+2][j] = bv.z; BsT[q*4+3][j] = bv.w;
    }
    {   // Pk staging: one entry per thread (dense per row); SoA writes
        int hh = t & 7, j = t >> 3;
        float dtv = dtb[(size_t)(row0 + j) * NHEADS + h0 + hh];
        const float* xr = xBCs + (size_t)(row0 + j) * CONV_DIM + (h0 + hh) * 3;
        Pk0[hh][j] = dtv * xr[0];
        Pk1[hh][j] = dtv * xr[1];
        Pk2[hh][j] = dtv * xr[2];
        Pkw[hh][j] = dtv;
    }
    __syncthreads();

    int wv = t >> 6, lane = t & 63;
    int hh = wv;
    int h = h0 + hh;
    int p = lane >> 4, n = lane & 15;
    int pc = (p < 3) ? p : 2;

    float pkx = Pk0[hh][lane], pky = Pk1[hh][lane], pkz = Pk2[hh][lane];
    float pkw = Pkw[hh][lane];
    float A = -__expf(A_log[h]);
    float cum = pkw * A;
    #pragma unroll
    for (int off = 1; off < 64; off <<= 1) {
        float sv = __shfl_up(cum, off);
        if (lane >= off) cum += sv;
    }
    float cum63 = __shfl(cum, 63);
    float wf = __expf(cum63 - cum);
    UT[hh][0][lane] = wf * pkx;
    UT[hh][1][lane] = wf * pky;
    UT[hh][2][lane] = wf * pkz;
    float state = 0.f;
    #pragma unroll
    for (int q = 0; q < 16; ++q) {
        float4 Bv = *(const float4*)&BsT[n][q * 4];
        float4 Uv = *(const float4*)&UT[hh][pc][q * 4];
        state = fmaf(Uv.x, Bv.x, state);
        state = fmaf(Uv.y, Bv.y, state);
        state = fmaf(Uv.z, Bv.z, state);
        state = fmaf(Uv.w, Bv.w, state);
    }
    size_t bh = (size_t)(b * NHEADS + h);
    if (p < 3) Sloc[(bh * SCAN_NC + c) * 48 + p * 16 + n] = state;
    if (lane == 0) prodA[bh * SCAN_NC + c] = __expf(cum63);
}

// ---------------------------------------------------------------------------
// K5b: sequential prefix over chunks, in place on Sloc
// ---------------------------------------------------------------------------
__global__ __launch_bounds__(256) void scan_prefix_kernel(
    float* __restrict__ Sloc, const float* __restrict__ prodA)
{
    int wv   = blockIdx.x * 4 + (threadIdx.x >> 6);
    int lane = threadIdx.x & 63;
    int p = lane >> 4, n = lane & 15;
    bool act = (p < 3);
    int l48 = ((p < 3) ? p : 2) * 16 + n;
    size_t base = (size_t)wv * SCAN_NC;

    float cur = 0.f;
    for (int c = 0; c < SCAN_NC; ++c) {
        float s  = Sloc[(base + c) * 48 + l48];
        float pa = prodA[base + c];
        if (act) Sloc[(base + c) * 48 + l48] = cur;
        cur = fmaf(pa, cur, s);
    }
}

// ---------------------------------------------------------------------------
// K5c: chunk-matmul final scan. 512 threads = 8 waves; ONE head per wave.
// G staged in LDS once per block; Pk in SoA (stride 66) -> the diagonal
// gather Pk*[hh][I*16+kk] hits banks 2-way (free) instead of 4-way.
// ---------------------------------------------------------------------------
__global__ __launch_bounds__(512) void scan_final2(
    const float* __restrict__ xBCs, const float* __restrict__ dtb,
    const float* __restrict__ A_log, const float* __restrict__ Dp,
    const float* __restrict__ Sinit, const float* __restrict__ G,
    float* __restrict__ y)
{
    __shared__ float  Pk0[8][66], Pk1[8][66], Pk2[8][66], Pkw[8][66];
    __shared__ float4 XW[8][64];
    __shared__ float  Sin[8][48];
    __shared__ float  CsT[16][66];          // [n][row]
    __shared__ float  ysr[64][25];          // [row][24 ch] padded (stride 25)
    __shared__ float  Gs[64][65];           // G tile, odd stride
    int b, c, hg;
    scan_decode(blockIdx.x, b, c, hg);
    int h0 = hg * 8;
    int t = threadIdx.x;
    int row0 = b * L_ + c * SCAN_CL;

    if (t < 256) {   // C tile (coalesced)
        int j = t >> 2, q = t & 3;
        const float* r = xBCs + (size_t)(row0 + j) * CONV_DIM + D_INNER + D_STATE;
        float4 cv = *(const float4*)(r + q * 4);
        CsT[q*4+0][j] = cv.x; CsT[q*4+1][j] = cv.y;
        CsT[q*4+2][j] = cv.z; CsT[q*4+3][j] = cv.w;
    }
    {   // Pk staging: one entry per thread; SoA writes
        int hh = t & 7, j = t >> 3;
        float dtv = dtb[(size_t)(row0 + j) * NHEADS + h0 + hh];
        const float* xr = xBCs + (size_t)(row0 + j) * CONV_DIM + (h0 + hh) * 3;
        Pk0[hh][j] = dtv * xr[0];
        Pk1[hh][j] = dtv * xr[1];
        Pk2[hh][j] = dtv * xr[2];
        Pkw[hh][j] = dtv;
    }
    if (t < 384) {   // Sin staging: 8 heads x 48
        int hh = t / 48, k = t % 48;
        Sin[hh][k] = Sinit[((size_t)(b * NHEADS + h0 + hh) * SCAN_NC + c) * 48 + k];
    }
    {   // G staging: 4096 floats, coalesced float4 global reads
        const float* Gsrc = G + (size_t)(b * SCAN_NC + c) * 4096;
        #pragma unroll
        for (int e = 0; e < 2; ++e) {
            int idx = e * 512 + t;              // float4 index 0..1023
            int row = idx >> 4, cq = (idx & 15) * 4;
            float4 gv = *(const float4*)(Gsrc + (size_t)idx * 4);
            Gs[row][cq + 0] = gv.x;
            Gs[row][cq + 1] = gv.y;
            Gs[row][cq + 2] = gv.z;
            Gs[row][cq + 3] = gv.w;
        }
    }
    __syncthreads();

    int wv = t >> 6, lane = t & 63;
    int hh = wv;
    int h = h0 + hh;
    int I = lane >> 4;

    float pkx = Pk0[hh][lane], pky = Pk1[hh][lane], pkz = Pk2[hh][lane];
    float pkw = Pkw[hh][lane];
    float A = -__expf(A_log[h]);
    float cum = pkw * A;
    #pragma unroll
    for (int off = 1; off < 64; off <<= 1) {
        float sv = __shfl_up(cum, off);
        if (lane >= off) cum += sv;
    }
    float e0 = __shfl(cum, 15);
    float e1 = __shfl(cum, 31);
    float e2 = __shfl(cum, 47);
    float e3 = __shfl(cum, 63);
    int ia = (I << 4) - 1;
    float AIr = __shfl(cum, ia < 0 ? 0 : ia);
    float AI = (I == 0) ? 0.f : AIr;
    float ri = __expf(cum - AI);
    float Eo = (I == 0) ? e0 : (I == 1) ? e1 : (I == 2) ? e2 : e3;
    float wj = __expf(Eo - cum);
    XW[hh][lane] = make_float4(wj * pkx, wj * pky, wj * pkz, 0.f);
    Pkw[hh][lane] = cum;                    // publish cum_j (wave-local)
    float S0 = (I > 0) ? __expf(AI - e0) : 0.f;
    float S1 = (I > 1) ? __expf(AI - e1) : 0.f;
    float S2 = (I > 2) ? __expf(AI - e2) : 0.f;
    float ecum = __expf(cum);

    float acc0 = 0.f, acc1 = 0.f, acc2 = 0.f;
    #pragma unroll
    for (int J = 0; J < 3; ++J) {
        float SJ = (J == 0) ? S0 : (J == 1) ? S1 : S2;
        float t0 = 0.f, t1 = 0.f, t2 = 0.f;
        #pragma unroll
        for (int kk = 0; kk < 16; ++kk) {
            float gk = Gs[lane][J * 16 + kk];
            float4 u = XW[hh][J * 16 + kk];
            t0 = fmaf(gk, u.x, t0);
            t1 = fmaf(gk, u.y, t1);
            t2 = fmaf(gk, u.z, t2);
        }
        acc0 = fmaf(SJ, t0, acc0);
        acc1 = fmaf(SJ, t1, acc1);
        acc2 = fmaf(SJ, t2, acc2);
    }

    float d0 = 0.f, d1 = 0.f, d2 = 0.f;
    #pragma unroll
    for (int kk = 0; kk < 16; ++kk) {
        int j = (I << 4) + kk;
        float gk = Gs[lane][j];
        float e = __expf(cum - Pkw[hh][j]);
        float m = (j <= lane) ? e : 0.f;
        float mg = m * gk;
        d0 = fmaf(mg, Pk0[hh][j], d0);
        d1 = fmaf(mg, Pk1[hh][j], d1);
        d2 = fmaf(mg, Pk2[hh][j], d2);
    }

    float s0 = 0.f, s1 = 0.f, s2 = 0.f;
    #pragma unroll
    for (int nq = 0; nq < 16; ++nq) {
        float Cv = CsT[nq][lane];
        s0 = fmaf(Cv, Sin[hh][nq],      s0);
        s1 = fmaf(Cv, Sin[hh][16 + nq], s1);
        s2 = fmaf(Cv, Sin[hh][32 + nq], s2);
    }

    float rdt = 1.0f / pkw;
    float Dh = Dp[h];
    float* yr = &ysr[lane][hh * 3];
    yr[0] = fmaf(ri, acc0, d0) + fmaf(ecum, s0, Dh * (pkx * rdt));
    yr[1] = fmaf(ri, acc1, d1) + fmaf(ecum, s1, Dh * (pky * rdt));
    yr[2] = fmaf(ri, acc2, d2) + fmaf(ecum, s2, Dh * (pkz * rdt));
    __syncthreads();

    {   // coalesced epilogue: 24 contiguous channels per row
        int i2 = t >> 3, q2 = t & 7;
        float* dst = y + (size_t)(row0 + i2) * D_INNER + hg * 24 + q2 * 3;
        dst[0] = ysr[i2][q2 * 3 + 0];
        dst[1] = ysr[i2][q2 * 3 + 1];
        dst[2] = ysr[i2][q2 * 3 + 2];
    }
}

// ---------------------------------------------------------------------------
// K6: y = y * silu(z); RMSNorm over 768; * norm_w.  Writes split-bf16 output.
// ---------------------------------------------------------------------------
__global__ __launch_bounds__(256) void gate_norm_kernel(
    const float* __restrict__ zx, const float* __restrict__ norm_w,
    const float* __restrict__ y,
    unsigned short* __restrict__ yh, unsigned short* __restrict__ yl)
{
    int bl = blockIdx.x;
    int t  = threadIdx.x;
    const float* zrow = zx + (size_t)bl * D_IN_PROJ;
    const float* yrow = y + (size_t)bl * D_INNER;

    float v[3];
    float ss = 0.f;
    #pragma unroll
    for (int j = 0; j < 3; ++j) {
        int i = t + j * 256;
        float z = zrow[i];
        float s = z / (1.f + expf(-z));
        float val = yrow[i] * s;
        v[j] = val;
        ss += val * val;
    }
    ss += __shfl_xor(ss, 32);
    ss += __shfl_xor(ss, 16);
    ss += __shfl_xor(ss, 8);
    ss += __shfl_xor(ss, 4);
    ss += __shfl_xor(ss, 2);
    ss += __shfl_xor(ss, 1);
    __shared__ float red[4];
    int lane = t & 63, wid = t >> 6;
    if (lane == 0) red[wid] = ss;
    __syncthreads();
    float tot = red[0] + red[1] + red[2] + red[3];
    float rs = rsqrtf(tot * (1.f / D_INNER) + 1e-5f);
    #pragma unroll
    for (int j = 0; j < 3; ++j) {
        int i = t + j * 256;
        float o = v[j] * rs * norm_w[i];
        unsigned short h = f2bf(o);
        yh[(size_t)bl * D_INNER + i] = h;
        yl[(size_t)bl * D_INNER + i] = f2bf(o - bf2f(h));
    }
}

// ---------------------------------------------------------------------------
extern "C" void kernel_launch(void* const* d_in, const int* in_sizes, int n_in,
                              void* d_out, int out_size, void* d_ws, size_t ws_size,
                              hipStream_t stream)
{
    const float* x           = (const float*)d_in[0];
    const float* conv_w      = (const float*)d_in[1];
    const float* conv_b      = (const float*)d_in[2];
    const float* in_proj_w   = (const float*)d_in[3];
    const float* dw_conv_w   = (const float*)d_in[4];
    const float* dw_conv_b   = (const float*)d_in[5];
    const float* dt_bias     = (const float*)d_in[6];
    const float* A_log       = (const float*)d_in[7];
    const float* Dp          = (const float*)d_in[8];
    const float* norm_w      = (const float*)d_in[9];
    const float* mamba_out_w = (const float*)d_in[10];
    const float* out_conv_w  = (const float*)d_in[11];
    float* out = (float*)d_out;
    float* ws  = (float*)d_ws;

    // ---- workspace layout (floats) ----
    float* S0   = ws;                        //  2,097,152  Gbuf+Sloc / late: cow
    float* zx   = S0 + 2097152;              // 14,942,208  early: xT+cw / late: tmpP+mow
    float* xBCs = zx + 14942208;             //  6,553,600  early: ipw / late: yb
    float* dtb  = xBCs + 6553600;            //  2,097,152
    float* ybuf = dtb + 2097152;             //  6,291,456  early: prodA+u

    float* Gbuf = S0;                        // 524,288
    float* Sloc = S0 + 524288;               // 1,572,864
    unsigned short* cow_hi = (unsigned short*)S0;
    unsigned short* cow_lo = (unsigned short*)(S0 + 65536);

    unsigned short* xT_hi = (unsigned short*)zx;
    unsigned short* xT_lo = (unsigned short*)(zx + 525056);
    unsigned short* cw_hi = (unsigned short*)(zx + 1050112);
    unsigned short* cw_lo = (unsigned short*)(zx + 1115648);
    unsigned short* tmpP_hi = (unsigned short*)zx;
    unsigned short* tmpP_lo = (unsigned short*)(zx + 1050112);
    unsigned short* mow_hi  = (unsigned short*)(zx + 2100224);
    unsigned short* mow_lo  = (unsigned short*)(zx + 2198528);

    unsigned short* ipw_hi = (unsigned short*)xBCs;
    unsigned short* ipw_lo = (unsigned short*)(xBCs + 233472);
    unsigned short* yb_hi  = (unsigned short*)xBCs;
    unsigned short* yb_lo  = (unsigned short*)(xBCs + 3145728);

    float* prodA = ybuf;
    unsigned short* u_hi = (unsigned short*)(ybuf + 32768);
    unsigned short* u_lo = (unsigned short*)(ybuf + 32768 + 1048576);

    // ---- 1. conv_in as GEMM ----
    zero_pads_kernel<<<6, 256, 0, stream>>>(xT_hi, xT_lo, IN_DIM);
    transpose_x_kernel<<<dim3(L_ / 32, IN_DIM / 32, B_), 256, 0, stream>>>(
        x, xT_hi, xT_lo);
    prep_cw_kernel<<<512, 256, 0, stream>>>(conv_w, cw_hi, cw_lo);
    gemm_ci_kernel<<<dim3(2, (B_ * L_) / 128), 256, 0, stream>>>(
        xT_hi, xT_lo, cw_hi, cw_lo, conv_b, u_hi, u_lo);

    // ---- 2. in_proj GEMM ----
    tconv_kernel<<<dim3(D_IN_PROJ / 32, D_MODEL / 32), 256, 0, stream>>>(
        in_proj_w, ipw_hi, ipw_lo, D_MODEL, D_IN_PROJ);
    gemm_bf16s_kernel<<<dim3((D_IN_PROJ + 127) / 128, (B_ * L_) / 128), 256, 0, stream>>>(
        u_hi, u_lo, ipw_hi, ipw_lo, zx, B_ * L_, D_IN_PROJ, D_MODEL);

    // ---- 3. elementwise + scan ----
    dt_kernel<<<(B_ * L_ * NHEADS) / 256, 256, 0, stream>>>(zx, dt_bias, dtb);
    dwconv_kernel<<<(B_ * (L_ / 8) * CONV_DIM) / 256, 256, 0, stream>>>(
        zx, dw_conv_w, dw_conv_b, xBCs);
    gmat_kernel<<<B_ * SCAN_NC, 256, 0, stream>>>(xBCs, Gbuf);
    scan_local2<<<B_ * SCAN_NC * (NHEADS / 8), 512, 0, stream>>>(
        xBCs, dtb, A_log, Sloc, prodA);
    scan_prefix_kernel<<<(B_ * NHEADS) / 4, 256, 0, stream>>>(Sloc, prodA);
    scan_final2<<<B_ * SCAN_NC * (NHEADS / 8), 512, 0, stream>>>(
        xBCs, dtb, A_log, Dp, Sloc, Gbuf, ybuf);

    // ---- 4. gate + norm (reads zx z-cols; last use of zx) ----
    gate_norm_kernel<<<B_ * L_, 256, 0, stream>>>(zx, norm_w, ybuf, yb_hi, yb_lo);

    // ---- 5. mamba_out GEMM -> padded split tmpP ----
    zero_pads_kernel<<<12, 256, 0, stream>>>(tmpP_hi, tmpP_lo, D_MODEL);
    prep_cow_kernel<<<512, 256, 0, stream>>>(out_conv_w, cow_hi, cow_lo);
    tconv_kernel<<<dim3(D_MODEL / 32, D_INNER / 32), 256, 0, stream>>>(
        mamba_out_w, mow_hi, mow_lo, D_INNER, D_MODEL);
    gemm_mo_kernel<<<dim3(2, (B_ * L_) / 128), 256, 0, stream>>>(
        yb_hi, yb_lo, mow_hi, mow_lo, tmpP_hi, tmpP_lo);

    // ---- 6. conv_out as full-K GEMM (64 blocks, regular stores) ----
    gemm_co_kernel<<<dim3(1, (B_ * L_) / 128), 256, 0, stream>>>(
        tmpP_hi, tmpP_lo, cow_hi, cow_lo, out);
}

// Round 16
// 313.248 us; speedup vs baseline: 1.2703x; 1.1175x over previous
//
#include <hip/hip_runtime.h>
#include <math.h>

#define B_      4
#define L_      2048
#define IN_DIM  128
#define D_MODEL 256
#define OUT_DIM 128
#define D_STATE 16
#define D_INNER 768
#define NHEADS  256
#define HEADDIM 3
#define CONV_DIM 800
#define D_IN_PROJ 1824

#define SCAN_NC 32
#define SCAN_CL 64
#define LPAD    2051        // L_ + 3 padded rows (row0 = left pad, rows 2049/2050 = right pad)

typedef short  short8 __attribute__((ext_vector_type(8)));
typedef float  f32x4  __attribute__((ext_vector_type(4)));

__device__ __forceinline__ unsigned short f2bf(float f) {
    unsigned int u = __float_as_uint(f);
    u = (u + 0x7fffu + ((u >> 16) & 1u)) >> 16;     // RN-to-even
    return (unsigned short)u;
}
__device__ __forceinline__ float bf2f(unsigned short h) {
    return __uint_as_float(((unsigned int)h) << 16);
}

// ---------------------------------------------------------------------------
// zero the 3 pad rows per batch of a padded split-bf16 tensor [B][LPAD][pitch]
// ---------------------------------------------------------------------------
__global__ __launch_bounds__(256) void zero_pads_kernel(
    unsigned short* __restrict__ ph, unsigned short* __restrict__ pl, int pitch)
{
    int t = blockIdx.x * 256 + threadIdx.x;
    int n = B_ * 3 * pitch;
    if (t < n) {
        int ch = t % pitch, rb = t / pitch;
        int b = rb / 3, ri = rb % 3;
        int row = (ri == 0) ? 0 : (ri == 1) ? (L_ + 1) : (L_ + 2);
        size_t off = ((size_t)b * LPAD + row) * pitch + ch;
        ph[off] = 0; pl[off] = 0;
    }
}

// ---------------------------------------------------------------------------
// transpose x [b][i][L] fp32 -> padded split-bf16 xT [b][LPAD][128], row l+1
// ---------------------------------------------------------------------------
__global__ __launch_bounds__(256) void transpose_x_kernel(
    const float* __restrict__ x, unsigned short* __restrict__ xh,
    unsigned short* __restrict__ xl)
{
    __shared__ float tile[32][33];
    int b = blockIdx.z;
    int l0 = blockIdx.x * 32, i0 = blockIdx.y * 32;
    int tx = threadIdx.x & 31, ty = threadIdx.x >> 5;   // ty 0..7
    const float* xb = x + (size_t)b * IN_DIM * L_;
    #pragma unroll
    for (int r = 0; r < 4; ++r)
        tile[ty + r * 8][tx] = xb[(size_t)(i0 + ty + r * 8) * L_ + l0 + tx];
    __syncthreads();
    #pragma unroll
    for (int r = 0; r < 4; ++r) {
        int l = l0 + ty + r * 8;
        float v = tile[tx][ty + r * 8];                  // x[b][i0+tx][l]
        size_t off = ((size_t)b * LPAD + l + 1) * IN_DIM + i0 + tx;
        unsigned short h = f2bf(v);
        xh[off] = h;
        xl[off] = f2bf(v - bf2f(h));
    }
}

// ---------------------------------------------------------------------------
// reindex+split conv_w [256][128][4] -> cw [256][512], kk = k*128+i
// ---------------------------------------------------------------------------
__global__ __launch_bounds__(256) void prep_cw_kernel(
    const float* __restrict__ w, unsigned short* __restrict__ wh,
    unsigned short* __restrict__ wl)
{
    int t = blockIdx.x * 256 + threadIdx.x;              // 256*512
    if (t < D_MODEL * 512) {
        int o = t >> 9, kk = t & 511;
        int k = kk >> 7, i = kk & 127;
        float v = w[((size_t)o * IN_DIM + i) * 4 + k];
        unsigned short h = f2bf(v);
        wh[t] = h; wl[t] = f2bf(v - bf2f(h));
    }
}

// ---------------------------------------------------------------------------
// reindex out_conv_w [128][256][4] -> cow [128][1024] bf16, kk = k*256+c
// ---------------------------------------------------------------------------
__global__ __launch_bounds__(256) void prep_cow_kernel(
    const float* __restrict__ w, unsigned short* __restrict__ wh)
{
    int t = blockIdx.x * 256 + threadIdx.x;              // 128*1024
    if (t < OUT_DIM * 1024) {
        int o = t >> 10, kk = t & 1023;
        int k = kk >> 8, c = kk & 255;
        wh[t] = f2bf(w[((size_t)o * D_MODEL + c) * 4 + k]);
    }
}

// ---------------------------------------------------------------------------
// transpose + split: src[K][N] fp32 -> dh/dl [N][K] bf16  (weight prep)
// ---------------------------------------------------------------------------
__global__ __launch_bounds__(256) void tconv_kernel(
    const float* __restrict__ src, unsigned short* __restrict__ dh,
    unsigned short* __restrict__ dl, int K, int N)
{
    __shared__ float tile[32][33];
    int k0 = blockIdx.y * 32, n0 = blockIdx.x * 32;
    int tx = threadIdx.x & 31, ty = threadIdx.x >> 5;
    #pragma unroll
    for (int r = 0; r < 4; ++r)
        tile[ty + r * 8][tx] = src[(size_t)(k0 + ty + r * 8) * N + n0 + tx];
    __syncthreads();
    #pragma unroll
    for (int r = 0; r < 4; ++r) {
        int n = n0 + ty + r * 8;
        float v = tile[tx][ty + r * 8];
        unsigned short h = f2bf(v);
        dh[(size_t)n * K + k0 + tx] = h;
        dl[(size_t)n * K + k0 + tx] = f2bf(v - bf2f(h));
    }
}

// ---------------------------------------------------------------------------
// K2: split-bf16 MFMA GEMM (generic).  C[M,N] fp32 = (Ah+Al)[M,K]*(Bh+Bl)^T
// ---------------------------------------------------------------------------
__global__ __launch_bounds__(256) void gemm_bf16s_kernel(
    const unsigned short* __restrict__ Ah, const unsigned short* __restrict__ Al,
    const unsigned short* __restrict__ Bh, const unsigned short* __restrict__ Bl,
    float* __restrict__ C, int M, int N, int K)
{
    __shared__ __align__(16) unsigned short AsH[128][40];
    __shared__ __align__(16) unsigned short AsL[128][40];
    __shared__ __align__(16) unsigned short BsH[128][40];
    __shared__ __align__(16) unsigned short BsL[128][40];

    int m0 = blockIdx.y * 128, n0 = blockIdx.x * 128;
    int t = threadIdx.x;
    int wid = t >> 6, lane = t & 63;
    int wm = (wid >> 1) * 64, wn = (wid & 1) * 64;
    int fr = lane & 15, fq = lane >> 4;

    f32x4 z4 = {0.f, 0.f, 0.f, 0.f};
    f32x4 acc[4][4];
    #pragma unroll
    for (int i = 0; i < 4; ++i)
        #pragma unroll
        for (int j = 0; j < 4; ++j) acc[i][j] = z4;

    for (int k0 = 0; k0 < K; k0 += 32) {
        __syncthreads();
        #pragma unroll
        for (int p = 0; p < 2; ++p) {
            int idx = p * 256 + t;
            int row = idx >> 2, q = idx & 3;
            int koff = k0 + q * 8;
            *(float4*)&AsH[row][q * 8] =
                *(const float4*)(Ah + (size_t)(m0 + row) * K + koff);
            *(float4*)&AsL[row][q * 8] =
                *(const float4*)(Al + (size_t)(m0 + row) * K + koff);
            int n = n0 + row;
            float4 vbh = make_float4(0.f, 0.f, 0.f, 0.f), vbl = vbh;
            if (n < N) {
                vbh = *(const float4*)(Bh + (size_t)n * K + koff);
                vbl = *(const float4*)(Bl + (size_t)n * K + koff);
            }
            *(float4*)&BsH[row][q * 8] = vbh;
            *(float4*)&BsL[row][q * 8] = vbl;
        }
        __syncthreads();

        short8 ah[4], al[4], bh[4], bl[4];
        #pragma unroll
        for (int i = 0; i < 4; ++i) {
            ah[i] = *(const short8*)&AsH[wm + i * 16 + fr][fq * 8];
            al[i] = *(const short8*)&AsL[wm + i * 16 + fr][fq * 8];
            bh[i] = *(const short8*)&BsH[wn + i * 16 + fr][fq * 8];
            bl[i] = *(const short8*)&BsL[wn + i * 16 + fr][fq * 8];
        }
        #pragma unroll
        for (int i = 0; i < 4; ++i)
            #pragma unroll
            for (int j = 0; j < 4; ++j) {
                acc[i][j] = __builtin_amdgcn_mfma_f32_16x16x32_bf16(
                    ah[i], bh[j], acc[i][j], 0, 0, 0);
                acc[i][j] = __builtin_amdgcn_mfma_f32_16x16x32_bf16(
                    ah[i], bl[j], acc[i][j], 0, 0, 0);
                acc[i][j] = __builtin_amdgcn_mfma_f32_16x16x32_bf16(
                    al[i], bh[j], acc[i][j], 0, 0, 0);
            }
    }

    #pragma unroll
    for (int i = 0; i < 4; ++i) {
        int r0 = m0 + wm + i * 16 + fq * 4;
        #pragma unroll
        for (int j = 0; j < 4; ++j) {
            int cc = n0 + wn + j * 16 + fr;
            if (cc < N) {
                #pragma unroll
                for (int r = 0; r < 4; ++r)
                    C[(size_t)(r0 + r) * N + cc] = acc[i][j][r];
            }
        }
    }
}

// ---------------------------------------------------------------------------
// conv_in as GEMM: A = xT window, B = cw [256][512]. Epilogue: + conv_b,
// write split-bf16 u [8192][256].
// ---------------------------------------------------------------------------
__global__ __launch_bounds__(256) void gemm_ci_kernel(
    const unsigned short* __restrict__ Ah, const unsigned short* __restrict__ Al,
    const unsigned short* __restrict__ Bh, const unsigned short* __restrict__ Bl,
    const float* __restrict__ bias,
    unsigned short* __restrict__ Ch, unsigned short* __restrict__ Cl)
{
    const int K = 512;
    __shared__ __align__(16) unsigned short AsH[128][40];
    __shared__ __align__(16) unsigned short AsL[128][40];
    __shared__ __align__(16) unsigned short BsH[128][40];
    __shared__ __align__(16) unsigned short BsL[128][40];

    int m0 = blockIdx.y * 128, n0 = blockIdx.x * 128;
    int b = m0 >> 11;
    size_t abase = ((size_t)b * LPAD + (m0 & 2047)) * IN_DIM;
    int t = threadIdx.x;
    int wid = t >> 6, lane = t & 63;
    int wm = (wid >> 1) * 64, wn = (wid & 1) * 64;
    int fr = lane & 15, fq = lane >> 4;

    f32x4 z4 = {0.f, 0.f, 0.f, 0.f};
    f32x4 acc[4][4];
    #pragma unroll
    for (int i = 0; i < 4; ++i)
        #pragma unroll
        for (int j = 0; j < 4; ++j) acc[i][j] = z4;

    for (int k0 = 0; k0 < K; k0 += 32) {
        __syncthreads();
        #pragma unroll
        for (int p = 0; p < 2; ++p) {
            int idx = p * 256 + t;
            int row = idx >> 2, q = idx & 3;
            int koff = k0 + q * 8;
            *(float4*)&AsH[row][q * 8] =
                *(const float4*)(Ah + abase + (size_t)row * IN_DIM + koff);
            *(float4*)&AsL[row][q * 8] =
                *(const float4*)(Al + abase + (size_t)row * IN_DIM + koff);
            int n = n0 + row;
            *(float4*)&BsH[row][q * 8] = *(const float4*)(Bh + (size_t)n * K + koff);
            *(float4*)&BsL[row][q * 8] = *(const float4*)(Bl + (size_t)n * K + koff);
        }
        __syncthreads();

        short8 ah[4], al[4], bh[4], bl[4];
        #pragma unroll
        for (int i = 0; i < 4; ++i) {
            ah[i] = *(const short8*)&AsH[wm + i * 16 + fr][fq * 8];
            al[i] = *(const short8*)&AsL[wm + i * 16 + fr][fq * 8];
            bh[i] = *(const short8*)&BsH[wn + i * 16 + fr][fq * 8];
            bl[i] = *(const short8*)&BsL[wn + i * 16 + fr][fq * 8];
        }
        #pragma unroll
        for (int i = 0; i < 4; ++i)
            #pragma unroll
            for (int j = 0; j < 4; ++j) {
                acc[i][j] = __builtin_amdgcn_mfma_f32_16x16x32_bf16(
                    ah[i], bh[j], acc[i][j], 0, 0, 0);
                acc[i][j] = __builtin_amdgcn_mfma_f32_16x16x32_bf16(
                    ah[i], bl[j], acc[i][j], 0, 0, 0);
                acc[i][j] = __builtin_amdgcn_mfma_f32_16x16x32_bf16(
                    al[i], bh[j], acc[i][j], 0, 0, 0);
            }
    }

    #pragma unroll
    for (int i = 0; i < 4; ++i) {
        int r0 = m0 + wm + i * 16 + fq * 4;
        #pragma unroll
        for (int j = 0; j < 4; ++j) {
            int cc = n0 + wn + j * 16 + fr;
            float bc = bias[cc];
            #pragma unroll
            for (int r = 0; r < 4; ++r) {
                float v = acc[i][j][r] + bc;
                unsigned short h = f2bf(v);
                size_t off = (size_t)(r0 + r) * D_MODEL + cc;
                Ch[off] = h;
                Cl[off] = f2bf(v - bf2f(h));
            }
        }
    }
}

// ---------------------------------------------------------------------------
// gemm2 (mamba_out), pure bf16 (post-scan path; error budget allows).
// A = yb_hi [8192][768], B = mow_hi [256][768]. Output: bf16 PADDED tmpP_hi,
// row m=(b,l) -> padded row b*LPAD+l+1.
// ---------------------------------------------------------------------------
__global__ __launch_bounds__(256) void gemm_mo_kernel(
    const unsigned short* __restrict__ Ah, const unsigned short* __restrict__ Bh,
    unsigned short* __restrict__ Ch)
{
    const int K = D_INNER;
    __shared__ __align__(16) unsigned short AsH[128][40];
    __shared__ __align__(16) unsigned short BsH[128][40];

    int m0 = blockIdx.y * 128, n0 = blockIdx.x * 128;
    int t = threadIdx.x;
    int wid = t >> 6, lane = t & 63;
    int wm = (wid >> 1) * 64, wn = (wid & 1) * 64;
    int fr = lane & 15, fq = lane >> 4;

    f32x4 z4 = {0.f, 0.f, 0.f, 0.f};
    f32x4 acc[4][4];
    #pragma unroll
    for (int i = 0; i < 4; ++i)
        #pragma unroll
        for (int j = 0; j < 4; ++j) acc[i][j] = z4;

    for (int k0 = 0; k0 < K; k0 += 32) {
        __syncthreads();
        #pragma unroll
        for (int p = 0; p < 2; ++p) {
            int idx = p * 256 + t;
            int row = idx >> 2, q = idx & 3;
            int koff = k0 + q * 8;
            *(float4*)&AsH[row][q * 8] =
                *(const float4*)(Ah + (size_t)(m0 + row) * K + koff);
            int n = n0 + row;
            *(float4*)&BsH[row][q * 8] = *(const float4*)(Bh + (size_t)n * K + koff);
        }
        __syncthreads();

        short8 ah[4], bh[4];
        #pragma unroll
        for (int i = 0; i < 4; ++i) {
            ah[i] = *(const short8*)&AsH[wm + i * 16 + fr][fq * 8];
            bh[i] = *(const short8*)&BsH[wn + i * 16 + fr][fq * 8];
        }
        #pragma unroll
        for (int i = 0; i < 4; ++i)
            #pragma unroll
            for (int j = 0; j < 4; ++j)
                acc[i][j] = __builtin_amdgcn_mfma_f32_16x16x32_bf16(
                    ah[i], bh[j], acc[i][j], 0, 0, 0);
    }

    int b = m0 >> 11;
    #pragma unroll
    for (int i = 0; i < 4; ++i) {
        int r0 = m0 + wm + i * 16 + fq * 4;
        #pragma unroll
        for (int j = 0; j < 4; ++j) {
            int cc = n0 + wn + j * 16 + fr;
            #pragma unroll
            for (int r = 0; r < 4; ++r) {
                int l = (r0 + r) & 2047;
                size_t off = ((size_t)b * LPAD + l + 1) * D_MODEL + cc;
                Ch[off] = f2bf(acc[i][j][r]);
            }
        }
    }
}

// ---------------------------------------------------------------------------
// conv_out as GEMM, pure bf16, full-K: A = tmpP_hi window
// [(b*LPAD+l)*256, 1024 contiguous], B = cow_hi [128][1024]. 64 blocks.
// ---------------------------------------------------------------------------
__global__ __launch_bounds__(256) void gemm_co_kernel(
    const unsigned short* __restrict__ Ah, const unsigned short* __restrict__ Bh,
    float* __restrict__ out)
{
    const int K = 1024;
    __shared__ __align__(16) unsigned short AsH[128][40];
    __shared__ __align__(16) unsigned short BsH[128][40];

    int m0 = blockIdx.y * 128;
    int b = m0 >> 11, l0t = m0 & 2047;
    size_t abase = ((size_t)b * LPAD + l0t) * D_MODEL;
    int t = threadIdx.x;
    int wid = t >> 6, lane = t & 63;
    int wm = (wid >> 1) * 64, wn = (wid & 1) * 64;
    int fr = lane & 15, fq = lane >> 4;

    f32x4 z4 = {0.f, 0.f, 0.f, 0.f};
    f32x4 acc[4][4];
    #pragma unroll
    for (int i = 0; i < 4; ++i)
        #pragma unroll
        for (int j = 0; j < 4; ++j) acc[i][j] = z4;

    for (int k0 = 0; k0 < K; k0 += 32) {
        __syncthreads();
        #pragma unroll
        for (int p = 0; p < 2; ++p) {
            int idx = p * 256 + t;
            int row = idx >> 2, q = idx & 3;
            int koff = k0 + q * 8;
            *(float4*)&AsH[row][q * 8] =
                *(const float4*)(Ah + abase + (size_t)row * D_MODEL + koff);
            *(float4*)&BsH[row][q * 8] = *(const float4*)(Bh + (size_t)row * K + koff);
        }
        __syncthreads();

        short8 ah[4], bh[4];
        #pragma unroll
        for (int i = 0; i < 4; ++i) {
            ah[i] = *(const short8*)&AsH[wm + i * 16 + fr][fq * 8];
            bh[i] = *(const short8*)&BsH[wn + i * 16 + fr][fq * 8];
        }
        #pragma unroll
        for (int i = 0; i < 4; ++i)
            #pragma unroll
            for (int j = 0; j < 4; ++j)
                acc[i][j] = __builtin_amdgcn_mfma_f32_16x16x32_bf16(
                    ah[i], bh[j], acc[i][j], 0, 0, 0);
    }

    #pragma unroll
    for (int i = 0; i < 4; ++i) {
        int lr = l0t + wm + i * 16 + fq * 4;
        #pragma unroll
        for (int j = 0; j < 4; ++j) {
            int cc = wn + j * 16 + fr;                  // o in 0..127
            float* dst = out + ((size_t)(b * OUT_DIM + cc)) * L_ + lr;
            float4 ov = make_float4(acc[i][j][0], acc[i][j][1],
                                    acc[i][j][2], acc[i][j][3]);
            *(float4*)dst = ov;
        }
    }
}

// ---------------------------------------------------------------------------
// K3: dt = softplus(dt_raw + dt_bias)    [B*L, 256]
// ---------------------------------------------------------------------------
__global__ __launch_bounds__(256) void dt_kernel(
    const float* __restrict__ zx, const float* __restrict__ dt_bias,
    float* __restrict__ dtb)
{
    int idx = blockIdx.x * 256 + threadIdx.x;
    int h  = idx & 255;
    int bl = idx >> 8;
    float v = zx[(size_t)bl * D_IN_PROJ + (D_INNER + CONV_DIM) + h] + dt_bias[h];
    float sp = (v > 20.f) ? v : log1pf(expf(v));
    dtb[idx] = sp;
}

// ---------------------------------------------------------------------------
// K4: causal depthwise conv + bias + SiLU. 8 l-values per thread.
// ---------------------------------------------------------------------------
__global__ __launch_bounds__(256) void dwconv_kernel(
    const float* __restrict__ zx, const float* __restrict__ w,
    const float* __restrict__ bias, float* __restrict__ xBCs)
{
    int idx = blockIdx.x * 256 + threadIdx.x;   // over B * L/8 * 800
    int c   = idx % CONV_DIM;
    int bl8 = idx / CONV_DIM;
    int b  = bl8 >> 8;               // L/8 = 256
    int l0 = (bl8 & 255) * 8;
    float4 wv = *(const float4*)&w[c * 4];
    float bi = bias[c];
    const float* base = zx + ((size_t)(b * L_ + l0)) * D_IN_PROJ + D_INNER + c;
    float r[11];
    #pragma unroll
    for (int k = 0; k < 11; ++k) {
        int l = l0 - 3 + k;
        r[k] = (l >= 0) ? base[(ptrdiff_t)(k - 3) * D_IN_PROJ] : 0.f;
    }
    #pragma unroll
    for (int i = 0; i < 8; ++i) {
        float acc = bi;
        acc = fmaf(r[i + 0], wv.x, acc);
        acc = fmaf(r[i + 1], wv.y, acc);
        acc = fmaf(r[i + 2], wv.z, acc);
        acc = fmaf(r[i + 3], wv.w, acc);
        float s = acc / (1.f + expf(-acc));
        xBCs[((size_t)(b * L_ + l0 + i)) * CONV_DIM + c] = s;
    }
}

// ---------------------------------------------------------------------------
// K5g: G[i][j] = C_i . B_j  per (b,chunk).  bid = b*32+c -> XCD = c%8,
// matching the scan swizzle (bc & 7) so G stays in the producing XCD's L2.
// ---------------------------------------------------------------------------
__global__ __launch_bounds__(256) void gmat_kernel(
    const float* __restrict__ xBCs, float* __restrict__ G)
{
    __shared__ float Bs[64][16];
    __shared__ float Cs[64][16];
    int c = blockIdx.x & 31, b = blockIdx.x >> 5;
    int t = threadIdx.x;
    int row0 = b * L_ + c * SCAN_CL;
    {
        int j = t >> 2, q = t & 3;
        const float* r = xBCs + (size_t)(row0 + j) * CONV_DIM + D_INNER;
        *(float4*)&Bs[j][q * 4] = *(const float4*)(r + q * 4);
        *(float4*)&Cs[j][q * 4] = *(const float4*)(r + D_STATE + q * 4);
    }
    __syncthreads();
    int i = t >> 2, jq = t & 3;
    float4 c0 = *(const float4*)&Cs[i][0];
    float4 c1 = *(const float4*)&Cs[i][4];
    float4 c2 = *(const float4*)&Cs[i][8];
    float4 c3 = *(const float4*)&Cs[i][12];
    float dot[16];
    #pragma unroll
    for (int jj = 0; jj < 16; ++jj) {
        int j = jq * 16 + jj;
        float4 b0 = *(const float4*)&Bs[j][0];
        float4 b1 = *(const float4*)&Bs[j][4];
        float4 b2 = *(const float4*)&Bs[j][8];
        float4 b3 = *(const float4*)&Bs[j][12];
        float d = c0.x * b0.x + c0.y * b0.y + c0.z * b0.z + c0.w * b0.w;
        d = fmaf(c1.x, b1.x, d); d = fmaf(c1.y, b1.y, d);
        d = fmaf(c1.z, b1.z, d); d = fmaf(c1.w, b1.w, d);
        d = fmaf(c2.x, b2.x, d); d = fmaf(c2.y, b2.y, d);
        d = fmaf(c2.z, b2.z, d); d = fmaf(c2.w, b2.w, d);
        d = fmaf(c3.x, b3.x, d); d = fmaf(c3.y, b3.y, d);
        d = fmaf(c3.z, b3.z, d); d = fmaf(c3.w, b3.w, d);
        dot[jj] = d;
    }
    float* gout = G + ((size_t)blockIdx.x * 64 + i) * 64 + jq * 16;
    #pragma unroll
    for (int q = 0; q < 4; ++q)
        *(float4*)(gout + q * 4) = make_float4(dot[q*4], dot[q*4+1], dot[q*4+2], dot[q*4+3]);
}

// ---------------------------------------------------------------------------
// XCD-locality swizzle: all 32 hg blocks of one (b,c) share bid%8 -> same XCD
// bid = (bc>>3)<<8 | hg<<3 | (bc&7);  bc = b*32+c.
// ---------------------------------------------------------------------------
__device__ __forceinline__ void scan_decode(int bid, int& b, int& c, int& hg)
{
    int bcl = bid & 7;
    hg = (bid >> 3) & 31;
    int bc = ((bid >> 8) << 3) | bcl;
    c = bc & 31;
    b = bc >> 5;
}

// ---------------------------------------------------------------------------
// K5a: chunk-local state build. 512 threads = 8 waves; ONE head per wave.
// Pk in SoA (stride 66) to avoid LDS bank conflicts.
// ---------------------------------------------------------------------------
__global__ __launch_bounds__(512) void scan_local2(
    const float* __restrict__ xBCs, const float* __restrict__ dtb,
    const float* __restrict__ A_log,
    float* __restrict__ Sloc, float* __restrict__ prodA)
{
    __shared__ float  BsT[16][68];          // [n][row], padded
    __shared__ float  Pk0[8][66], Pk1[8][66], Pk2[8][66], Pkw[8][66];
    __shared__ float  UT[8][3][64];
    int b, c, hg;
    scan_decode(blockIdx.x, b, c, hg);
    int h0 = hg * 8;
    int t = threadIdx.x;
    int row0 = b * L_ + c * SCAN_CL;

    if (t < 256) {   // B tile (coalesced)
        int j = t >> 2, q = t & 3;
        const float* r = xBCs + (size_t)(row0 + j) * CONV_DIM;
        float4 bv = *(const float4*)(r + D_INNER + q * 4);
        BsT[q*4+0][j] = bv.x; BsT[q*4+1][j] = bv.y;
        BsT[q*4+2][j] = bv.z; BsT[q*4+3][j] = bv.w;
    }
    {   // Pk staging: one entry per thread (dense per row); SoA writes
        int hh = t & 7, j = t >> 3;
        float dtv = dtb[(size_t)(row0 + j) * NHEADS + h0 + hh];
        const float* xr = xBCs + (size_t)(row0 + j) * CONV_DIM + (h0 + hh) * 3;
        Pk0[hh][j] = dtv * xr[0];
        Pk1[hh][j] = dtv * xr[1];
        Pk2[hh][j] = dtv * xr[2];
        Pkw[hh][j] = dtv;
    }
    __syncthreads();

    int wv = t >> 6, lane = t & 63;
    int hh = wv;
    int h = h0 + hh;
    int p = lane >> 4, n = lane & 15;
    int pc = (p < 3) ? p : 2;

    float pkx = Pk0[hh][lane], pky = Pk1[hh][lane], pkz = Pk2[hh][lane];
    float pkw = Pkw[hh][lane];
    float A = -__expf(A_log[h]);
    float cum = pkw * A;
    #pragma unroll
    for (int off = 1; off < 64; off <<= 1) {
        float sv = __shfl_up(cum, off);
        if (lane >= off) cum += sv;
    }
    float cum63 = __shfl(cum, 63);
    float wf = __expf(cum63 - cum);
    UT[hh][0][lane] = wf * pkx;
    UT[hh][1][lane] = wf * pky;
    UT[hh][2][lane] = wf * pkz;
    float state = 0.f;
    #pragma unroll
    for (int q = 0; q < 16; ++q) {
        float4 Bv = *(const float4*)&BsT[n][q * 4];
        float4 Uv = *(const float4*)&UT[hh][pc][q * 4];
        state = fmaf(Uv.x, Bv.x, state);
        state = fmaf(Uv.y, Bv.y, state);
        state = fmaf(Uv.z, Bv.z, state);
        state = fmaf(Uv.w, Bv.w, state);
    }
    size_t bh = (size_t)(b * NHEADS + h);
    if (p < 3) Sloc[(bh * SCAN_NC + c) * 48 + p * 16 + n] = state;
    if (lane == 0) prodA[bh * SCAN_NC + c] = __expf(cum63);
}

// ---------------------------------------------------------------------------
// K5b: sequential prefix over chunks, in place on Sloc
// ---------------------------------------------------------------------------
__global__ __launch_bounds__(256) void scan_prefix_kernel(
    float* __restrict__ Sloc, const float* __restrict__ prodA)
{
    int wv   = blockIdx.x * 4 + (threadIdx.x >> 6);
    int lane = threadIdx.x & 63;
    int p = lane >> 4, n = lane & 15;
    bool act = (p < 3);
    int l48 = ((p < 3) ? p : 2) * 16 + n;
    size_t base = (size_t)wv * SCAN_NC;

    float cur = 0.f;
    for (int c = 0; c < SCAN_NC; ++c) {
        float s  = Sloc[(base + c) * 48 + l48];
        float pa = prodA[base + c];
        if (act) Sloc[(base + c) * 48 + l48] = cur;
        cur = fmaf(pa, cur, s);
    }
}

// ---------------------------------------------------------------------------
// K5c: chunk-matmul final scan. 512 threads = 8 waves; ONE head per wave.
// G staged in LDS once per block; Pk in SoA (stride 66).
// ---------------------------------------------------------------------------
__global__ __launch_bounds__(512) void scan_final2(
    const float* __restrict__ xBCs, const float* __restrict__ dtb,
    const float* __restrict__ A_log, const float* __restrict__ Dp,
    const float* __restrict__ Sinit, const float* __restrict__ G,
    float* __restrict__ y)
{
    __shared__ float  Pk0[8][66], Pk1[8][66], Pk2[8][66], Pkw[8][66];
    __shared__ float4 XW[8][64];
    __shared__ float  Sin[8][48];
    __shared__ float  CsT[16][66];          // [n][row]
    __shared__ float  ysr[64][25];          // [row][24 ch] padded (stride 25)
    __shared__ float  Gs[64][65];           // G tile, odd stride
    int b, c, hg;
    scan_decode(blockIdx.x, b, c, hg);
    int h0 = hg * 8;
    int t = threadIdx.x;
    int row0 = b * L_ + c * SCAN_CL;

    if (t < 256) {   // C tile (coalesced)
        int j = t >> 2, q = t & 3;
        const float* r = xBCs + (size_t)(row0 + j) * CONV_DIM + D_INNER + D_STATE;
        float4 cv = *(const float4*)(r + q * 4);
        CsT[q*4+0][j] = cv.x; CsT[q*4+1][j] = cv.y;
        CsT[q*4+2][j] = cv.z; CsT[q*4+3][j] = cv.w;
    }
    {   // Pk staging: one entry per thread; SoA writes
        int hh = t & 7, j = t >> 3;
        float dtv = dtb[(size_t)(row0 + j) * NHEADS + h0 + hh];
        const float* xr = xBCs + (size_t)(row0 + j) * CONV_DIM + (h0 + hh) * 3;
        Pk0[hh][j] = dtv * xr[0];
        Pk1[hh][j] = dtv * xr[1];
        Pk2[hh][j] = dtv * xr[2];
        Pkw[hh][j] = dtv;
    }
    if (t < 384) {   // Sin staging: 8 heads x 48
        int hh = t / 48, k = t % 48;
        Sin[hh][k] = Sinit[((size_t)(b * NHEADS + h0 + hh) * SCAN_NC + c) * 48 + k];
    }
    {   // G staging: 4096 floats, coalesced float4 global reads
        const float* Gsrc = G + (size_t)(b * SCAN_NC + c) * 4096;
        #pragma unroll
        for (int e = 0; e < 2; ++e) {
            int idx = e * 512 + t;              // float4 index 0..1023
            int row = idx >> 4, cq = (idx & 15) * 4;
            float4 gv = *(const float4*)(Gsrc + (size_t)idx * 4);
            Gs[row][cq + 0] = gv.x;
            Gs[row][cq + 1] = gv.y;
            Gs[row][cq + 2] = gv.z;
            Gs[row][cq + 3] = gv.w;
        }
    }
    __syncthreads();

    int wv = t >> 6, lane = t & 63;
    int hh = wv;
    int h = h0 + hh;
    int I = lane >> 4;

    float pkx = Pk0[hh][lane], pky = Pk1[hh][lane], pkz = Pk2[hh][lane];
    float pkw = Pkw[hh][lane];
    float A = -__expf(A_log[h]);
    float cum = pkw * A;
    #pragma unroll
    for (int off = 1; off < 64; off <<= 1) {
        float sv = __shfl_up(cum, off);
        if (lane >= off) cum += sv;
    }
    float e0 = __shfl(cum, 15);
    float e1 = __shfl(cum, 31);
    float e2 = __shfl(cum, 47);
    float e3 = __shfl(cum, 63);
    int ia = (I << 4) - 1;
    float AIr = __shfl(cum, ia < 0 ? 0 : ia);
    float AI = (I == 0) ? 0.f : AIr;
    float ri = __expf(cum - AI);
    float Eo = (I == 0) ? e0 : (I == 1) ? e1 : (I == 2) ? e2 : e3;
    float wj = __expf(Eo - cum);
    XW[hh][lane] = make_float4(wj * pkx, wj * pky, wj * pkz, 0.f);
    Pkw[hh][lane] = cum;                    // publish cum_j (wave-local)
    float S0 = (I > 0) ? __expf(AI - e0) : 0.f;
    float S1 = (I > 1) ? __expf(AI - e1) : 0.f;
    float S2 = (I > 2) ? __expf(AI - e2) : 0.f;
    float ecum = __expf(cum);

    float acc0 = 0.f, acc1 = 0.f, acc2 = 0.f;
    #pragma unroll
    for (int J = 0; J < 3; ++J) {
        float SJ = (J == 0) ? S0 : (J == 1) ? S1 : S2;
        float t0 = 0.f, t1 = 0.f, t2 = 0.f;
        #pragma unroll
        for (int kk = 0; kk < 16; ++kk) {
            float gk = Gs[lane][J * 16 + kk];
            float4 u = XW[hh][J * 16 + kk];
            t0 = fmaf(gk, u.x, t0);
            t1 = fmaf(gk, u.y, t1);
            t2 = fmaf(gk, u.z, t2);
        }
        acc0 = fmaf(SJ, t0, acc0);
        acc1 = fmaf(SJ, t1, acc1);
        acc2 = fmaf(SJ, t2, acc2);
    }

    float d0 = 0.f, d1 = 0.f, d2 = 0.f;
    #pragma unroll
    for (int kk = 0; kk < 16; ++kk) {
        int j = (I << 4) + kk;
        float gk = Gs[lane][j];
        float e = __expf(cum - Pkw[hh][j]);
        float m = (j <= lane) ? e : 0.f;
        float mg = m * gk;
        d0 = fmaf(mg, Pk0[hh][j], d0);
        d1 = fmaf(mg, Pk1[hh][j], d1);
        d2 = fmaf(mg, Pk2[hh][j], d2);
    }

    float s0 = 0.f, s1 = 0.f, s2 = 0.f;
    #pragma unroll
    for (int nq = 0; nq < 16; ++nq) {
        float Cv = CsT[nq][lane];
        s0 = fmaf(Cv, Sin[hh][nq],      s0);
        s1 = fmaf(Cv, Sin[hh][16 + nq], s1);
        s2 = fmaf(Cv, Sin[hh][32 + nq], s2);
    }

    float rdt = 1.0f / pkw;
    float Dh = Dp[h];
    float* yr = &ysr[lane][hh * 3];
    yr[0] = fmaf(ri, acc0, d0) + fmaf(ecum, s0, Dh * (pkx * rdt));
    yr[1] = fmaf(ri, acc1, d1) + fmaf(ecum, s1, Dh * (pky * rdt));
    yr[2] = fmaf(ri, acc2, d2) + fmaf(ecum, s2, Dh * (pkz * rdt));
    __syncthreads();

    {   // coalesced epilogue: 24 contiguous channels per row
        int i2 = t >> 3, q2 = t & 7;
        float* dst = y + (size_t)(row0 + i2) * D_INNER + hg * 24 + q2 * 3;
        dst[0] = ysr[i2][q2 * 3 + 0];
        dst[1] = ysr[i2][q2 * 3 + 1];
        dst[2] = ysr[i2][q2 * 3 + 2];
    }
}

// ---------------------------------------------------------------------------
// K6: y = y * silu(z); RMSNorm over 768; * norm_w.  Writes plain bf16 output
// (post-scan path: split-lo dropped per error budget).
// ---------------------------------------------------------------------------
__global__ __launch_bounds__(256) void gate_norm_kernel(
    const float* __restrict__ zx, const float* __restrict__ norm_w,
    const float* __restrict__ y, unsigned short* __restrict__ yh)
{
    int bl = blockIdx.x;
    int t  = threadIdx.x;
    const float* zrow = zx + (size_t)bl * D_IN_PROJ;
    const float* yrow = y + (size_t)bl * D_INNER;

    float v[3];
    float ss = 0.f;
    #pragma unroll
    for (int j = 0; j < 3; ++j) {
        int i = t + j * 256;
        float z = zrow[i];
        float s = z / (1.f + expf(-z));
        float val = yrow[i] * s;
        v[j] = val;
        ss += val * val;
    }
    ss += __shfl_xor(ss, 32);
    ss += __shfl_xor(ss, 16);
    ss += __shfl_xor(ss, 8);
    ss += __shfl_xor(ss, 4);
    ss += __shfl_xor(ss, 2);
    ss += __shfl_xor(ss, 1);
    __shared__ float red[4];
    int lane = t & 63, wid = t >> 6;
    if (lane == 0) red[wid] = ss;
    __syncthreads();
    float tot = red[0] + red[1] + red[2] + red[3];
    float rs = rsqrtf(tot * (1.f / D_INNER) + 1e-5f);
    #pragma unroll
    for (int j = 0; j < 3; ++j) {
        int i = t + j * 256;
        float o = v[j] * rs * norm_w[i];
        yh[(size_t)bl * D_INNER + i] = f2bf(o);
    }
}

// ---------------------------------------------------------------------------
extern "C" void kernel_launch(void* const* d_in, const int* in_sizes, int n_in,
                              void* d_out, int out_size, void* d_ws, size_t ws_size,
                              hipStream_t stream)
{
    const float* x           = (const float*)d_in[0];
    const float* conv_w      = (const float*)d_in[1];
    const float* conv_b      = (const float*)d_in[2];
    const float* in_proj_w   = (const float*)d_in[3];
    const float* dw_conv_w   = (const float*)d_in[4];
    const float* dw_conv_b   = (const float*)d_in[5];
    const float* dt_bias     = (const float*)d_in[6];
    const float* A_log       = (const float*)d_in[7];
    const float* Dp          = (const float*)d_in[8];
    const float* norm_w      = (const float*)d_in[9];
    const float* mamba_out_w = (const float*)d_in[10];
    const float* out_conv_w  = (const float*)d_in[11];
    float* out = (float*)d_out;
    float* ws  = (float*)d_ws;

    // ---- workspace layout (floats) ----
    float* S0   = ws;                        //  2,097,152  Gbuf+Sloc / late: cow
    float* zx   = S0 + 2097152;              // 14,942,208  early: xT+cw / late: tmpP+mow
    float* xBCs = zx + 14942208;             //  6,553,600  early: ipw / late: yb
    float* dtb  = xBCs + 6553600;            //  2,097,152
    float* ybuf = dtb + 2097152;             //  6,291,456  early: prodA+u

    float* Gbuf = S0;                        // 524,288
    float* Sloc = S0 + 524288;               // 1,572,864
    unsigned short* cow_hi = (unsigned short*)S0;              // late, 131,072 ush

    unsigned short* xT_hi = (unsigned short*)zx;
    unsigned short* xT_lo = (unsigned short*)(zx + 525056);
    unsigned short* cw_hi = (unsigned short*)(zx + 1050112);
    unsigned short* cw_lo = (unsigned short*)(zx + 1115648);
    unsigned short* tmpP_hi = (unsigned short*)zx;             // late, 2,100,224 ush
    unsigned short* mow_hi  = (unsigned short*)(zx + 2100224); // 196,608 ush
    unsigned short* mow_lo  = (unsigned short*)(zx + 2198528); // written, unused

    unsigned short* ipw_hi = (unsigned short*)xBCs;
    unsigned short* ipw_lo = (unsigned short*)(xBCs + 233472);
    unsigned short* yb_hi  = (unsigned short*)xBCs;            // after scan_final

    float* prodA = ybuf;
    unsigned short* u_hi = (unsigned short*)(ybuf + 32768);
    unsigned short* u_lo = (unsigned short*)(ybuf + 32768 + 1048576);

    // ---- 1. conv_in as GEMM ----
    zero_pads_kernel<<<6, 256, 0, stream>>>(xT_hi, xT_lo, IN_DIM);
    transpose_x_kernel<<<dim3(L_ / 32, IN_DIM / 32, B_), 256, 0, stream>>>(
        x, xT_hi, xT_lo);
    prep_cw_kernel<<<512, 256, 0, stream>>>(conv_w, cw_hi, cw_lo);
    gemm_ci_kernel<<<dim3(2, (B_ * L_) / 128), 256, 0, stream>>>(
        xT_hi, xT_lo, cw_hi, cw_lo, conv_b, u_hi, u_lo);

    // ---- 2. in_proj GEMM (full split precision: feeds dt/exp path) ----
    tconv_kernel<<<dim3(D_IN_PROJ / 32, D_MODEL / 32), 256, 0, stream>>>(
        in_proj_w, ipw_hi, ipw_lo, D_MODEL, D_IN_PROJ);
    gemm_bf16s_kernel<<<dim3((D_IN_PROJ + 127) / 128, (B_ * L_) / 128), 256, 0, stream>>>(
        u_hi, u_lo, ipw_hi, ipw_lo, zx, B_ * L_, D_IN_PROJ, D_MODEL);

    // ---- 3. elementwise + scan ----
    dt_kernel<<<(B_ * L_ * NHEADS) / 256, 256, 0, stream>>>(zx, dt_bias, dtb);
    dwconv_kernel<<<(B_ * (L_ / 8) * CONV_DIM) / 256, 256, 0, stream>>>(
        zx, dw_conv_w, dw_conv_b, xBCs);
    gmat_kernel<<<B_ * SCAN_NC, 256, 0, stream>>>(xBCs, Gbuf);
    scan_local2<<<B_ * SCAN_NC * (NHEADS / 8), 512, 0, stream>>>(
        xBCs, dtb, A_log, Sloc, prodA);
    scan_prefix_kernel<<<(B_ * NHEADS) / 4, 256, 0, stream>>>(Sloc, prodA);
    scan_final2<<<B_ * SCAN_NC * (NHEADS / 8), 512, 0, stream>>>(
        xBCs, dtb, A_log, Dp, Sloc, Gbuf, ybuf);

    // ---- 4. gate + norm (reads zx z-cols; last use of zx) -> bf16 yb ----
    gate_norm_kernel<<<B_ * L_, 256, 0, stream>>>(zx, norm_w, ybuf, yb_hi);

    // ---- 5. mamba_out GEMM (pure bf16) -> padded bf16 tmpP ----
    zero_pads_kernel<<<12, 256, 0, stream>>>(tmpP_hi, tmpP_hi, D_MODEL);
    prep_cow_kernel<<<512, 256, 0, stream>>>(out_conv_w, cow_hi);
    tconv_kernel<<<dim3(D_MODEL / 32, D_INNER / 32), 256, 0, stream>>>(
        mamba_out_w, mow_hi, mow_lo, D_INNER, D_MODEL);
    gemm_mo_kernel<<<dim3(2, (B_ * L_) / 128), 256, 0, stream>>>(
        yb_hi, mow_hi, tmpP_hi);

    // ---- 6. conv_out as full-K GEMM (pure bf16, regular stores) ----
    gemm_co_kernel<<<dim3(1, (B_ * L_) / 128), 256, 0, stream>>>(
        tmpP_hi, cow_hi, out);
}

// Round 17
// 307.149 us; speedup vs baseline: 1.2955x; 1.0199x over previous
//
#include <hip/hip_runtime.h>
#include <math.h>

#define B_      4
#define L_      2048
#define IN_DIM  128
#define D_MODEL 256
#define OUT_DIM 128
#define D_STATE 16
#define D_INNER 768
#define NHEADS  256
#define HEADDIM 3
#define CONV_DIM 800
#define D_IN_PROJ 1824
#define DT_START (D_INNER + CONV_DIM)   // 1568

#define SCAN_NC 32
#define SCAN_CL 64
#define LPAD    2051        // L_ + 3 padded rows (row0 = left pad, rows 2049/2050 = right pad)

typedef short  short8 __attribute__((ext_vector_type(8)));
typedef float  f32x4  __attribute__((ext_vector_type(4)));

__device__ __forceinline__ unsigned short f2bf(float f) {
    unsigned int u = __float_as_uint(f);
    u = (u + 0x7fffu + ((u >> 16) & 1u)) >> 16;     // RN-to-even
    return (unsigned short)u;
}
__device__ __forceinline__ float bf2f(unsigned short h) {
    return __uint_as_float(((unsigned int)h) << 16);
}

// ---------------------------------------------------------------------------
// zero the 3 pad rows per batch of a padded split-bf16 tensor [B][LPAD][pitch]
// ---------------------------------------------------------------------------
__global__ __launch_bounds__(256) void zero_pads_kernel(
    unsigned short* __restrict__ ph, unsigned short* __restrict__ pl, int pitch)
{
    int t = blockIdx.x * 256 + threadIdx.x;
    int n = B_ * 3 * pitch;
    if (t < n) {
        int ch = t % pitch, rb = t / pitch;
        int b = rb / 3, ri = rb % 3;
        int row = (ri == 0) ? 0 : (ri == 1) ? (L_ + 1) : (L_ + 2);
        size_t off = ((size_t)b * LPAD + row) * pitch + ch;
        ph[off] = 0; pl[off] = 0;
    }
}

// ---------------------------------------------------------------------------
// transpose x [b][i][L] fp32 -> padded split-bf16 xT [b][LPAD][128], row l+1
// ---------------------------------------------------------------------------
__global__ __launch_bounds__(256) void transpose_x_kernel(
    const float* __restrict__ x, unsigned short* __restrict__ xh,
    unsigned short* __restrict__ xl)
{
    __shared__ float tile[32][33];
    int b = blockIdx.z;
    int l0 = blockIdx.x * 32, i0 = blockIdx.y * 32;
    int tx = threadIdx.x & 31, ty = threadIdx.x >> 5;   // ty 0..7
    const float* xb = x + (size_t)b * IN_DIM * L_;
    #pragma unroll
    for (int r = 0; r < 4; ++r)
        tile[ty + r * 8][tx] = xb[(size_t)(i0 + ty + r * 8) * L_ + l0 + tx];
    __syncthreads();
    #pragma unroll
    for (int r = 0; r < 4; ++r) {
        int l = l0 + ty + r * 8;
        float v = tile[tx][ty + r * 8];                  // x[b][i0+tx][l]
        size_t off = ((size_t)b * LPAD + l + 1) * IN_DIM + i0 + tx;
        unsigned short h = f2bf(v);
        xh[off] = h;
        xl[off] = f2bf(v - bf2f(h));
    }
}

// ---------------------------------------------------------------------------
// reindex+split conv_w [256][128][4] -> cw [256][512], kk = k*128+i
// ---------------------------------------------------------------------------
__global__ __launch_bounds__(256) void prep_cw_kernel(
    const float* __restrict__ w, unsigned short* __restrict__ wh,
    unsigned short* __restrict__ wl)
{
    int t = blockIdx.x * 256 + threadIdx.x;              // 256*512
    if (t < D_MODEL * 512) {
        int o = t >> 9, kk = t & 511;
        int k = kk >> 7, i = kk & 127;
        float v = w[((size_t)o * IN_DIM + i) * 4 + k];
        unsigned short h = f2bf(v);
        wh[t] = h; wl[t] = f2bf(v - bf2f(h));
    }
}

// ---------------------------------------------------------------------------
// reindex out_conv_w [128][256][4] -> cow [128][1024] bf16, kk = k*256+c
// ---------------------------------------------------------------------------
__global__ __launch_bounds__(256) void prep_cow_kernel(
    const float* __restrict__ w, unsigned short* __restrict__ wh)
{
    int t = blockIdx.x * 256 + threadIdx.x;              // 128*1024
    if (t < OUT_DIM * 1024) {
        int o = t >> 10, kk = t & 1023;
        int k = kk >> 8, c = kk & 255;
        wh[t] = f2bf(w[((size_t)o * D_MODEL + c) * 4 + k]);
    }
}

// ---------------------------------------------------------------------------
// transpose + split: src[K][N] fp32 -> dh/dl [N][K] bf16  (weight prep)
// ---------------------------------------------------------------------------
__global__ __launch_bounds__(256) void tconv_kernel(
    const float* __restrict__ src, unsigned short* __restrict__ dh,
    unsigned short* __restrict__ dl, int K, int N)
{
    __shared__ float tile[32][33];
    int k0 = blockIdx.y * 32, n0 = blockIdx.x * 32;
    int tx = threadIdx.x & 31, ty = threadIdx.x >> 5;
    #pragma unroll
    for (int r = 0; r < 4; ++r)
        tile[ty + r * 8][tx] = src[(size_t)(k0 + ty + r * 8) * N + n0 + tx];
    __syncthreads();
    #pragma unroll
    for (int r = 0; r < 4; ++r) {
        int n = n0 + ty + r * 8;
        float v = tile[tx][ty + r * 8];
        unsigned short h = f2bf(v);
        dh[(size_t)n * K + k0 + tx] = h;
        dl[(size_t)n * K + k0 + tx] = f2bf(v - bf2f(h));
    }
}

// ---------------------------------------------------------------------------
// in_proj GEMM, selective precision: tiles fully in z/xBC columns
// (n0+127 < DT_START) use pure bf16 (1 MFMA, hi-only staging); tiles touching
// dt columns keep the full 3-MFMA split (dt feeds exp/cumsum — error
// amplifies). Branch is block-uniform.
// ---------------------------------------------------------------------------
__global__ __launch_bounds__(256) void gemm_ip2_kernel(
    const unsigned short* __restrict__ Ah, const unsigned short* __restrict__ Al,
    const unsigned short* __restrict__ Bh, const unsigned short* __restrict__ Bl,
    float* __restrict__ C, int M, int N, int K)
{
    __shared__ __align__(16) unsigned short AsH[128][40];
    __shared__ __align__(16) unsigned short AsL[128][40];
    __shared__ __align__(16) unsigned short BsH[128][40];
    __shared__ __align__(16) unsigned short BsL[128][40];

    int m0 = blockIdx.y * 128, n0 = blockIdx.x * 128;
    int t = threadIdx.x;
    int wid = t >> 6, lane = t & 63;
    int wm = (wid >> 1) * 64, wn = (wid & 1) * 64;
    int fr = lane & 15, fq = lane >> 4;
    bool full = (n0 + 127 >= DT_START);

    f32x4 z4 = {0.f, 0.f, 0.f, 0.f};
    f32x4 acc[4][4];
    #pragma unroll
    for (int i = 0; i < 4; ++i)
        #pragma unroll
        for (int j = 0; j < 4; ++j) acc[i][j] = z4;

    if (!full) {
        // -------- fast path: pure bf16, hi staging only, 1 MFMA --------
        for (int k0 = 0; k0 < K; k0 += 32) {
            __syncthreads();
            #pragma unroll
            for (int p = 0; p < 2; ++p) {
                int idx = p * 256 + t;
                int row = idx >> 2, q = idx & 3;
                int koff = k0 + q * 8;
                *(float4*)&AsH[row][q * 8] =
                    *(const float4*)(Ah + (size_t)(m0 + row) * K + koff);
                int n = n0 + row;
                *(float4*)&BsH[row][q * 8] =
                    *(const float4*)(Bh + (size_t)n * K + koff);
            }
            __syncthreads();

            short8 ah[4], bh[4];
            #pragma unroll
            for (int i = 0; i < 4; ++i) {
                ah[i] = *(const short8*)&AsH[wm + i * 16 + fr][fq * 8];
                bh[i] = *(const short8*)&BsH[wn + i * 16 + fr][fq * 8];
            }
            #pragma unroll
            for (int i = 0; i < 4; ++i)
                #pragma unroll
                for (int j = 0; j < 4; ++j)
                    acc[i][j] = __builtin_amdgcn_mfma_f32_16x16x32_bf16(
                        ah[i], bh[j], acc[i][j], 0, 0, 0);
        }
    } else {
        // -------- full path: 3-MFMA split (dt columns) --------
        for (int k0 = 0; k0 < K; k0 += 32) {
            __syncthreads();
            #pragma unroll
            for (int p = 0; p < 2; ++p) {
                int idx = p * 256 + t;
                int row = idx >> 2, q = idx & 3;
                int koff = k0 + q * 8;
                *(float4*)&AsH[row][q * 8] =
                    *(const float4*)(Ah + (size_t)(m0 + row) * K + koff);
                *(float4*)&AsL[row][q * 8] =
                    *(const float4*)(Al + (size_t)(m0 + row) * K + koff);
                int n = n0 + row;
                float4 vbh = make_float4(0.f, 0.f, 0.f, 0.f), vbl = vbh;
                if (n < N) {
                    vbh = *(const float4*)(Bh + (size_t)n * K + koff);
                    vbl = *(const float4*)(Bl + (size_t)n * K + koff);
                }
                *(float4*)&BsH[row][q * 8] = vbh;
                *(float4*)&BsL[row][q * 8] = vbl;
            }
            __syncthreads();

            short8 ah[4], al[4], bh[4], bl[4];
            #pragma unroll
            for (int i = 0; i < 4; ++i) {
                ah[i] = *(const short8*)&AsH[wm + i * 16 + fr][fq * 8];
                al[i] = *(const short8*)&AsL[wm + i * 16 + fr][fq * 8];
                bh[i] = *(const short8*)&BsH[wn + i * 16 + fr][fq * 8];
                bl[i] = *(const short8*)&BsL[wn + i * 16 + fr][fq * 8];
            }
            #pragma unroll
            for (int i = 0; i < 4; ++i)
                #pragma unroll
                for (int j = 0; j < 4; ++j) {
                    acc[i][j] = __builtin_amdgcn_mfma_f32_16x16x32_bf16(
                        ah[i], bh[j], acc[i][j], 0, 0, 0);
                    acc[i][j] = __builtin_amdgcn_mfma_f32_16x16x32_bf16(
                        ah[i], bl[j], acc[i][j], 0, 0, 0);
                    acc[i][j] = __builtin_amdgcn_mfma_f32_16x16x32_bf16(
                        al[i], bh[j], acc[i][j], 0, 0, 0);
                }
        }
    }

    #pragma unroll
    for (int i = 0; i < 4; ++i) {
        int r0 = m0 + wm + i * 16 + fq * 4;
        #pragma unroll
        for (int j = 0; j < 4; ++j) {
            int cc = n0 + wn + j * 16 + fr;
            if (cc < N) {
                #pragma unroll
                for (int r = 0; r < 4; ++r)
                    C[(size_t)(r0 + r) * N + cc] = acc[i][j][r];
            }
        }
    }
}

// ---------------------------------------------------------------------------
// conv_in as GEMM: A = xT window, B = cw [256][512]. Epilogue: + conv_b,
// write split-bf16 u [8192][256].
// ---------------------------------------------------------------------------
__global__ __launch_bounds__(256) void gemm_ci_kernel(
    const unsigned short* __restrict__ Ah, const unsigned short* __restrict__ Al,
    const unsigned short* __restrict__ Bh, const unsigned short* __restrict__ Bl,
    const float* __restrict__ bias,
    unsigned short* __restrict__ Ch, unsigned short* __restrict__ Cl)
{
    const int K = 512;
    __shared__ __align__(16) unsigned short AsH[128][40];
    __shared__ __align__(16) unsigned short AsL[128][40];
    __shared__ __align__(16) unsigned short BsH[128][40];
    __shared__ __align__(16) unsigned short BsL[128][40];

    int m0 = blockIdx.y * 128, n0 = blockIdx.x * 128;
    int b = m0 >> 11;
    size_t abase = ((size_t)b * LPAD + (m0 & 2047)) * IN_DIM;
    int t = threadIdx.x;
    int wid = t >> 6, lane = t & 63;
    int wm = (wid >> 1) * 64, wn = (wid & 1) * 64;
    int fr = lane & 15, fq = lane >> 4;

    f32x4 z4 = {0.f, 0.f, 0.f, 0.f};
    f32x4 acc[4][4];
    #pragma unroll
    for (int i = 0; i < 4; ++i)
        #pragma unroll
        for (int j = 0; j < 4; ++j) acc[i][j] = z4;

    for (int k0 = 0; k0 < K; k0 += 32) {
        __syncthreads();
        #pragma unroll
        for (int p = 0; p < 2; ++p) {
            int idx = p * 256 + t;
            int row = idx >> 2, q = idx & 3;
            int koff = k0 + q * 8;
            *(float4*)&AsH[row][q * 8] =
                *(const float4*)(Ah + abase + (size_t)row * IN_DIM + koff);
            *(float4*)&AsL[row][q * 8] =
                *(const float4*)(Al + abase + (size_t)row * IN_DIM + koff);
            int n = n0 + row;
            *(float4*)&BsH[row][q * 8] = *(const float4*)(Bh + (size_t)n * K + koff);
            *(float4*)&BsL[row][q * 8] = *(const float4*)(Bl + (size_t)n * K + koff);
        }
        __syncthreads();

        short8 ah[4], al[4], bh[4], bl[4];
        #pragma unroll
        for (int i = 0; i < 4; ++i) {
            ah[i] = *(const short8*)&AsH[wm + i * 16 + fr][fq * 8];
            al[i] = *(const short8*)&AsL[wm + i * 16 + fr][fq * 8];
            bh[i] = *(const short8*)&BsH[wn + i * 16 + fr][fq * 8];
            bl[i] = *(const short8*)&BsL[wn + i * 16 + fr][fq * 8];
        }
        #pragma unroll
        for (int i = 0; i < 4; ++i)
            #pragma unroll
            for (int j = 0; j < 4; ++j) {
                acc[i][j] = __builtin_amdgcn_mfma_f32_16x16x32_bf16(
                    ah[i], bh[j], acc[i][j], 0, 0, 0);
                acc[i][j] = __builtin_amdgcn_mfma_f32_16x16x32_bf16(
                    ah[i], bl[j], acc[i][j], 0, 0, 0);
                acc[i][j] = __builtin_amdgcn_mfma_f32_16x16x32_bf16(
                    al[i], bh[j], acc[i][j], 0, 0, 0);
            }
    }

    #pragma unroll
    for (int i = 0; i < 4; ++i) {
        int r0 = m0 + wm + i * 16 + fq * 4;
        #pragma unroll
        for (int j = 0; j < 4; ++j) {
            int cc = n0 + wn + j * 16 + fr;
            float bc = bias[cc];
            #pragma unroll
            for (int r = 0; r < 4; ++r) {
                float v = acc[i][j][r] + bc;
                unsigned short h = f2bf(v);
                size_t off = (size_t)(r0 + r) * D_MODEL + cc;
                Ch[off] = h;
                Cl[off] = f2bf(v - bf2f(h));
            }
        }
    }
}

// ---------------------------------------------------------------------------
// gemm2 (mamba_out), pure bf16 (post-scan path; error budget allows).
// ---------------------------------------------------------------------------
__global__ __launch_bounds__(256) void gemm_mo_kernel(
    const unsigned short* __restrict__ Ah, const unsigned short* __restrict__ Bh,
    unsigned short* __restrict__ Ch)
{
    const int K = D_INNER;
    __shared__ __align__(16) unsigned short AsH[128][40];
    __shared__ __align__(16) unsigned short BsH[128][40];

    int m0 = blockIdx.y * 128, n0 = blockIdx.x * 128;
    int t = threadIdx.x;
    int wid = t >> 6, lane = t & 63;
    int wm = (wid >> 1) * 64, wn = (wid & 1) * 64;
    int fr = lane & 15, fq = lane >> 4;

    f32x4 z4 = {0.f, 0.f, 0.f, 0.f};
    f32x4 acc[4][4];
    #pragma unroll
    for (int i = 0; i < 4; ++i)
        #pragma unroll
        for (int j = 0; j < 4; ++j) acc[i][j] = z4;

    for (int k0 = 0; k0 < K; k0 += 32) {
        __syncthreads();
        #pragma unroll
        for (int p = 0; p < 2; ++p) {
            int idx = p * 256 + t;
            int row = idx >> 2, q = idx & 3;
            int koff = k0 + q * 8;
            *(float4*)&AsH[row][q * 8] =
                *(const float4*)(Ah + (size_t)(m0 + row) * K + koff);
            int n = n0 + row;
            *(float4*)&BsH[row][q * 8] = *(const float4*)(Bh + (size_t)n * K + koff);
        }
        __syncthreads();

        short8 ah[4], bh[4];
        #pragma unroll
        for (int i = 0; i < 4; ++i) {
            ah[i] = *(const short8*)&AsH[wm + i * 16 + fr][fq * 8];
            bh[i] = *(const short8*)&BsH[wn + i * 16 + fr][fq * 8];
        }
        #pragma unroll
        for (int i = 0; i < 4; ++i)
            #pragma unroll
            for (int j = 0; j < 4; ++j)
                acc[i][j] = __builtin_amdgcn_mfma_f32_16x16x32_bf16(
                    ah[i], bh[j], acc[i][j], 0, 0, 0);
    }

    int b = m0 >> 11;
    #pragma unroll
    for (int i = 0; i < 4; ++i) {
        int r0 = m0 + wm + i * 16 + fq * 4;
        #pragma unroll
        for (int j = 0; j < 4; ++j) {
            int cc = n0 + wn + j * 16 + fr;
            #pragma unroll
            for (int r = 0; r < 4; ++r) {
                int l = (r0 + r) & 2047;
                size_t off = ((size_t)b * LPAD + l + 1) * D_MODEL + cc;
                Ch[off] = f2bf(acc[i][j][r]);
            }
        }
    }
}

// ---------------------------------------------------------------------------
// conv_out as GEMM, pure bf16, full-K. 64 blocks.
// ---------------------------------------------------------------------------
__global__ __launch_bounds__(256) void gemm_co_kernel(
    const unsigned short* __restrict__ Ah, const unsigned short* __restrict__ Bh,
    float* __restrict__ out)
{
    const int K = 1024;
    __shared__ __align__(16) unsigned short AsH[128][40];
    __shared__ __align__(16) unsigned short BsH[128][40];

    int m0 = blockIdx.y * 128;
    int b = m0 >> 11, l0t = m0 & 2047;
    size_t abase = ((size_t)b * LPAD + l0t) * D_MODEL;
    int t = threadIdx.x;
    int wid = t >> 6, lane = t & 63;
    int wm = (wid >> 1) * 64, wn = (wid & 1) * 64;
    int fr = lane & 15, fq = lane >> 4;

    f32x4 z4 = {0.f, 0.f, 0.f, 0.f};
    f32x4 acc[4][4];
    #pragma unroll
    for (int i = 0; i < 4; ++i)
        #pragma unroll
        for (int j = 0; j < 4; ++j) acc[i][j] = z4;

    for (int k0 = 0; k0 < K; k0 += 32) {
        __syncthreads();
        #pragma unroll
        for (int p = 0; p < 2; ++p) {
            int idx = p * 256 + t;
            int row = idx >> 2, q = idx & 3;
            int koff = k0 + q * 8;
            *(float4*)&AsH[row][q * 8] =
                *(const float4*)(Ah + abase + (size_t)row * D_MODEL + koff);
            *(float4*)&BsH[row][q * 8] = *(const float4*)(Bh + (size_t)row * K + koff);
        }
        __syncthreads();

        short8 ah[4], bh[4];
        #pragma unroll
        for (int i = 0; i < 4; ++i) {
            ah[i] = *(const short8*)&AsH[wm + i * 16 + fr][fq * 8];
            bh[i] = *(const short8*)&BsH[wn + i * 16 + fr][fq * 8];
        }
        #pragma unroll
        for (int i = 0; i < 4; ++i)
            #pragma unroll
            for (int j = 0; j < 4; ++j)
                acc[i][j] = __builtin_amdgcn_mfma_f32_16x16x32_bf16(
                    ah[i], bh[j], acc[i][j], 0, 0, 0);
    }

    #pragma unroll
    for (int i = 0; i < 4; ++i) {
        int lr = l0t + wm + i * 16 + fq * 4;
        #pragma unroll
        for (int j = 0; j < 4; ++j) {
            int cc = wn + j * 16 + fr;                  // o in 0..127
            float* dst = out + ((size_t)(b * OUT_DIM + cc)) * L_ + lr;
            float4 ov = make_float4(acc[i][j][0], acc[i][j][1],
                                    acc[i][j][2], acc[i][j][3]);
            *(float4*)dst = ov;
        }
    }
}

// ---------------------------------------------------------------------------
// K3: dt = softplus(dt_raw + dt_bias)    [B*L, 256]
// ---------------------------------------------------------------------------
__global__ __launch_bounds__(256) void dt_kernel(
    const float* __restrict__ zx, const float* __restrict__ dt_bias,
    float* __restrict__ dtb)
{
    int idx = blockIdx.x * 256 + threadIdx.x;
    int h  = idx & 255;
    int bl = idx >> 8;
    float v = zx[(size_t)bl * D_IN_PROJ + (D_INNER + CONV_DIM) + h] + dt_bias[h];
    float sp = (v > 20.f) ? v : log1pf(expf(v));
    dtb[idx] = sp;
}

// ---------------------------------------------------------------------------
// K4: causal depthwise conv + bias + SiLU. 8 l-values per thread.
// ---------------------------------------------------------------------------
__global__ __launch_bounds__(256) void dwconv_kernel(
    const float* __restrict__ zx, const float* __restrict__ w,
    const float* __restrict__ bias, float* __restrict__ xBCs)
{
    int idx = blockIdx.x * 256 + threadIdx.x;   // over B * L/8 * 800
    int c   = idx % CONV_DIM;
    int bl8 = idx / CONV_DIM;
    int b  = bl8 >> 8;               // L/8 = 256
    int l0 = (bl8 & 255) * 8;
    float4 wv = *(const float4*)&w[c * 4];
    float bi = bias[c];
    const float* base = zx + ((size_t)(b * L_ + l0)) * D_IN_PROJ + D_INNER + c;
    float r[11];
    #pragma unroll
    for (int k = 0; k < 11; ++k) {
        int l = l0 - 3 + k;
        r[k] = (l >= 0) ? base[(ptrdiff_t)(k - 3) * D_IN_PROJ] : 0.f;
    }
    #pragma unroll
    for (int i = 0; i < 8; ++i) {
        float acc = bi;
        acc = fmaf(r[i + 0], wv.x, acc);
        acc = fmaf(r[i + 1], wv.y, acc);
        acc = fmaf(r[i + 2], wv.z, acc);
        acc = fmaf(r[i + 3], wv.w, acc);
        float s = acc / (1.f + expf(-acc));
        xBCs[((size_t)(b * L_ + l0 + i)) * CONV_DIM + c] = s;
    }
}

// ---------------------------------------------------------------------------
// K5g: G[i][j] = C_i . B_j  per (b,chunk).  bid = b*32+c -> XCD = c%8,
// matching the scan swizzle (bc & 7) so G stays in the producing XCD's L2.
// ---------------------------------------------------------------------------
__global__ __launch_bounds__(256) void gmat_kernel(
    const float* __restrict__ xBCs, float* __restrict__ G)
{
    __shared__ float Bs[64][16];
    __shared__ float Cs[64][16];
    int c = blockIdx.x & 31, b = blockIdx.x >> 5;
    int t = threadIdx.x;
    int row0 = b * L_ + c * SCAN_CL;
    {
        int j = t >> 2, q = t & 3;
        const float* r = xBCs + (size_t)(row0 + j) * CONV_DIM + D_INNER;
        *(float4*)&Bs[j][q * 4] = *(const float4*)(r + q * 4);
        *(float4*)&Cs[j][q * 4] = *(const float4*)(r + D_STATE + q * 4);
    }
    __syncthreads();
    int i = t >> 2, jq = t & 3;
    float4 c0 = *(const float4*)&Cs[i][0];
    float4 c1 = *(const float4*)&Cs[i][4];
    float4 c2 = *(const float4*)&Cs[i][8];
    float4 c3 = *(const float4*)&Cs[i][12];
    float dot[16];
    #pragma unroll
    for (int jj = 0; jj < 16; ++jj) {
        int j = jq * 16 + jj;
        float4 b0 = *(const float4*)&Bs[j][0];
        float4 b1 = *(const float4*)&Bs[j][4];
        float4 b2 = *(const float4*)&Bs[j][8];
        float4 b3 = *(const float4*)&Bs[j][12];
        float d = c0.x * b0.x + c0.y * b0.y + c0.z * b0.z + c0.w * b0.w;
        d = fmaf(c1.x, b1.x, d); d = fmaf(c1.y, b1.y, d);
        d = fmaf(c1.z, b1.z, d); d = fmaf(c1.w, b1.w, d);
        d = fmaf(c2.x, b2.x, d); d = fmaf(c2.y, b2.y, d);
        d = fmaf(c2.z, b2.z, d); d = fmaf(c2.w, b2.w, d);
        d = fmaf(c3.x, b3.x, d); d = fmaf(c3.y, b3.y, d);
        d = fmaf(c3.z, b3.z, d); d = fmaf(c3.w, b3.w, d);
        dot[jj] = d;
    }
    float* gout = G + ((size_t)blockIdx.x * 64 + i) * 64 + jq * 16;
    #pragma unroll
    for (int q = 0; q < 4; ++q)
        *(float4*)(gout + q * 4) = make_float4(dot[q*4], dot[q*4+1], dot[q*4+2], dot[q*4+3]);
}

// ---------------------------------------------------------------------------
// XCD-locality swizzle: all 32 hg blocks of one (b,c) share bid%8 -> same XCD
// bid = (bc>>3)<<8 | hg<<3 | (bc&7);  bc = b*32+c.
// ---------------------------------------------------------------------------
__device__ __forceinline__ void scan_decode(int bid, int& b, int& c, int& hg)
{
    int bcl = bid & 7;
    hg = (bid >> 3) & 31;
    int bc = ((bid >> 8) << 3) | bcl;
    c = bc & 31;
    b = bc >> 5;
}

// ---------------------------------------------------------------------------
// K5a: chunk-local state build. 512 threads = 8 waves; ONE head per wave.
// Pk in SoA (stride 66) to avoid LDS bank conflicts.
// ---------------------------------------------------------------------------
__global__ __launch_bounds__(512) void scan_local2(
    const float* __restrict__ xBCs, const float* __restrict__ dtb,
    const float* __restrict__ A_log,
    float* __restrict__ Sloc, float* __restrict__ prodA)
{
    __shared__ float  BsT[16][68];          // [n][row], padded
    __shared__ float  Pk0[8][66], Pk1[8][66], Pk2[8][66], Pkw[8][66];
    __shared__ float  UT[8][3][64];
    int b, c, hg;
    scan_decode(blockIdx.x, b, c, hg);
    int h0 = hg * 8;
    int t = threadIdx.x;
    int row0 = b * L_ + c * SCAN_CL;

    if (t < 256) {   // B tile (coalesced)
        int j = t >> 2, q = t & 3;
        const float* r = xBCs + (size_t)(row0 + j) * CONV_DIM;
        float4 bv = *(const float4*)(r + D_INNER + q * 4);
        BsT[q*4+0][j] = bv.x; BsT[q*4+1][j] = bv.y;
        BsT[q*4+2][j] = bv.z; BsT[q*4+3][j] = bv.w;
    }
    {   // Pk staging: one entry per thread (dense per row); SoA writes
        int hh = t & 7, j = t >> 3;
        float dtv = dtb[(size_t)(row0 + j) * NHEADS + h0 + hh];
        const float* xr = xBCs + (size_t)(row0 + j) * CONV_DIM + (h0 + hh) * 3;
        Pk0[hh][j] = dtv * xr[0];
        Pk1[hh][j] = dtv * xr[1];
        Pk2[hh][j] = dtv * xr[2];
        Pkw[hh][j] = dtv;
    }
    __syncthreads();

    int wv = t >> 6, lane = t & 63;
    int hh = wv;
    int h = h0 + hh;
    int p = lane >> 4, n = lane & 15;
    int pc = (p < 3) ? p : 2;

    float pkx = Pk0[hh][lane], pky = Pk1[hh][lane], pkz = Pk2[hh][lane];
    float pkw = Pkw[hh][lane];
    float A = -__expf(A_log[h]);
    float cum = pkw * A;
    #pragma unroll
    for (int off = 1; off < 64; off <<= 1) {
        float sv = __shfl_up(cum, off);
        if (lane >= off) cum += sv;
    }
    float cum63 = __shfl(cum, 63);
    float wf = __expf(cum63 - cum);
    UT[hh][0][lane] = wf * pkx;
    UT[hh][1][lane] = wf * pky;
    UT[hh][2][lane] = wf * pkz;
    float state = 0.f;
    #pragma unroll
    for (int q = 0; q < 16; ++q) {
        float4 Bv = *(const float4*)&BsT[n][q * 4];
        float4 Uv = *(const float4*)&UT[hh][pc][q * 4];
        state = fmaf(Uv.x, Bv.x, state);
        state = fmaf(Uv.y, Bv.y, state);
        state = fmaf(Uv.z, Bv.z, state);
        state = fmaf(Uv.w, Bv.w, state);
    }
    size_t bh = (size_t)(b * NHEADS + h);
    if (p < 3) Sloc[(bh * SCAN_NC + c) * 48 + p * 16 + n] = state;
    if (lane == 0) prodA[bh * SCAN_NC + c] = __expf(cum63);
}

// ---------------------------------------------------------------------------
// K5b: sequential prefix over chunks, in place on Sloc
// ---------------------------------------------------------------------------
__global__ __launch_bounds__(256) void scan_prefix_kernel(
    float* __restrict__ Sloc, const float* __restrict__ prodA)
{
    int wv   = blockIdx.x * 4 + (threadIdx.x >> 6);
    int lane = threadIdx.x & 63;
    int p = lane >> 4, n = lane & 15;
    bool act = (p < 3);
    int l48 = ((p < 3) ? p : 2) * 16 + n;
    size_t base = (size_t)wv * SCAN_NC;

    float cur = 0.f;
    for (int c = 0; c < SCAN_NC; ++c) {
        float s  = Sloc[(base + c) * 48 + l48];
        float pa = prodA[base + c];
        if (act) Sloc[(base + c) * 48 + l48] = cur;
        cur = fmaf(pa, cur, s);
    }
}

// ---------------------------------------------------------------------------
// K5c: chunk-matmul final scan. 512 threads = 8 waves; ONE head per wave.
// G staged in LDS once per block; Pk in SoA (stride 66).
// ---------------------------------------------------------------------------
__global__ __launch_bounds__(512) void scan_final2(
    const float* __restrict__ xBCs, const float* __restrict__ dtb,
    const float* __restrict__ A_log, const float* __restrict__ Dp,
    const float* __restrict__ Sinit, const float* __restrict__ G,
    float* __restrict__ y)
{
    __shared__ float  Pk0[8][66], Pk1[8][66], Pk2[8][66], Pkw[8][66];
    __shared__ float4 XW[8][64];
    __shared__ float  Sin[8][48];
    __shared__ float  CsT[16][66];          // [n][row]
    __shared__ float  ysr[64][25];          // [row][24 ch] padded (stride 25)
    __shared__ float  Gs[64][65];           // G tile, odd stride
    int b, c, hg;
    scan_decode(blockIdx.x, b, c, hg);
    int h0 = hg * 8;
    int t = threadIdx.x;
    int row0 = b * L_ + c * SCAN_CL;

    if (t < 256) {   // C tile (coalesced)
        int j = t >> 2, q = t & 3;
        const float* r = xBCs + (size_t)(row0 + j) * CONV_DIM + D_INNER + D_STATE;
        float4 cv = *(const float4*)(r + q * 4);
        CsT[q*4+0][j] = cv.x; CsT[q*4+1][j] = cv.y;
        CsT[q*4+2][j] = cv.z; CsT[q*4+3][j] = cv.w;
    }
    {   // Pk staging: one entry per thread; SoA writes
        int hh = t & 7, j = t >> 3;
        float dtv = dtb[(size_t)(row0 + j) * NHEADS + h0 + hh];
        const float* xr = xBCs + (size_t)(row0 + j) * CONV_DIM + (h0 + hh) * 3;
        Pk0[hh][j] = dtv * xr[0];
        Pk1[hh][j] = dtv * xr[1];
        Pk2[hh][j] = dtv * xr[2];
        Pkw[hh][j] = dtv;
    }
    if (t < 384) {   // Sin staging: 8 heads x 48
        int hh = t / 48, k = t % 48;
        Sin[hh][k] = Sinit[((size_t)(b * NHEADS + h0 + hh) * SCAN_NC + c) * 48 + k];
    }
    {   // G staging: 4096 floats, coalesced float4 global reads
        const float* Gsrc = G + (size_t)(b * SCAN_NC + c) * 4096;
        #pragma unroll
        for (int e = 0; e < 2; ++e) {
            int idx = e * 512 + t;              // float4 index 0..1023
            int row = idx >> 4, cq = (idx & 15) * 4;
            float4 gv = *(const float4*)(Gsrc + (size_t)idx * 4);
            Gs[row][cq + 0] = gv.x;
            Gs[row][cq + 1] = gv.y;
            Gs[row][cq + 2] = gv.z;
            Gs[row][cq + 3] = gv.w;
        }
    }
    __syncthreads();

    int wv = t >> 6, lane = t & 63;
    int hh = wv;
    int h = h0 + hh;
    int I = lane >> 4;

    float pkx = Pk0[hh][lane], pky = Pk1[hh][lane], pkz = Pk2[hh][lane];
    float pkw = Pkw[hh][lane];
    float A = -__expf(A_log[h]);
    float cum = pkw * A;
    #pragma unroll
    for (int off = 1; off < 64; off <<= 1) {
        float sv = __shfl_up(cum, off);
        if (lane >= off) cum += sv;
    }
    float e0 = __shfl(cum, 15);
    float e1 = __shfl(cum, 31);
    float e2 = __shfl(cum, 47);
    float e3 = __shfl(cum, 63);
    int ia = (I << 4) - 1;
    float AIr = __shfl(cum, ia < 0 ? 0 : ia);
    float AI = (I == 0) ? 0.f : AIr;
    float ri = __expf(cum - AI);
    float Eo = (I == 0) ? e0 : (I == 1) ? e1 : (I == 2) ? e2 : e3;
    float wj = __expf(Eo - cum);
    XW[hh][lane] = make_float4(wj * pkx, wj * pky, wj * pkz, 0.f);
    Pkw[hh][lane] = cum;                    // publish cum_j (wave-local)
    float S0 = (I > 0) ? __expf(AI - e0) : 0.f;
    float S1 = (I > 1) ? __expf(AI - e1) : 0.f;
    float S2 = (I > 2) ? __expf(AI - e2) : 0.f;
    float ecum = __expf(cum);

    float acc0 = 0.f, acc1 = 0.f, acc2 = 0.f;
    #pragma unroll
    for (int J = 0; J < 3; ++J) {
        float SJ = (J == 0) ? S0 : (J == 1) ? S1 : S2;
        float t0 = 0.f, t1 = 0.f, t2 = 0.f;
        #pragma unroll
        for (int kk = 0; kk < 16; ++kk) {
            float gk = Gs[lane][J * 16 + kk];
            float4 u = XW[hh][J * 16 + kk];
            t0 = fmaf(gk, u.x, t0);
            t1 = fmaf(gk, u.y, t1);
            t2 = fmaf(gk, u.z, t2);
        }
        acc0 = fmaf(SJ, t0, acc0);
        acc1 = fmaf(SJ, t1, acc1);
        acc2 = fmaf(SJ, t2, acc2);
    }

    float d0 = 0.f, d1 = 0.f, d2 = 0.f;
    #pragma unroll
    for (int kk = 0; kk < 16; ++kk) {
        int j = (I << 4) + kk;
        float gk = Gs[lane][j];
        float e = __expf(cum - Pkw[hh][j]);
        float m = (j <= lane) ? e : 0.f;
        float mg = m * gk;
        d0 = fmaf(mg, Pk0[hh][j], d0);
        d1 = fmaf(mg, Pk1[hh][j], d1);
        d2 = fmaf(mg, Pk2[hh][j], d2);
    }

    float s0 = 0.f, s1 = 0.f, s2 = 0.f;
    #pragma unroll
    for (int nq = 0; nq < 16; ++nq) {
        float Cv = CsT[nq][lane];
        s0 = fmaf(Cv, Sin[hh][nq],      s0);
        s1 = fmaf(Cv, Sin[hh][16 + nq], s1);
        s2 = fmaf(Cv, Sin[hh][32 + nq], s2);
    }

    float rdt = 1.0f / pkw;
    float Dh = Dp[h];
    float* yr = &ysr[lane][hh * 3];
    yr[0] = fmaf(ri, acc0, d0) + fmaf(ecum, s0, Dh * (pkx * rdt));
    yr[1] = fmaf(ri, acc1, d1) + fmaf(ecum, s1, Dh * (pky * rdt));
    yr[2] = fmaf(ri, acc2, d2) + fmaf(ecum, s2, Dh * (pkz * rdt));
    __syncthreads();

    {   // coalesced epilogue: 24 contiguous channels per row
        int i2 = t >> 3, q2 = t & 7;
        float* dst = y + (size_t)(row0 + i2) * D_INNER + hg * 24 + q2 * 3;
        dst[0] = ysr[i2][q2 * 3 + 0];
        dst[1] = ysr[i2][q2 * 3 + 1];
        dst[2] = ysr[i2][q2 * 3 + 2];
    }
}

// ---------------------------------------------------------------------------
// K6: y = y * silu(z); RMSNorm over 768; * norm_w.  Writes plain bf16 output.
// ---------------------------------------------------------------------------
__global__ __launch_bounds__(256) void gate_norm_kernel(
    const float* __restrict__ zx, const float* __restrict__ norm_w,
    const float* __restrict__ y, unsigned short* __restrict__ yh)
{
    int bl = blockIdx.x;
    int t  = threadIdx.x;
    const float* zrow = zx + (size_t)bl * D_IN_PROJ;
    const float* yrow = y + (size_t)bl * D_INNER;

    float v[3];
    float ss = 0.f;
    #pragma unroll
    for (int j = 0; j < 3; ++j) {
        int i = t + j * 256;
        float z = zrow[i];
        float s = z / (1.f + expf(-z));
        float val = yrow[i] * s;
        v[j] = val;
        ss += val * val;
    }
    ss += __shfl_xor(ss, 32);
    ss += __shfl_xor(ss, 16);
    ss += __shfl_xor(ss, 8);
    ss += __shfl_xor(ss, 4);
    ss += __shfl_xor(ss, 2);
    ss += __shfl_xor(ss, 1);
    __shared__ float red[4];
    int lane = t & 63, wid = t >> 6;
    if (lane == 0) red[wid] = ss;
    __syncthreads();
    float tot = red[0] + red[1] + red[2] + red[3];
    float rs = rsqrtf(tot * (1.f / D_INNER) + 1e-5f);
    #pragma unroll
    for (int j = 0; j < 3; ++j) {
        int i = t + j * 256;
        float o = v[j] * rs * norm_w[i];
        yh[(size_t)bl * D_INNER + i] = f2bf(o);
    }
}

// ---------------------------------------------------------------------------
extern "C" void kernel_launch(void* const* d_in, const int* in_sizes, int n_in,
                              void* d_out, int out_size, void* d_ws, size_t ws_size,
                              hipStream_t stream)
{
    const float* x           = (const float*)d_in[0];
    const float* conv_w      = (const float*)d_in[1];
    const float* conv_b      = (const float*)d_in[2];
    const float* in_proj_w   = (const float*)d_in[3];
    const float* dw_conv_w   = (const float*)d_in[4];
    const float* dw_conv_b   = (const float*)d_in[5];
    const float* dt_bias     = (const float*)d_in[6];
    const float* A_log       = (const float*)d_in[7];
    const float* Dp          = (const float*)d_in[8];
    const float* norm_w      = (const float*)d_in[9];
    const float* mamba_out_w = (const float*)d_in[10];
    const float* out_conv_w  = (const float*)d_in[11];
    float* out = (float*)d_out;
    float* ws  = (float*)d_ws;

    // ---- workspace layout (floats) ----
    float* S0   = ws;                        //  2,097,152  Gbuf+Sloc / late: cow
    float* zx   = S0 + 2097152;              // 14,942,208  early: xT+cw / late: tmpP+mow
    float* xBCs = zx + 14942208;             //  6,553,600  early: ipw / late: yb
    float* dtb  = xBCs + 6553600;            //  2,097,152
    float* ybuf = dtb + 2097152;             //  6,291,456  early: prodA+u

    float* Gbuf = S0;                        // 524,288
    float* Sloc = S0 + 524288;               // 1,572,864
    unsigned short* cow_hi = (unsigned short*)S0;              // late, 131,072 ush

    unsigned short* xT_hi = (unsigned short*)zx;
    unsigned short* xT_lo = (unsigned short*)(zx + 525056);
    unsigned short* cw_hi = (unsigned short*)(zx + 1050112);
    unsigned short* cw_lo = (unsigned short*)(zx + 1115648);
    unsigned short* tmpP_hi = (unsigned short*)zx;             // late, 2,100,224 ush
    unsigned short* mow_hi  = (unsigned short*)(zx + 2100224); // 196,608 ush
    unsigned short* mow_lo  = (unsigned short*)(zx + 2198528); // written, unused

    unsigned short* ipw_hi = (unsigned short*)xBCs;
    unsigned short* ipw_lo = (unsigned short*)(xBCs + 233472);
    unsigned short* yb_hi  = (unsigned short*)xBCs;            // after scan_final

    float* prodA = ybuf;
    unsigned short* u_hi = (unsigned short*)(ybuf + 32768);
    unsigned short* u_lo = (unsigned short*)(ybuf + 32768 + 1048576);

    // ---- 1. conv_in as GEMM ----
    zero_pads_kernel<<<6, 256, 0, stream>>>(xT_hi, xT_lo, IN_DIM);
    transpose_x_kernel<<<dim3(L_ / 32, IN_DIM / 32, B_), 256, 0, stream>>>(
        x, xT_hi, xT_lo);
    prep_cw_kernel<<<512, 256, 0, stream>>>(conv_w, cw_hi, cw_lo);
    gemm_ci_kernel<<<dim3(2, (B_ * L_) / 128), 256, 0, stream>>>(
        xT_hi, xT_lo, cw_hi, cw_lo, conv_b, u_hi, u_lo);

    // ---- 2. in_proj GEMM (selective precision: split only for dt tiles) ----
    tconv_kernel<<<dim3(D_IN_PROJ / 32, D_MODEL / 32), 256, 0, stream>>>(
        in_proj_w, ipw_hi, ipw_lo, D_MODEL, D_IN_PROJ);
    gemm_ip2_kernel<<<dim3((D_IN_PROJ + 127) / 128, (B_ * L_) / 128), 256, 0, stream>>>(
        u_hi, u_lo, ipw_hi, ipw_lo, zx, B_ * L_, D_IN_PROJ, D_MODEL);

    // ---- 3. elementwise + scan ----
    dt_kernel<<<(B_ * L_ * NHEADS) / 256, 256, 0, stream>>>(zx, dt_bias, dtb);
    dwconv_kernel<<<(B_ * (L_ / 8) * CONV_DIM) / 256, 256, 0, stream>>>(
        zx, dw_conv_w, dw_conv_b, xBCs);
    gmat_kernel<<<B_ * SCAN_NC, 256, 0, stream>>>(xBCs, Gbuf);
    scan_local2<<<B_ * SCAN_NC * (NHEADS / 8), 512, 0, stream>>>(
        xBCs, dtb, A_log, Sloc, prodA);
    scan_prefix_kernel<<<(B_ * NHEADS) / 4, 256, 0, stream>>>(Sloc, prodA);
    scan_final2<<<B_ * SCAN_NC * (NHEADS / 8), 512, 0, stream>>>(
        xBCs, dtb, A_log, Dp, Sloc, Gbuf, ybuf);

    // ---- 4. gate + norm (reads zx z-cols; last use of zx) -> bf16 yb ----
    gate_norm_kernel<<<B_ * L_, 256, 0, stream>>>(zx, norm_w, ybuf, yb_hi);

    // ---- 5. mamba_out GEMM (pure bf16) -> padded bf16 tmpP ----
    zero_pads_kernel<<<12, 256, 0, stream>>>(tmpP_hi, tmpP_hi, D_MODEL);
    prep_cow_kernel<<<512, 256, 0, stream>>>(out_conv_w, cow_hi);
    tconv_kernel<<<dim3(D_MODEL / 32, D_INNER / 32), 256, 0, stream>>>(
        mamba_out_w, mow_hi, mow_lo, D_INNER, D_MODEL);
    gemm_mo_kernel<<<dim3(2, (B_ * L_) / 128), 256, 0, stream>>>(
        yb_hi, mow_hi, tmpP_hi);

    // ---- 6. conv_out as full-K GEMM (pure bf16, regular stores) ----
    gemm_co_kernel<<<dim3(1, (B_ * L_) / 128), 256, 0, stream>>>(
        tmpP_hi, cow_hi, out);
}

// Round 18
// 297.694 us; speedup vs baseline: 1.3366x; 1.0318x over previous
//
#include <hip/hip_runtime.h>
#include <math.h>

#define B_      4
#define L_      2048
#define IN_DIM  128
#define D_MODEL 256
#define OUT_DIM 128
#define D_STATE 16
#define D_INNER 768
#define NHEADS  256
#define HEADDIM 3
#define CONV_DIM 800
#define D_IN_PROJ 1824
#define DT_START (D_INNER + CONV_DIM)   // 1568

#define SCAN_NC 32
#define SCAN_CL 64
#define LPAD    2051        // L_ + 3 padded rows (row0 = left pad, rows 2049/2050 = right pad)

typedef short  short8 __attribute__((ext_vector_type(8)));
typedef float  f32x4  __attribute__((ext_vector_type(4)));

__device__ __forceinline__ unsigned short f2bf(float f) {
    unsigned int u = __float_as_uint(f);
    u = (u + 0x7fffu + ((u >> 16) & 1u)) >> 16;     // RN-to-even
    return (unsigned short)u;
}
__device__ __forceinline__ float bf2f(unsigned short h) {
    return __uint_as_float(((unsigned int)h) << 16);
}

// ---------------------------------------------------------------------------
// prep_early: blocks 0..5 zero xT pads (hi+lo); blocks 6..517 reindex+split
// conv_w [256][128][4] -> cw [256][512], kk = k*128+i
// ---------------------------------------------------------------------------
__global__ __launch_bounds__(256) void prep_early_kernel(
    unsigned short* __restrict__ xh, unsigned short* __restrict__ xl,
    const float* __restrict__ cw, unsigned short* __restrict__ cwh,
    unsigned short* __restrict__ cwl)
{
    if (blockIdx.x < 6) {
        int t = blockIdx.x * 256 + threadIdx.x;
        int n = B_ * 3 * IN_DIM;
        if (t < n) {
            int ch = t % IN_DIM, rb = t / IN_DIM;
            int b = rb / 3, ri = rb % 3;
            int row = (ri == 0) ? 0 : (ri == 1) ? (L_ + 1) : (L_ + 2);
            size_t off = ((size_t)b * LPAD + row) * IN_DIM + ch;
            xh[off] = 0; xl[off] = 0;
        }
    } else {
        int t = (blockIdx.x - 6) * 256 + threadIdx.x;   // 256*512
        if (t < D_MODEL * 512) {
            int o = t >> 9, kk = t & 511;
            int k = kk >> 7, i = kk & 127;
            float v = cw[((size_t)o * IN_DIM + i) * 4 + k];
            unsigned short h = f2bf(v);
            cwh[t] = h; cwl[t] = f2bf(v - bf2f(h));
        }
    }
}

// ---------------------------------------------------------------------------
// prep_late: blocks 0..511 reindex out_conv_w -> cow bf16 [128][1024];
// blocks 512..523 zero tmpP_hi pads
// ---------------------------------------------------------------------------
__global__ __launch_bounds__(256) void prep_late_kernel(
    const float* __restrict__ cow, unsigned short* __restrict__ cowh,
    unsigned short* __restrict__ th)
{
    if (blockIdx.x < 512) {
        int t = blockIdx.x * 256 + threadIdx.x;          // 128*1024
        if (t < OUT_DIM * 1024) {
            int o = t >> 10, kk = t & 1023;
            int k = kk >> 8, c = kk & 255;
            cowh[t] = f2bf(cow[((size_t)o * D_MODEL + c) * 4 + k]);
        }
    } else {
        int t = (blockIdx.x - 512) * 256 + threadIdx.x;
        int n = B_ * 3 * D_MODEL;
        if (t < n) {
            int ch = t % D_MODEL, rb = t / D_MODEL;
            int b = rb / 3, ri = rb % 3;
            int row = (ri == 0) ? 0 : (ri == 1) ? (L_ + 1) : (L_ + 2);
            size_t off = ((size_t)b * LPAD + row) * D_MODEL + ch;
            th[off] = 0;
        }
    }
}

// ---------------------------------------------------------------------------
// transpose x [b][i][L] fp32 -> padded split-bf16 xT [b][LPAD][128], row l+1
// ---------------------------------------------------------------------------
__global__ __launch_bounds__(256) void transpose_x_kernel(
    const float* __restrict__ x, unsigned short* __restrict__ xh,
    unsigned short* __restrict__ xl)
{
    __shared__ float tile[32][33];
    int b = blockIdx.z;
    int l0 = blockIdx.x * 32, i0 = blockIdx.y * 32;
    int tx = threadIdx.x & 31, ty = threadIdx.x >> 5;   // ty 0..7
    const float* xb = x + (size_t)b * IN_DIM * L_;
    #pragma unroll
    for (int r = 0; r < 4; ++r)
        tile[ty + r * 8][tx] = xb[(size_t)(i0 + ty + r * 8) * L_ + l0 + tx];
    __syncthreads();
    #pragma unroll
    for (int r = 0; r < 4; ++r) {
        int l = l0 + ty + r * 8;
        float v = tile[tx][ty + r * 8];                  // x[b][i0+tx][l]
        size_t off = ((size_t)b * LPAD + l + 1) * IN_DIM + i0 + tx;
        unsigned short h = f2bf(v);
        xh[off] = h;
        xl[off] = f2bf(v - bf2f(h));
    }
}

// ---------------------------------------------------------------------------
// transpose + split: src[K][N] fp32 -> dh/dl [N][K] bf16  (weight prep)
// ---------------------------------------------------------------------------
__global__ __launch_bounds__(256) void tconv_kernel(
    const float* __restrict__ src, unsigned short* __restrict__ dh,
    unsigned short* __restrict__ dl, int K, int N)
{
    __shared__ float tile[32][33];
    int k0 = blockIdx.y * 32, n0 = blockIdx.x * 32;
    int tx = threadIdx.x & 31, ty = threadIdx.x >> 5;
    #pragma unroll
    for (int r = 0; r < 4; ++r)
        tile[ty + r * 8][tx] = src[(size_t)(k0 + ty + r * 8) * N + n0 + tx];
    __syncthreads();
    #pragma unroll
    for (int r = 0; r < 4; ++r) {
        int n = n0 + ty + r * 8;
        float v = tile[tx][ty + r * 8];
        unsigned short h = f2bf(v);
        dh[(size_t)n * K + k0 + tx] = h;
        dl[(size_t)n * K + k0 + tx] = f2bf(v - bf2f(h));
    }
}

// ---------------------------------------------------------------------------
// in_proj GEMM, selective precision: tiles fully in z/xBC columns use pure
// bf16 (1 MFMA); tiles touching dt columns keep the full 3-MFMA split.
// ---------------------------------------------------------------------------
__global__ __launch_bounds__(256) void gemm_ip2_kernel(
    const unsigned short* __restrict__ Ah, const unsigned short* __restrict__ Al,
    const unsigned short* __restrict__ Bh, const unsigned short* __restrict__ Bl,
    float* __restrict__ C, int M, int N, int K)
{
    __shared__ __align__(16) unsigned short AsH[128][40];
    __shared__ __align__(16) unsigned short AsL[128][40];
    __shared__ __align__(16) unsigned short BsH[128][40];
    __shared__ __align__(16) unsigned short BsL[128][40];

    int m0 = blockIdx.y * 128, n0 = blockIdx.x * 128;
    int t = threadIdx.x;
    int wid = t >> 6, lane = t & 63;
    int wm = (wid >> 1) * 64, wn = (wid & 1) * 64;
    int fr = lane & 15, fq = lane >> 4;
    bool full = (n0 + 127 >= DT_START);

    f32x4 z4 = {0.f, 0.f, 0.f, 0.f};
    f32x4 acc[4][4];
    #pragma unroll
    for (int i = 0; i < 4; ++i)
        #pragma unroll
        for (int j = 0; j < 4; ++j) acc[i][j] = z4;

    if (!full) {
        for (int k0 = 0; k0 < K; k0 += 32) {
            __syncthreads();
            #pragma unroll
            for (int p = 0; p < 2; ++p) {
                int idx = p * 256 + t;
                int row = idx >> 2, q = idx & 3;
                int koff = k0 + q * 8;
                *(float4*)&AsH[row][q * 8] =
                    *(const float4*)(Ah + (size_t)(m0 + row) * K + koff);
                int n = n0 + row;
                *(float4*)&BsH[row][q * 8] =
                    *(const float4*)(Bh + (size_t)n * K + koff);
            }
            __syncthreads();

            short8 ah[4], bh[4];
            #pragma unroll
            for (int i = 0; i < 4; ++i) {
                ah[i] = *(const short8*)&AsH[wm + i * 16 + fr][fq * 8];
                bh[i] = *(const short8*)&BsH[wn + i * 16 + fr][fq * 8];
            }
            #pragma unroll
            for (int i = 0; i < 4; ++i)
                #pragma unroll
                for (int j = 0; j < 4; ++j)
                    acc[i][j] = __builtin_amdgcn_mfma_f32_16x16x32_bf16(
                        ah[i], bh[j], acc[i][j], 0, 0, 0);
        }
    } else {
        for (int k0 = 0; k0 < K; k0 += 32) {
            __syncthreads();
            #pragma unroll
            for (int p = 0; p < 2; ++p) {
                int idx = p * 256 + t;
                int row = idx >> 2, q = idx & 3;
                int koff = k0 + q * 8;
                *(float4*)&AsH[row][q * 8] =
                    *(const float4*)(Ah + (size_t)(m0 + row) * K + koff);
                *(float4*)&AsL[row][q * 8] =
                    *(const float4*)(Al + (size_t)(m0 + row) * K + koff);
                int n = n0 + row;
                float4 vbh = make_float4(0.f, 0.f, 0.f, 0.f), vbl = vbh;
                if (n < N) {
                    vbh = *(const float4*)(Bh + (size_t)n * K + koff);
                    vbl = *(const float4*)(Bl + (size_t)n * K + koff);
                }
                *(float4*)&BsH[row][q * 8] = vbh;
                *(float4*)&BsL[row][q * 8] = vbl;
            }
            __syncthreads();

            short8 ah[4], al[4], bh[4], bl[4];
            #pragma unroll
            for (int i = 0; i < 4; ++i) {
                ah[i] = *(const short8*)&AsH[wm + i * 16 + fr][fq * 8];
                al[i] = *(const short8*)&AsL[wm + i * 16 + fr][fq * 8];
                bh[i] = *(const short8*)&BsH[wn + i * 16 + fr][fq * 8];
                bl[i] = *(const short8*)&BsL[wn + i * 16 + fr][fq * 8];
            }
            #pragma unroll
            for (int i = 0; i < 4; ++i)
                #pragma unroll
                for (int j = 0; j < 4; ++j) {
                    acc[i][j] = __builtin_amdgcn_mfma_f32_16x16x32_bf16(
                        ah[i], bh[j], acc[i][j], 0, 0, 0);
                    acc[i][j] = __builtin_amdgcn_mfma_f32_16x16x32_bf16(
                        ah[i], bl[j], acc[i][j], 0, 0, 0);
                    acc[i][j] = __builtin_amdgcn_mfma_f32_16x16x32_bf16(
                        al[i], bh[j], acc[i][j], 0, 0, 0);
                }
        }
    }

    #pragma unroll
    for (int i = 0; i < 4; ++i) {
        int r0 = m0 + wm + i * 16 + fq * 4;
        #pragma unroll
        for (int j = 0; j < 4; ++j) {
            int cc = n0 + wn + j * 16 + fr;
            if (cc < N) {
                #pragma unroll
                for (int r = 0; r < 4; ++r)
                    C[(size_t)(r0 + r) * N + cc] = acc[i][j][r];
            }
        }
    }
}

// ---------------------------------------------------------------------------
// conv_in as GEMM: A = xT window, B = cw [256][512]. Epilogue: + conv_b,
// write split-bf16 u [8192][256].
// ---------------------------------------------------------------------------
__global__ __launch_bounds__(256) void gemm_ci_kernel(
    const unsigned short* __restrict__ Ah, const unsigned short* __restrict__ Al,
    const unsigned short* __restrict__ Bh, const unsigned short* __restrict__ Bl,
    const float* __restrict__ bias,
    unsigned short* __restrict__ Ch, unsigned short* __restrict__ Cl)
{
    const int K = 512;
    __shared__ __align__(16) unsigned short AsH[128][40];
    __shared__ __align__(16) unsigned short AsL[128][40];
    __shared__ __align__(16) unsigned short BsH[128][40];
    __shared__ __align__(16) unsigned short BsL[128][40];

    int m0 = blockIdx.y * 128, n0 = blockIdx.x * 128;
    int b = m0 >> 11;
    size_t abase = ((size_t)b * LPAD + (m0 & 2047)) * IN_DIM;
    int t = threadIdx.x;
    int wid = t >> 6, lane = t & 63;
    int wm = (wid >> 1) * 64, wn = (wid & 1) * 64;
    int fr = lane & 15, fq = lane >> 4;

    f32x4 z4 = {0.f, 0.f, 0.f, 0.f};
    f32x4 acc[4][4];
    #pragma unroll
    for (int i = 0; i < 4; ++i)
        #pragma unroll
        for (int j = 0; j < 4; ++j) acc[i][j] = z4;

    for (int k0 = 0; k0 < K; k0 += 32) {
        __syncthreads();
        #pragma unroll
        for (int p = 0; p < 2; ++p) {
            int idx = p * 256 + t;
            int row = idx >> 2, q = idx & 3;
            int koff = k0 + q * 8;
            *(float4*)&AsH[row][q * 8] =
                *(const float4*)(Ah + abase + (size_t)row * IN_DIM + koff);
            *(float4*)&AsL[row][q * 8] =
                *(const float4*)(Al + abase + (size_t)row * IN_DIM + koff);
            int n = n0 + row;
            *(float4*)&BsH[row][q * 8] = *(const float4*)(Bh + (size_t)n * K + koff);
            *(float4*)&BsL[row][q * 8] = *(const float4*)(Bl + (size_t)n * K + koff);
        }
        __syncthreads();

        short8 ah[4], al[4], bh[4], bl[4];
        #pragma unroll
        for (int i = 0; i < 4; ++i) {
            ah[i] = *(const short8*)&AsH[wm + i * 16 + fr][fq * 8];
            al[i] = *(const short8*)&AsL[wm + i * 16 + fr][fq * 8];
            bh[i] = *(const short8*)&BsH[wn + i * 16 + fr][fq * 8];
            bl[i] = *(const short8*)&BsL[wn + i * 16 + fr][fq * 8];
        }
        #pragma unroll
        for (int i = 0; i < 4; ++i)
            #pragma unroll
            for (int j = 0; j < 4; ++j) {
                acc[i][j] = __builtin_amdgcn_mfma_f32_16x16x32_bf16(
                    ah[i], bh[j], acc[i][j], 0, 0, 0);
                acc[i][j] = __builtin_amdgcn_mfma_f32_16x16x32_bf16(
                    ah[i], bl[j], acc[i][j], 0, 0, 0);
                acc[i][j] = __builtin_amdgcn_mfma_f32_16x16x32_bf16(
                    al[i], bh[j], acc[i][j], 0, 0, 0);
            }
    }

    #pragma unroll
    for (int i = 0; i < 4; ++i) {
        int r0 = m0 + wm + i * 16 + fq * 4;
        #pragma unroll
        for (int j = 0; j < 4; ++j) {
            int cc = n0 + wn + j * 16 + fr;
            float bc = bias[cc];
            #pragma unroll
            for (int r = 0; r < 4; ++r) {
                float v = acc[i][j][r] + bc;
                unsigned short h = f2bf(v);
                size_t off = (size_t)(r0 + r) * D_MODEL + cc;
                Ch[off] = h;
                Cl[off] = f2bf(v - bf2f(h));
            }
        }
    }
}

// ---------------------------------------------------------------------------
// gemm2 (mamba_out), pure bf16 (post-scan path; error budget allows).
// ---------------------------------------------------------------------------
__global__ __launch_bounds__(256) void gemm_mo_kernel(
    const unsigned short* __restrict__ Ah, const unsigned short* __restrict__ Bh,
    unsigned short* __restrict__ Ch)
{
    const int K = D_INNER;
    __shared__ __align__(16) unsigned short AsH[128][40];
    __shared__ __align__(16) unsigned short BsH[128][40];

    int m0 = blockIdx.y * 128, n0 = blockIdx.x * 128;
    int t = threadIdx.x;
    int wid = t >> 6, lane = t & 63;
    int wm = (wid >> 1) * 64, wn = (wid & 1) * 64;
    int fr = lane & 15, fq = lane >> 4;

    f32x4 z4 = {0.f, 0.f, 0.f, 0.f};
    f32x4 acc[4][4];
    #pragma unroll
    for (int i = 0; i < 4; ++i)
        #pragma unroll
        for (int j = 0; j < 4; ++j) acc[i][j] = z4;

    for (int k0 = 0; k0 < K; k0 += 32) {
        __syncthreads();
        #pragma unroll
        for (int p = 0; p < 2; ++p) {
            int idx = p * 256 + t;
            int row = idx >> 2, q = idx & 3;
            int koff = k0 + q * 8;
            *(float4*)&AsH[row][q * 8] =
                *(const float4*)(Ah + (size_t)(m0 + row) * K + koff);
            int n = n0 + row;
            *(float4*)&BsH[row][q * 8] = *(const float4*)(Bh + (size_t)n * K + koff);
        }
        __syncthreads();

        short8 ah[4], bh[4];
        #pragma unroll
        for (int i = 0; i < 4; ++i) {
            ah[i] = *(const short8*)&AsH[wm + i * 16 + fr][fq * 8];
            bh[i] = *(const short8*)&BsH[wn + i * 16 + fr][fq * 8];
        }
        #pragma unroll
        for (int i = 0; i < 4; ++i)
            #pragma unroll
            for (int j = 0; j < 4; ++j)
                acc[i][j] = __builtin_amdgcn_mfma_f32_16x16x32_bf16(
                    ah[i], bh[j], acc[i][j], 0, 0, 0);
    }

    int b = m0 >> 11;
    #pragma unroll
    for (int i = 0; i < 4; ++i) {
        int r0 = m0 + wm + i * 16 + fq * 4;
        #pragma unroll
        for (int j = 0; j < 4; ++j) {
            int cc = n0 + wn + j * 16 + fr;
            #pragma unroll
            for (int r = 0; r < 4; ++r) {
                int l = (r0 + r) & 2047;
                size_t off = ((size_t)b * LPAD + l + 1) * D_MODEL + cc;
                Ch[off] = f2bf(acc[i][j][r]);
            }
        }
    }
}

// ---------------------------------------------------------------------------
// conv_out as GEMM, pure bf16, full-K. 64 blocks.
// ---------------------------------------------------------------------------
__global__ __launch_bounds__(256) void gemm_co_kernel(
    const unsigned short* __restrict__ Ah, const unsigned short* __restrict__ Bh,
    float* __restrict__ out)
{
    const int K = 1024;
    __shared__ __align__(16) unsigned short AsH[128][40];
    __shared__ __align__(16) unsigned short BsH[128][40];

    int m0 = blockIdx.y * 128;
    int b = m0 >> 11, l0t = m0 & 2047;
    size_t abase = ((size_t)b * LPAD + l0t) * D_MODEL;
    int t = threadIdx.x;
    int wid = t >> 6, lane = t & 63;
    int wm = (wid >> 1) * 64, wn = (wid & 1) * 64;
    int fr = lane & 15, fq = lane >> 4;

    f32x4 z4 = {0.f, 0.f, 0.f, 0.f};
    f32x4 acc[4][4];
    #pragma unroll
    for (int i = 0; i < 4; ++i)
        #pragma unroll
        for (int j = 0; j < 4; ++j) acc[i][j] = z4;

    for (int k0 = 0; k0 < K; k0 += 32) {
        __syncthreads();
        #pragma unroll
        for (int p = 0; p < 2; ++p) {
            int idx = p * 256 + t;
            int row = idx >> 2, q = idx & 3;
            int koff = k0 + q * 8;
            *(float4*)&AsH[row][q * 8] =
                *(const float4*)(Ah + abase + (size_t)row * D_MODEL + koff);
            *(float4*)&BsH[row][q * 8] = *(const float4*)(Bh + (size_t)row * K + koff);
        }
        __syncthreads();

        short8 ah[4], bh[4];
        #pragma unroll
        for (int i = 0; i < 4; ++i) {
            ah[i] = *(const short8*)&AsH[wm + i * 16 + fr][fq * 8];
            bh[i] = *(const short8*)&BsH[wn + i * 16 + fr][fq * 8];
        }
        #pragma unroll
        for (int i = 0; i < 4; ++i)
            #pragma unroll
            for (int j = 0; j < 4; ++j)
                acc[i][j] = __builtin_amdgcn_mfma_f32_16x16x32_bf16(
                    ah[i], bh[j], acc[i][j], 0, 0, 0);
    }

    #pragma unroll
    for (int i = 0; i < 4; ++i) {
        int lr = l0t + wm + i * 16 + fq * 4;
        #pragma unroll
        for (int j = 0; j < 4; ++j) {
            int cc = wn + j * 16 + fr;                  // o in 0..127
            float* dst = out + ((size_t)(b * OUT_DIM + cc)) * L_ + lr;
            float4 ov = make_float4(acc[i][j][0], acc[i][j][1],
                                    acc[i][j][2], acc[i][j][3]);
            *(float4*)dst = ov;
        }
    }
}

// ---------------------------------------------------------------------------
// K4: causal depthwise conv + bias + SiLU. 8 l-values per thread.
// ---------------------------------------------------------------------------
__global__ __launch_bounds__(256) void dwconv_kernel(
    const float* __restrict__ zx, const float* __restrict__ w,
    const float* __restrict__ bias, float* __restrict__ xBCs)
{
    int idx = blockIdx.x * 256 + threadIdx.x;   // over B * L/8 * 800
    int c   = idx % CONV_DIM;
    int bl8 = idx / CONV_DIM;
    int b  = bl8 >> 8;               // L/8 = 256
    int l0 = (bl8 & 255) * 8;
    float4 wv = *(const float4*)&w[c * 4];
    float bi = bias[c];
    const float* base = zx + ((size_t)(b * L_ + l0)) * D_IN_PROJ + D_INNER + c;
    float r[11];
    #pragma unroll
    for (int k = 0; k < 11; ++k) {
        int l = l0 - 3 + k;
        r[k] = (l >= 0) ? base[(ptrdiff_t)(k - 3) * D_IN_PROJ] : 0.f;
    }
    #pragma unroll
    for (int i = 0; i < 8; ++i) {
        float acc = bi;
        acc = fmaf(r[i + 0], wv.x, acc);
        acc = fmaf(r[i + 1], wv.y, acc);
        acc = fmaf(r[i + 2], wv.z, acc);
        acc = fmaf(r[i + 3], wv.w, acc);
        float s = acc / (1.f + expf(-acc));
        xBCs[((size_t)(b * L_ + l0 + i)) * CONV_DIM + c] = s;
    }
}

// ---------------------------------------------------------------------------
// K5g: G[i][j] = C_i . B_j  per (b,chunk).  bid = b*32+c -> XCD = c%8,
// matching the scan swizzle (bc & 7) so G stays in the producing XCD's L2.
// ---------------------------------------------------------------------------
__global__ __launch_bounds__(256) void gmat_kernel(
    const float* __restrict__ xBCs, float* __restrict__ G)
{
    __shared__ float Bs[64][16];
    __shared__ float Cs[64][16];
    int c = blockIdx.x & 31, b = blockIdx.x >> 5;
    int t = threadIdx.x;
    int row0 = b * L_ + c * SCAN_CL;
    {
        int j = t >> 2, q = t & 3;
        const float* r = xBCs + (size_t)(row0 + j) * CONV_DIM + D_INNER;
        *(float4*)&Bs[j][q * 4] = *(const float4*)(r + q * 4);
        *(float4*)&Cs[j][q * 4] = *(const float4*)(r + D_STATE + q * 4);
    }
    __syncthreads();
    int i = t >> 2, jq = t & 3;
    float4 c0 = *(const float4*)&Cs[i][0];
    float4 c1 = *(const float4*)&Cs[i][4];
    float4 c2 = *(const float4*)&Cs[i][8];
    float4 c3 = *(const float4*)&Cs[i][12];
    float dot[16];
    #pragma unroll
    for (int jj = 0; jj < 16; ++jj) {
        int j = jq * 16 + jj;
        float4 b0 = *(const float4*)&Bs[j][0];
        float4 b1 = *(const float4*)&Bs[j][4];
        float4 b2 = *(const float4*)&Bs[j][8];
        float4 b3 = *(const float4*)&Bs[j][12];
        float d = c0.x * b0.x + c0.y * b0.y + c0.z * b0.z + c0.w * b0.w;
        d = fmaf(c1.x, b1.x, d); d = fmaf(c1.y, b1.y, d);
        d = fmaf(c1.z, b1.z, d); d = fmaf(c1.w, b1.w, d);
        d = fmaf(c2.x, b2.x, d); d = fmaf(c2.y, b2.y, d);
        d = fmaf(c2.z, b2.z, d); d = fmaf(c2.w, b2.w, d);
        d = fmaf(c3.x, b3.x, d); d = fmaf(c3.y, b3.y, d);
        d = fmaf(c3.z, b3.z, d); d = fmaf(c3.w, b3.w, d);
        dot[jj] = d;
    }
    float* gout = G + ((size_t)blockIdx.x * 64 + i) * 64 + jq * 16;
    #pragma unroll
    for (int q = 0; q < 4; ++q)
        *(float4*)(gout + q * 4) = make_float4(dot[q*4], dot[q*4+1], dot[q*4+2], dot[q*4+3]);
}

// ---------------------------------------------------------------------------
// XCD-locality swizzle: all 32 hg blocks of one (b,c) share bid%8 -> same XCD
// bid = (bc>>3)<<8 | hg<<3 | (bc&7);  bc = b*32+c.
// ---------------------------------------------------------------------------
__device__ __forceinline__ void scan_decode(int bid, int& b, int& c, int& hg)
{
    int bcl = bid & 7;
    hg = (bid >> 3) & 31;
    int bc = ((bid >> 8) << 3) | bcl;
    c = bc & 31;
    b = bc >> 5;
}

// ---------------------------------------------------------------------------
// K5a: chunk-local state build. 512 threads = 8 waves; ONE head per wave.
// Pk in SoA (stride 66). dt-softplus fused into staging (reads zx directly;
// bit-identical to the old dt_kernel -> dtb path).
// ---------------------------------------------------------------------------
__global__ __launch_bounds__(512) void scan_local2(
    const float* __restrict__ xBCs, const float* __restrict__ zx,
    const float* __restrict__ dt_bias, const float* __restrict__ A_log,
    float* __restrict__ Sloc, float* __restrict__ prodA)
{
    __shared__ float  BsT[16][68];          // [n][row], padded
    __shared__ float  Pk0[8][66], Pk1[8][66], Pk2[8][66], Pkw[8][66];
    __shared__ float  UT[8][3][64];
    int b, c, hg;
    scan_decode(blockIdx.x, b, c, hg);
    int h0 = hg * 8;
    int t = threadIdx.x;
    int row0 = b * L_ + c * SCAN_CL;

    if (t < 256) {   // B tile (coalesced)
        int j = t >> 2, q = t & 3;
        const float* r = xBCs + (size_t)(row0 + j) * CONV_DIM;
        float4 bv = *(const float4*)(r + D_INNER + q * 4);
        BsT[q*4+0][j] = bv.x; BsT[q*4+1][j] = bv.y;
        BsT[q*4+2][j] = bv.z; BsT[q*4+3][j] = bv.w;
    }
    {   // Pk staging: one entry per thread; fused softplus; SoA writes
        int hh = t & 7, j = t >> 3;
        float v = zx[(size_t)(row0 + j) * D_IN_PROJ + DT_START + h0 + hh]
                  + dt_bias[h0 + hh];
        float dtv = (v > 20.f) ? v : log1pf(expf(v));
        const float* xr = xBCs + (size_t)(row0 + j) * CONV_DIM + (h0 + hh) * 3;
        Pk0[hh][j] = dtv * xr[0];
        Pk1[hh][j] = dtv * xr[1];
        Pk2[hh][j] = dtv * xr[2];
        Pkw[hh][j] = dtv;
    }
    __syncthreads();

    int wv = t >> 6, lane = t & 63;
    int hh = wv;
    int h = h0 + hh;
    int p = lane >> 4, n = lane & 15;
    int pc = (p < 3) ? p : 2;

    float pkx = Pk0[hh][lane], pky = Pk1[hh][lane], pkz = Pk2[hh][lane];
    float pkw = Pkw[hh][lane];
    float A = -__expf(A_log[h]);
    float cum = pkw * A;
    #pragma unroll
    for (int off = 1; off < 64; off <<= 1) {
        float sv = __shfl_up(cum, off);
        if (lane >= off) cum += sv;
    }
    float cum63 = __shfl(cum, 63);
    float wf = __expf(cum63 - cum);
    UT[hh][0][lane] = wf * pkx;
    UT[hh][1][lane] = wf * pky;
    UT[hh][2][lane] = wf * pkz;
    float state = 0.f;
    #pragma unroll
    for (int q = 0; q < 16; ++q) {
        float4 Bv = *(const float4*)&BsT[n][q * 4];
        float4 Uv = *(const float4*)&UT[hh][pc][q * 4];
        state = fmaf(Uv.x, Bv.x, state);
        state = fmaf(Uv.y, Bv.y, state);
        state = fmaf(Uv.z, Bv.z, state);
        state = fmaf(Uv.w, Bv.w, state);
    }
    size_t bh = (size_t)(b * NHEADS + h);
    if (p < 3) Sloc[(bh * SCAN_NC + c) * 48 + p * 16 + n] = state;
    if (lane == 0) prodA[bh * SCAN_NC + c] = __expf(cum63);
}

// ---------------------------------------------------------------------------
// K5b: sequential prefix over chunks, in place on Sloc
// ---------------------------------------------------------------------------
__global__ __launch_bounds__(256) void scan_prefix_kernel(
    float* __restrict__ Sloc, const float* __restrict__ prodA)
{
    int wv   = blockIdx.x * 4 + (threadIdx.x >> 6);
    int lane = threadIdx.x & 63;
    int p = lane >> 4, n = lane & 15;
    bool act = (p < 3);
    int l48 = ((p < 3) ? p : 2) * 16 + n;
    size_t base = (size_t)wv * SCAN_NC;

    float cur = 0.f;
    for (int c = 0; c < SCAN_NC; ++c) {
        float s  = Sloc[(base + c) * 48 + l48];
        float pa = prodA[base + c];
        if (act) Sloc[(base + c) * 48 + l48] = cur;
        cur = fmaf(pa, cur, s);
    }
}

// ---------------------------------------------------------------------------
// K5c: chunk-matmul final scan. 512 threads = 8 waves; ONE head per wave.
// G staged in LDS once per block; Pk in SoA (stride 66); fused dt-softplus.
// ---------------------------------------------------------------------------
__global__ __launch_bounds__(512) void scan_final2(
    const float* __restrict__ xBCs, const float* __restrict__ zx,
    const float* __restrict__ dt_bias, const float* __restrict__ A_log,
    const float* __restrict__ Dp, const float* __restrict__ Sinit,
    const float* __restrict__ G, float* __restrict__ y)
{
    __shared__ float  Pk0[8][66], Pk1[8][66], Pk2[8][66], Pkw[8][66];
    __shared__ float4 XW[8][64];
    __shared__ float  Sin[8][48];
    __shared__ float  CsT[16][66];          // [n][row]
    __shared__ float  ysr[64][25];          // [row][24 ch] padded (stride 25)
    __shared__ float  Gs[64][65];           // G tile, odd stride
    int b, c, hg;
    scan_decode(blockIdx.x, b, c, hg);
    int h0 = hg * 8;
    int t = threadIdx.x;
    int row0 = b * L_ + c * SCAN_CL;

    if (t < 256) {   // C tile (coalesced)
        int j = t >> 2, q = t & 3;
        const float* r = xBCs + (size_t)(row0 + j) * CONV_DIM + D_INNER + D_STATE;
        float4 cv = *(const float4*)(r + q * 4);
        CsT[q*4+0][j] = cv.x; CsT[q*4+1][j] = cv.y;
        CsT[q*4+2][j] = cv.z; CsT[q*4+3][j] = cv.w;
    }
    {   // Pk staging: one entry per thread; fused softplus; SoA writes
        int hh = t & 7, j = t >> 3;
        float v = zx[(size_t)(row0 + j) * D_IN_PROJ + DT_START + h0 + hh]
                  + dt_bias[h0 + hh];
        float dtv = (v > 20.f) ? v : log1pf(expf(v));
        const float* xr = xBCs + (size_t)(row0 + j) * CONV_DIM + (h0 + hh) * 3;
        Pk0[hh][j] = dtv * xr[0];
        Pk1[hh][j] = dtv * xr[1];
        Pk2[hh][j] = dtv * xr[2];
        Pkw[hh][j] = dtv;
    }
    if (t < 384) {   // Sin staging: 8 heads x 48
        int hh = t / 48, k = t % 48;
        Sin[hh][k] = Sinit[((size_t)(b * NHEADS + h0 + hh) * SCAN_NC + c) * 48 + k];
    }
    {   // G staging: 4096 floats, coalesced float4 global reads
        const float* Gsrc = G + (size_t)(b * SCAN_NC + c) * 4096;
        #pragma unroll
        for (int e = 0; e < 2; ++e) {
            int idx = e * 512 + t;              // float4 index 0..1023
            int row = idx >> 4, cq = (idx & 15) * 4;
            float4 gv = *(const float4*)(Gsrc + (size_t)idx * 4);
            Gs[row][cq + 0] = gv.x;
            Gs[row][cq + 1] = gv.y;
            Gs[row][cq + 2] = gv.z;
            Gs[row][cq + 3] = gv.w;
        }
    }
    __syncthreads();

    int wv = t >> 6, lane = t & 63;
    int hh = wv;
    int h = h0 + hh;
    int I = lane >> 4;

    float pkx = Pk0[hh][lane], pky = Pk1[hh][lane], pkz = Pk2[hh][lane];
    float pkw = Pkw[hh][lane];
    float A = -__expf(A_log[h]);
    float cum = pkw * A;
    #pragma unroll
    for (int off = 1; off < 64; off <<= 1) {
        float sv = __shfl_up(cum, off);
        if (lane >= off) cum += sv;
    }
    float e0 = __shfl(cum, 15);
    float e1 = __shfl(cum, 31);
    float e2 = __shfl(cum, 47);
    float e3 = __shfl(cum, 63);
    int ia = (I << 4) - 1;
    float AIr = __shfl(cum, ia < 0 ? 0 : ia);
    float AI = (I == 0) ? 0.f : AIr;
    float ri = __expf(cum - AI);
    float Eo = (I == 0) ? e0 : (I == 1) ? e1 : (I == 2) ? e2 : e3;
    float wj = __expf(Eo - cum);
    XW[hh][lane] = make_float4(wj * pkx, wj * pky, wj * pkz, 0.f);
    Pkw[hh][lane] = cum;                    // publish cum_j (wave-local)
    float S0 = (I > 0) ? __expf(AI - e0) : 0.f;
    float S1 = (I > 1) ? __expf(AI - e1) : 0.f;
    float S2 = (I > 2) ? __expf(AI - e2) : 0.f;
    float ecum = __expf(cum);

    float acc0 = 0.f, acc1 = 0.f, acc2 = 0.f;
    #pragma unroll
    for (int J = 0; J < 3; ++J) {
        float SJ = (J == 0) ? S0 : (J == 1) ? S1 : S2;
        float t0 = 0.f, t1 = 0.f, t2 = 0.f;
        #pragma unroll
        for (int kk = 0; kk < 16; ++kk) {
            float gk = Gs[lane][J * 16 + kk];
            float4 u = XW[hh][J * 16 + kk];
            t0 = fmaf(gk, u.x, t0);
            t1 = fmaf(gk, u.y, t1);
            t2 = fmaf(gk, u.z, t2);
        }
        acc0 = fmaf(SJ, t0, acc0);
        acc1 = fmaf(SJ, t1, acc1);
        acc2 = fmaf(SJ, t2, acc2);
    }

    float d0 = 0.f, d1 = 0.f, d2 = 0.f;
    #pragma unroll
    for (int kk = 0; kk < 16; ++kk) {
        int j = (I << 4) + kk;
        float gk = Gs[lane][j];
        float e = __expf(cum - Pkw[hh][j]);
        float m = (j <= lane) ? e : 0.f;
        float mg = m * gk;
        d0 = fmaf(mg, Pk0[hh][j], d0);
        d1 = fmaf(mg, Pk1[hh][j], d1);
        d2 = fmaf(mg, Pk2[hh][j], d2);
    }

    float s0 = 0.f, s1 = 0.f, s2 = 0.f;
    #pragma unroll
    for (int nq = 0; nq < 16; ++nq) {
        float Cv = CsT[nq][lane];
        s0 = fmaf(Cv, Sin[hh][nq],      s0);
        s1 = fmaf(Cv, Sin[hh][16 + nq], s1);
        s2 = fmaf(Cv, Sin[hh][32 + nq], s2);
    }

    float rdt = 1.0f / pkw;
    float Dh = Dp[h];
    float* yr = &ysr[lane][hh * 3];
    yr[0] = fmaf(ri, acc0, d0) + fmaf(ecum, s0, Dh * (pkx * rdt));
    yr[1] = fmaf(ri, acc1, d1) + fmaf(ecum, s1, Dh * (pky * rdt));
    yr[2] = fmaf(ri, acc2, d2) + fmaf(ecum, s2, Dh * (pkz * rdt));
    __syncthreads();

    {   // coalesced epilogue: 24 contiguous channels per row
        int i2 = t >> 3, q2 = t & 7;
        float* dst = y + (size_t)(row0 + i2) * D_INNER + hg * 24 + q2 * 3;
        dst[0] = ysr[i2][q2 * 3 + 0];
        dst[1] = ysr[i2][q2 * 3 + 1];
        dst[2] = ysr[i2][q2 * 3 + 2];
    }
}

// ---------------------------------------------------------------------------
// K6: y = y * silu(z); RMSNorm over 768; * norm_w.  Writes plain bf16 output.
// ---------------------------------------------------------------------------
__global__ __launch_bounds__(256) void gate_norm_kernel(
    const float* __restrict__ zx, const float* __restrict__ norm_w,
    const float* __restrict__ y, unsigned short* __restrict__ yh)
{
    int bl = blockIdx.x;
    int t  = threadIdx.x;
    const float* zrow = zx + (size_t)bl * D_IN_PROJ;
    const float* yrow = y + (size_t)bl * D_INNER;

    float v[3];
    float ss = 0.f;
    #pragma unroll
    for (int j = 0; j < 3; ++j) {
        int i = t + j * 256;
        float z = zrow[i];
        float s = z / (1.f + expf(-z));
        float val = yrow[i] * s;
        v[j] = val;
        ss += val * val;
    }
    ss += __shfl_xor(ss, 32);
    ss += __shfl_xor(ss, 16);
    ss += __shfl_xor(ss, 8);
    ss += __shfl_xor(ss, 4);
    ss += __shfl_xor(ss, 2);
    ss += __shfl_xor(ss, 1);
    __shared__ float red[4];
    int lane = t & 63, wid = t >> 6;
    if (lane == 0) red[wid] = ss;
    __syncthreads();
    float tot = red[0] + red[1] + red[2] + red[3];
    float rs = rsqrtf(tot * (1.f / D_INNER) + 1e-5f);
    #pragma unroll
    for (int j = 0; j < 3; ++j) {
        int i = t + j * 256;
        float o = v[j] * rs * norm_w[i];
        yh[(size_t)bl * D_INNER + i] = f2bf(o);
    }
}

// ---------------------------------------------------------------------------
extern "C" void kernel_launch(void* const* d_in, const int* in_sizes, int n_in,
                              void* d_out, int out_size, void* d_ws, size_t ws_size,
                              hipStream_t stream)
{
    const float* x           = (const float*)d_in[0];
    const float* conv_w      = (const float*)d_in[1];
    const float* conv_b      = (const float*)d_in[2];
    const float* in_proj_w   = (const float*)d_in[3];
    const float* dw_conv_w   = (const float*)d_in[4];
    const float* dw_conv_b   = (const float*)d_in[5];
    const float* dt_bias     = (const float*)d_in[6];
    const float* A_log       = (const float*)d_in[7];
    const float* Dp          = (const float*)d_in[8];
    const float* norm_w      = (const float*)d_in[9];
    const float* mamba_out_w = (const float*)d_in[10];
    const float* out_conv_w  = (const float*)d_in[11];
    float* out = (float*)d_out;
    float* ws  = (float*)d_ws;

    // ---- workspace layout (floats) ----
    float* S0   = ws;                        //  2,097,152  Gbuf+Sloc / late: cow
    float* zx   = S0 + 2097152;              // 14,942,208  early: xT+cw / late: tmpP+mow
    float* xBCs = zx + 14942208;             //  6,553,600  early: ipw / late: yb
    float* dtb  = xBCs + 6553600;            //  2,097,152  (unused now)
    float* ybuf = dtb + 2097152;             //  6,291,456  early: prodA+u
    (void)dtb;

    float* Gbuf = S0;                        // 524,288
    float* Sloc = S0 + 524288;               // 1,572,864
    unsigned short* cow_hi = (unsigned short*)S0;              // late, 131,072 ush

    unsigned short* xT_hi = (unsigned short*)zx;
    unsigned short* xT_lo = (unsigned short*)(zx + 525056);
    unsigned short* cw_hi = (unsigned short*)(zx + 1050112);
    unsigned short* cw_lo = (unsigned short*)(zx + 1115648);
    unsigned short* tmpP_hi = (unsigned short*)zx;             // late, 2,100,224 ush
    unsigned short* mow_hi  = (unsigned short*)(zx + 2100224); // 196,608 ush
    unsigned short* mow_lo  = (unsigned short*)(zx + 2198528); // written, unused

    unsigned short* ipw_hi = (unsigned short*)xBCs;
    unsigned short* ipw_lo = (unsigned short*)(xBCs + 233472);
    unsigned short* yb_hi  = (unsigned short*)xBCs;            // after scan_final

    float* prodA = ybuf;
    unsigned short* u_hi = (unsigned short*)(ybuf + 32768);
    unsigned short* u_lo = (unsigned short*)(ybuf + 32768 + 1048576);

    // ---- 1. conv_in as GEMM ----
    prep_early_kernel<<<518, 256, 0, stream>>>(xT_hi, xT_lo, conv_w, cw_hi, cw_lo);
    transpose_x_kernel<<<dim3(L_ / 32, IN_DIM / 32, B_), 256, 0, stream>>>(
        x, xT_hi, xT_lo);
    gemm_ci_kernel<<<dim3(2, (B_ * L_) / 128), 256, 0, stream>>>(
        xT_hi, xT_lo, cw_hi, cw_lo, conv_b, u_hi, u_lo);

    // ---- 2. in_proj GEMM (selective precision: split only for dt tiles) ----
    tconv_kernel<<<dim3(D_IN_PROJ / 32, D_MODEL / 32), 256, 0, stream>>>(
        in_proj_w, ipw_hi, ipw_lo, D_MODEL, D_IN_PROJ);
    gemm_ip2_kernel<<<dim3((D_IN_PROJ + 127) / 128, (B_ * L_) / 128), 256, 0, stream>>>(
        u_hi, u_lo, ipw_hi, ipw_lo, zx, B_ * L_, D_IN_PROJ, D_MODEL);

    // ---- 3. elementwise + scan (dt-softplus fused into scan staging) ----
    dwconv_kernel<<<(B_ * (L_ / 8) * CONV_DIM) / 256, 256, 0, stream>>>(
        zx, dw_conv_w, dw_conv_b, xBCs);
    gmat_kernel<<<B_ * SCAN_NC, 256, 0, stream>>>(xBCs, Gbuf);
    scan_local2<<<B_ * SCAN_NC * (NHEADS / 8), 512, 0, stream>>>(
        xBCs, zx, dt_bias, A_log, Sloc, prodA);
    scan_prefix_kernel<<<(B_ * NHEADS) / 4, 256, 0, stream>>>(Sloc, prodA);
    scan_final2<<<B_ * SCAN_NC * (NHEADS / 8), 512, 0, stream>>>(
        xBCs, zx, dt_bias, A_log, Dp, Sloc, Gbuf, ybuf);

    // ---- 4. gate + norm (reads zx z-cols; last use of zx) -> bf16 yb ----
    gate_norm_kernel<<<B_ * L_, 256, 0, stream>>>(zx, norm_w, ybuf, yb_hi);

    // ---- 5. mamba_out GEMM (pure bf16) -> padded bf16 tmpP ----
    prep_late_kernel<<<524, 256, 0, stream>>>(out_conv_w, cow_hi, tmpP_hi);
    tconv_kernel<<<dim3(D_MODEL / 32, D_INNER / 32), 256, 0, stream>>>(
        mamba_out_w, mow_hi, mow_lo, D_INNER, D_MODEL);
    gemm_mo_kernel<<<dim3(2, (B_ * L_) / 128), 256, 0, stream>>>(
        yb_hi, mow_hi, tmpP_hi);

    // ---- 6. conv_out as full-K GEMM (pure bf16, regular stores) ----
    gemm_co_kernel<<<dim3(1, (B_ * L_) / 128), 256, 0, stream>>>(
        tmpP_hi, cow_hi, out);
}

// Round 19
// 294.879 us; speedup vs baseline: 1.3494x; 1.0095x over previous
//
#include <hip/hip_runtime.h>
#include <math.h>

#define B_      4
#define L_      2048
#define IN_DIM  128
#define D_MODEL 256
#define OUT_DIM 128
#define D_STATE 16
#define D_INNER 768
#define NHEADS  256
#define HEADDIM 3
#define CONV_DIM 800
#define D_IN_PROJ 1824
#define DT_START (D_INNER + CONV_DIM)   // 1568

#define SCAN_NC 32
#define SCAN_CL 64
#define LPAD    2051        // L_ + 3 padded rows (row0 = left pad, rows 2049/2050 = right pad)

typedef short  short8 __attribute__((ext_vector_type(8)));
typedef float  f32x4  __attribute__((ext_vector_type(4)));

__device__ __forceinline__ unsigned short f2bf(float f) {
    unsigned int u = __float_as_uint(f);
    u = (u + 0x7fffu + ((u >> 16) & 1u)) >> 16;     // RN-to-even
    return (unsigned short)u;
}
__device__ __forceinline__ float bf2f(unsigned short h) {
    return __uint_as_float(((unsigned int)h) << 16);
}

// ---------------------------------------------------------------------------
// prep_early: blocks 0..5 zero xT pads (hi+lo); blocks 6..517 reindex+split
// conv_w [256][128][4] -> cw [256][512], kk = k*128+i
// ---------------------------------------------------------------------------
__global__ __launch_bounds__(256) void prep_early_kernel(
    unsigned short* __restrict__ xh, unsigned short* __restrict__ xl,
    const float* __restrict__ cw, unsigned short* __restrict__ cwh,
    unsigned short* __restrict__ cwl)
{
    if (blockIdx.x < 6) {
        int t = blockIdx.x * 256 + threadIdx.x;
        int n = B_ * 3 * IN_DIM;
        if (t < n) {
            int ch = t % IN_DIM, rb = t / IN_DIM;
            int b = rb / 3, ri = rb % 3;
            int row = (ri == 0) ? 0 : (ri == 1) ? (L_ + 1) : (L_ + 2);
            size_t off = ((size_t)b * LPAD + row) * IN_DIM + ch;
            xh[off] = 0; xl[off] = 0;
        }
    } else {
        int t = (blockIdx.x - 6) * 256 + threadIdx.x;   // 256*512
        if (t < D_MODEL * 512) {
            int o = t >> 9, kk = t & 511;
            int k = kk >> 7, i = kk & 127;
            float v = cw[((size_t)o * IN_DIM + i) * 4 + k];
            unsigned short h = f2bf(v);
            cwh[t] = h; cwl[t] = f2bf(v - bf2f(h));
        }
    }
}

// ---------------------------------------------------------------------------
// prep_late: blocks 0..511 reindex out_conv_w -> cow bf16 [128][1024];
// blocks 512..523 zero tmpP_hi pads
// ---------------------------------------------------------------------------
__global__ __launch_bounds__(256) void prep_late_kernel(
    const float* __restrict__ cow, unsigned short* __restrict__ cowh,
    unsigned short* __restrict__ th)
{
    if (blockIdx.x < 512) {
        int t = blockIdx.x * 256 + threadIdx.x;          // 128*1024
        if (t < OUT_DIM * 1024) {
            int o = t >> 10, kk = t & 1023;
            int k = kk >> 8, c = kk & 255;
            cowh[t] = f2bf(cow[((size_t)o * D_MODEL + c) * 4 + k]);
        }
    } else {
        int t = (blockIdx.x - 512) * 256 + threadIdx.x;
        int n = B_ * 3 * D_MODEL;
        if (t < n) {
            int ch = t % D_MODEL, rb = t / D_MODEL;
            int b = rb / 3, ri = rb % 3;
            int row = (ri == 0) ? 0 : (ri == 1) ? (L_ + 1) : (L_ + 2);
            size_t off = ((size_t)b * LPAD + row) * D_MODEL + ch;
            th[off] = 0;
        }
    }
}

// ---------------------------------------------------------------------------
// transpose x [b][i][L] fp32 -> padded split-bf16 xT [b][LPAD][128], row l+1
// ---------------------------------------------------------------------------
__global__ __launch_bounds__(256) void transpose_x_kernel(
    const float* __restrict__ x, unsigned short* __restrict__ xh,
    unsigned short* __restrict__ xl)
{
    __shared__ float tile[32][33];
    int b = blockIdx.z;
    int l0 = blockIdx.x * 32, i0 = blockIdx.y * 32;
    int tx = threadIdx.x & 31, ty = threadIdx.x >> 5;   // ty 0..7
    const float* xb = x + (size_t)b * IN_DIM * L_;
    #pragma unroll
    for (int r = 0; r < 4; ++r)
        tile[ty + r * 8][tx] = xb[(size_t)(i0 + ty + r * 8) * L_ + l0 + tx];
    __syncthreads();
    #pragma unroll
    for (int r = 0; r < 4; ++r) {
        int l = l0 + ty + r * 8;
        float v = tile[tx][ty + r * 8];                  // x[b][i0+tx][l]
        size_t off = ((size_t)b * LPAD + l + 1) * IN_DIM + i0 + tx;
        unsigned short h = f2bf(v);
        xh[off] = h;
        xl[off] = f2bf(v - bf2f(h));
    }
}

// ---------------------------------------------------------------------------
// transpose + split: src[K][N] fp32 -> dh/dl [N][K] bf16  (weight prep)
// ---------------------------------------------------------------------------
__global__ __launch_bounds__(256) void tconv_kernel(
    const float* __restrict__ src, unsigned short* __restrict__ dh,
    unsigned short* __restrict__ dl, int K, int N)
{
    __shared__ float tile[32][33];
    int k0 = blockIdx.y * 32, n0 = blockIdx.x * 32;
    int tx = threadIdx.x & 31, ty = threadIdx.x >> 5;
    #pragma unroll
    for (int r = 0; r < 4; ++r)
        tile[ty + r * 8][tx] = src[(size_t)(k0 + ty + r * 8) * N + n0 + tx];
    __syncthreads();
    #pragma unroll
    for (int r = 0; r < 4; ++r) {
        int n = n0 + ty + r * 8;
        float v = tile[tx][ty + r * 8];
        unsigned short h = f2bf(v);
        dh[(size_t)n * K + k0 + tx] = h;
        dl[(size_t)n * K + k0 + tx] = f2bf(v - bf2f(h));
    }
}

// ---------------------------------------------------------------------------
// in_proj GEMM, selective precision: tiles fully in z/xBC columns use pure
// bf16 (1 MFMA); tiles touching dt columns keep the full 3-MFMA split.
// ---------------------------------------------------------------------------
__global__ __launch_bounds__(256) void gemm_ip2_kernel(
    const unsigned short* __restrict__ Ah, const unsigned short* __restrict__ Al,
    const unsigned short* __restrict__ Bh, const unsigned short* __restrict__ Bl,
    float* __restrict__ C, int M, int N, int K)
{
    __shared__ __align__(16) unsigned short AsH[128][40];
    __shared__ __align__(16) unsigned short AsL[128][40];
    __shared__ __align__(16) unsigned short BsH[128][40];
    __shared__ __align__(16) unsigned short BsL[128][40];

    int m0 = blockIdx.y * 128, n0 = blockIdx.x * 128;
    int t = threadIdx.x;
    int wid = t >> 6, lane = t & 63;
    int wm = (wid >> 1) * 64, wn = (wid & 1) * 64;
    int fr = lane & 15, fq = lane >> 4;
    bool full = (n0 + 127 >= DT_START);

    f32x4 z4 = {0.f, 0.f, 0.f, 0.f};
    f32x4 acc[4][4];
    #pragma unroll
    for (int i = 0; i < 4; ++i)
        #pragma unroll
        for (int j = 0; j < 4; ++j) acc[i][j] = z4;

    if (!full) {
        for (int k0 = 0; k0 < K; k0 += 32) {
            __syncthreads();
            #pragma unroll
            for (int p = 0; p < 2; ++p) {
                int idx = p * 256 + t;
                int row = idx >> 2, q = idx & 3;
                int koff = k0 + q * 8;
                *(float4*)&AsH[row][q * 8] =
                    *(const float4*)(Ah + (size_t)(m0 + row) * K + koff);
                int n = n0 + row;
                *(float4*)&BsH[row][q * 8] =
                    *(const float4*)(Bh + (size_t)n * K + koff);
            }
            __syncthreads();

            short8 ah[4], bh[4];
            #pragma unroll
            for (int i = 0; i < 4; ++i) {
                ah[i] = *(const short8*)&AsH[wm + i * 16 + fr][fq * 8];
                bh[i] = *(const short8*)&BsH[wn + i * 16 + fr][fq * 8];
            }
            #pragma unroll
            for (int i = 0; i < 4; ++i)
                #pragma unroll
                for (int j = 0; j < 4; ++j)
                    acc[i][j] = __builtin_amdgcn_mfma_f32_16x16x32_bf16(
                        ah[i], bh[j], acc[i][j], 0, 0, 0);
        }
    } else {
        for (int k0 = 0; k0 < K; k0 += 32) {
            __syncthreads();
            #pragma unroll
            for (int p = 0; p < 2; ++p) {
                int idx = p * 256 + t;
                int row = idx >> 2, q = idx & 3;
                int koff = k0 + q * 8;
                *(float4*)&AsH[row][q * 8] =
                    *(const float4*)(Ah + (size_t)(m0 + row) * K + koff);
                *(float4*)&AsL[row][q * 8] =
                    *(const float4*)(Al + (size_t)(m0 + row) * K + koff);
                int n = n0 + row;
                float4 vbh = make_float4(0.f, 0.f, 0.f, 0.f), vbl = vbh;
                if (n < N) {
                    vbh = *(const float4*)(Bh + (size_t)n * K + koff);
                    vbl = *(const float4*)(Bl + (size_t)n * K + koff);
                }
                *(float4*)&BsH[row][q * 8] = vbh;
                *(float4*)&BsL[row][q * 8] = vbl;
            }
            __syncthreads();

            short8 ah[4], al[4], bh[4], bl[4];
            #pragma unroll
            for (int i = 0; i < 4; ++i) {
                ah[i] = *(const short8*)&AsH[wm + i * 16 + fr][fq * 8];
                al[i] = *(const short8*)&AsL[wm + i * 16 + fr][fq * 8];
                bh[i] = *(const short8*)&BsH[wn + i * 16 + fr][fq * 8];
                bl[i] = *(const short8*)&BsL[wn + i * 16 + fr][fq * 8];
            }
            #pragma unroll
            for (int i = 0; i < 4; ++i)
                #pragma unroll
                for (int j = 0; j < 4; ++j) {
                    acc[i][j] = __builtin_amdgcn_mfma_f32_16x16x32_bf16(
                        ah[i], bh[j], acc[i][j], 0, 0, 0);
                    acc[i][j] = __builtin_amdgcn_mfma_f32_16x16x32_bf16(
                        ah[i], bl[j], acc[i][j], 0, 0, 0);
                    acc[i][j] = __builtin_amdgcn_mfma_f32_16x16x32_bf16(
                        al[i], bh[j], acc[i][j], 0, 0, 0);
                }
        }
    }

    #pragma unroll
    for (int i = 0; i < 4; ++i) {
        int r0 = m0 + wm + i * 16 + fq * 4;
        #pragma unroll
        for (int j = 0; j < 4; ++j) {
            int cc = n0 + wn + j * 16 + fr;
            if (cc < N) {
                #pragma unroll
                for (int r = 0; r < 4; ++r)
                    C[(size_t)(r0 + r) * N + cc] = acc[i][j][r];
            }
        }
    }
}

// ---------------------------------------------------------------------------
// conv_in as GEMM: A = xT window, B = cw [256][512]. Epilogue: + conv_b,
// write split-bf16 u [8192][256].
// ---------------------------------------------------------------------------
__global__ __launch_bounds__(256) void gemm_ci_kernel(
    const unsigned short* __restrict__ Ah, const unsigned short* __restrict__ Al,
    const unsigned short* __restrict__ Bh, const unsigned short* __restrict__ Bl,
    const float* __restrict__ bias,
    unsigned short* __restrict__ Ch, unsigned short* __restrict__ Cl)
{
    const int K = 512;
    __shared__ __align__(16) unsigned short AsH[128][40];
    __shared__ __align__(16) unsigned short AsL[128][40];
    __shared__ __align__(16) unsigned short BsH[128][40];
    __shared__ __align__(16) unsigned short BsL[128][40];

    int m0 = blockIdx.y * 128, n0 = blockIdx.x * 128;
    int b = m0 >> 11;
    size_t abase = ((size_t)b * LPAD + (m0 & 2047)) * IN_DIM;
    int t = threadIdx.x;
    int wid = t >> 6, lane = t & 63;
    int wm = (wid >> 1) * 64, wn = (wid & 1) * 64;
    int fr = lane & 15, fq = lane >> 4;

    f32x4 z4 = {0.f, 0.f, 0.f, 0.f};
    f32x4 acc[4][4];
    #pragma unroll
    for (int i = 0; i < 4; ++i)
        #pragma unroll
        for (int j = 0; j < 4; ++j) acc[i][j] = z4;

    for (int k0 = 0; k0 < K; k0 += 32) {
        __syncthreads();
        #pragma unroll
        for (int p = 0; p < 2; ++p) {
            int idx = p * 256 + t;
            int row = idx >> 2, q = idx & 3;
            int koff = k0 + q * 8;
            *(float4*)&AsH[row][q * 8] =
                *(const float4*)(Ah + abase + (size_t)row * IN_DIM + koff);
            *(float4*)&AsL[row][q * 8] =
                *(const float4*)(Al + abase + (size_t)row * IN_DIM + koff);
            int n = n0 + row;
            *(float4*)&BsH[row][q * 8] = *(const float4*)(Bh + (size_t)n * K + koff);
            *(float4*)&BsL[row][q * 8] = *(const float4*)(Bl + (size_t)n * K + koff);
        }
        __syncthreads();

        short8 ah[4], al[4], bh[4], bl[4];
        #pragma unroll
        for (int i = 0; i < 4; ++i) {
            ah[i] = *(const short8*)&AsH[wm + i * 16 + fr][fq * 8];
            al[i] = *(const short8*)&AsL[wm + i * 16 + fr][fq * 8];
            bh[i] = *(const short8*)&BsH[wn + i * 16 + fr][fq * 8];
            bl[i] = *(const short8*)&BsL[wn + i * 16 + fr][fq * 8];
        }
        #pragma unroll
        for (int i = 0; i < 4; ++i)
            #pragma unroll
            for (int j = 0; j < 4; ++j) {
                acc[i][j] = __builtin_amdgcn_mfma_f32_16x16x32_bf16(
                    ah[i], bh[j], acc[i][j], 0, 0, 0);
                acc[i][j] = __builtin_amdgcn_mfma_f32_16x16x32_bf16(
                    ah[i], bl[j], acc[i][j], 0, 0, 0);
                acc[i][j] = __builtin_amdgcn_mfma_f32_16x16x32_bf16(
                    al[i], bh[j], acc[i][j], 0, 0, 0);
            }
    }

    #pragma unroll
    for (int i = 0; i < 4; ++i) {
        int r0 = m0 + wm + i * 16 + fq * 4;
        #pragma unroll
        for (int j = 0; j < 4; ++j) {
            int cc = n0 + wn + j * 16 + fr;
            float bc = bias[cc];
            #pragma unroll
            for (int r = 0; r < 4; ++r) {
                float v = acc[i][j][r] + bc;
                unsigned short h = f2bf(v);
                size_t off = (size_t)(r0 + r) * D_MODEL + cc;
                Ch[off] = h;
                Cl[off] = f2bf(v - bf2f(h));
            }
        }
    }
}

// ---------------------------------------------------------------------------
// gemm2 (mamba_out), pure bf16 (post-scan path; error budget allows).
// ---------------------------------------------------------------------------
__global__ __launch_bounds__(256) void gemm_mo_kernel(
    const unsigned short* __restrict__ Ah, const unsigned short* __restrict__ Bh,
    unsigned short* __restrict__ Ch)
{
    const int K = D_INNER;
    __shared__ __align__(16) unsigned short AsH[128][40];
    __shared__ __align__(16) unsigned short BsH[128][40];

    int m0 = blockIdx.y * 128, n0 = blockIdx.x * 128;
    int t = threadIdx.x;
    int wid = t >> 6, lane = t & 63;
    int wm = (wid >> 1) * 64, wn = (wid & 1) * 64;
    int fr = lane & 15, fq = lane >> 4;

    f32x4 z4 = {0.f, 0.f, 0.f, 0.f};
    f32x4 acc[4][4];
    #pragma unroll
    for (int i = 0; i < 4; ++i)
        #pragma unroll
        for (int j = 0; j < 4; ++j) acc[i][j] = z4;

    for (int k0 = 0; k0 < K; k0 += 32) {
        __syncthreads();
        #pragma unroll
        for (int p = 0; p < 2; ++p) {
            int idx = p * 256 + t;
            int row = idx >> 2, q = idx & 3;
            int koff = k0 + q * 8;
            *(float4*)&AsH[row][q * 8] =
                *(const float4*)(Ah + (size_t)(m0 + row) * K + koff);
            int n = n0 + row;
            *(float4*)&BsH[row][q * 8] = *(const float4*)(Bh + (size_t)n * K + koff);
        }
        __syncthreads();

        short8 ah[4], bh[4];
        #pragma unroll
        for (int i = 0; i < 4; ++i) {
            ah[i] = *(const short8*)&AsH[wm + i * 16 + fr][fq * 8];
            bh[i] = *(const short8*)&BsH[wn + i * 16 + fr][fq * 8];
        }
        #pragma unroll
        for (int i = 0; i < 4; ++i)
            #pragma unroll
            for (int j = 0; j < 4; ++j)
                acc[i][j] = __builtin_amdgcn_mfma_f32_16x16x32_bf16(
                    ah[i], bh[j], acc[i][j], 0, 0, 0);
    }

    int b = m0 >> 11;
    #pragma unroll
    for (int i = 0; i < 4; ++i) {
        int r0 = m0 + wm + i * 16 + fq * 4;
        #pragma unroll
        for (int j = 0; j < 4; ++j) {
            int cc = n0 + wn + j * 16 + fr;
            #pragma unroll
            for (int r = 0; r < 4; ++r) {
                int l = (r0 + r) & 2047;
                size_t off = ((size_t)b * LPAD + l + 1) * D_MODEL + cc;
                Ch[off] = f2bf(acc[i][j][r]);
            }
        }
    }
}

// ---------------------------------------------------------------------------
// conv_out as GEMM, pure bf16, full-K. 64 blocks.
// ---------------------------------------------------------------------------
__global__ __launch_bounds__(256) void gemm_co_kernel(
    const unsigned short* __restrict__ Ah, const unsigned short* __restrict__ Bh,
    float* __restrict__ out)
{
    const int K = 1024;
    __shared__ __align__(16) unsigned short AsH[128][40];
    __shared__ __align__(16) unsigned short BsH[128][40];

    int m0 = blockIdx.y * 128;
    int b = m0 >> 11, l0t = m0 & 2047;
    size_t abase = ((size_t)b * LPAD + l0t) * D_MODEL;
    int t = threadIdx.x;
    int wid = t >> 6, lane = t & 63;
    int wm = (wid >> 1) * 64, wn = (wid & 1) * 64;
    int fr = lane & 15, fq = lane >> 4;

    f32x4 z4 = {0.f, 0.f, 0.f, 0.f};
    f32x4 acc[4][4];
    #pragma unroll
    for (int i = 0; i < 4; ++i)
        #pragma unroll
        for (int j = 0; j < 4; ++j) acc[i][j] = z4;

    for (int k0 = 0; k0 < K; k0 += 32) {
        __syncthreads();
        #pragma unroll
        for (int p = 0; p < 2; ++p) {
            int idx = p * 256 + t;
            int row = idx >> 2, q = idx & 3;
            int koff = k0 + q * 8;
            *(float4*)&AsH[row][q * 8] =
                *(const float4*)(Ah + abase + (size_t)row * D_MODEL + koff);
            *(float4*)&BsH[row][q * 8] = *(const float4*)(Bh + (size_t)row * K + koff);
        }
        __syncthreads();

        short8 ah[4], bh[4];
        #pragma unroll
        for (int i = 0; i < 4; ++i) {
            ah[i] = *(const short8*)&AsH[wm + i * 16 + fr][fq * 8];
            bh[i] = *(const short8*)&BsH[wn + i * 16 + fr][fq * 8];
        }
        #pragma unroll
        for (int i = 0; i < 4; ++i)
            #pragma unroll
            for (int j = 0; j < 4; ++j)
                acc[i][j] = __builtin_amdgcn_mfma_f32_16x16x32_bf16(
                    ah[i], bh[j], acc[i][j], 0, 0, 0);
    }

    #pragma unroll
    for (int i = 0; i < 4; ++i) {
        int lr = l0t + wm + i * 16 + fq * 4;
        #pragma unroll
        for (int j = 0; j < 4; ++j) {
            int cc = wn + j * 16 + fr;                  // o in 0..127
            float* dst = out + ((size_t)(b * OUT_DIM + cc)) * L_ + lr;
            float4 ov = make_float4(acc[i][j][0], acc[i][j][1],
                                    acc[i][j][2], acc[i][j][3]);
            *(float4*)dst = ov;
        }
    }
}

// ---------------------------------------------------------------------------
// K4: causal depthwise conv + bias + SiLU. 8 l-values per thread.
// ---------------------------------------------------------------------------
__global__ __launch_bounds__(256) void dwconv_kernel(
    const float* __restrict__ zx, const float* __restrict__ w,
    const float* __restrict__ bias, float* __restrict__ xBCs)
{
    int idx = blockIdx.x * 256 + threadIdx.x;   // over B * L/8 * 800
    int c   = idx % CONV_DIM;
    int bl8 = idx / CONV_DIM;
    int b  = bl8 >> 8;               // L/8 = 256
    int l0 = (bl8 & 255) * 8;
    float4 wv = *(const float4*)&w[c * 4];
    float bi = bias[c];
    const float* base = zx + ((size_t)(b * L_ + l0)) * D_IN_PROJ + D_INNER + c;
    float r[11];
    #pragma unroll
    for (int k = 0; k < 11; ++k) {
        int l = l0 - 3 + k;
        r[k] = (l >= 0) ? base[(ptrdiff_t)(k - 3) * D_IN_PROJ] : 0.f;
    }
    #pragma unroll
    for (int i = 0; i < 8; ++i) {
        float acc = bi;
        acc = fmaf(r[i + 0], wv.x, acc);
        acc = fmaf(r[i + 1], wv.y, acc);
        acc = fmaf(r[i + 2], wv.z, acc);
        acc = fmaf(r[i + 3], wv.w, acc);
        float s = acc / (1.f + expf(-acc));
        xBCs[((size_t)(b * L_ + l0 + i)) * CONV_DIM + c] = s;
    }
}

// ---------------------------------------------------------------------------
// K5g: G[i][j] = C_i . B_j  per (b,chunk).  bid = b*32+c -> XCD = c%8,
// matching the scan swizzle (bc & 7) so G stays in the producing XCD's L2.
// ---------------------------------------------------------------------------
__global__ __launch_bounds__(256) void gmat_kernel(
    const float* __restrict__ xBCs, float* __restrict__ G)
{
    __shared__ float Bs[64][16];
    __shared__ float Cs[64][16];
    int c = blockIdx.x & 31, b = blockIdx.x >> 5;
    int t = threadIdx.x;
    int row0 = b * L_ + c * SCAN_CL;
    {
        int j = t >> 2, q = t & 3;
        const float* r = xBCs + (size_t)(row0 + j) * CONV_DIM + D_INNER;
        *(float4*)&Bs[j][q * 4] = *(const float4*)(r + q * 4);
        *(float4*)&Cs[j][q * 4] = *(const float4*)(r + D_STATE + q * 4);
    }
    __syncthreads();
    int i = t >> 2, jq = t & 3;
    float4 c0 = *(const float4*)&Cs[i][0];
    float4 c1 = *(const float4*)&Cs[i][4];
    float4 c2 = *(const float4*)&Cs[i][8];
    float4 c3 = *(const float4*)&Cs[i][12];
    float dot[16];
    #pragma unroll
    for (int jj = 0; jj < 16; ++jj) {
        int j = jq * 16 + jj;
        float4 b0 = *(const float4*)&Bs[j][0];
        float4 b1 = *(const float4*)&Bs[j][4];
        float4 b2 = *(const float4*)&Bs[j][8];
        float4 b3 = *(const float4*)&Bs[j][12];
        float d = c0.x * b0.x + c0.y * b0.y + c0.z * b0.z + c0.w * b0.w;
        d = fmaf(c1.x, b1.x, d); d = fmaf(c1.y, b1.y, d);
        d = fmaf(c1.z, b1.z, d); d = fmaf(c1.w, b1.w, d);
        d = fmaf(c2.x, b2.x, d); d = fmaf(c2.y, b2.y, d);
        d = fmaf(c2.z, b2.z, d); d = fmaf(c2.w, b2.w, d);
        d = fmaf(c3.x, b3.x, d); d = fmaf(c3.y, b3.y, d);
        d = fmaf(c3.z, b3.z, d); d = fmaf(c3.w, b3.w, d);
        dot[jj] = d;
    }
    float* gout = G + ((size_t)blockIdx.x * 64 + i) * 64 + jq * 16;
    #pragma unroll
    for (int q = 0; q < 4; ++q)
        *(float4*)(gout + q * 4) = make_float4(dot[q*4], dot[q*4+1], dot[q*4+2], dot[q*4+3]);
}

// ---------------------------------------------------------------------------
// XCD-locality swizzle: all 32 hg blocks of one (b,c) share bid%8 -> same XCD
// bid = (bc>>3)<<8 | hg<<3 | (bc&7);  bc = b*32+c.
// ---------------------------------------------------------------------------
__device__ __forceinline__ void scan_decode(int bid, int& b, int& c, int& hg)
{
    int bcl = bid & 7;
    hg = (bid >> 3) & 31;
    int bc = ((bid >> 8) << 3) | bcl;
    c = bc & 31;
    b = bc >> 5;
}

// ---------------------------------------------------------------------------
// K5a: chunk-local state build. 512 threads = 8 waves; ONE head per wave.
// Pk in SoA (stride 66). dt-softplus fused into staging (reads zx directly);
// also spills dtv to dtb so scan_final2 can read it cheaply.
// ---------------------------------------------------------------------------
__global__ __launch_bounds__(512) void scan_local2(
    const float* __restrict__ xBCs, const float* __restrict__ zx,
    const float* __restrict__ dt_bias, const float* __restrict__ A_log,
    float* __restrict__ Sloc, float* __restrict__ prodA,
    float* __restrict__ dtb)
{
    __shared__ float  BsT[16][68];          // [n][row], padded
    __shared__ float  Pk0[8][66], Pk1[8][66], Pk2[8][66], Pkw[8][66];
    __shared__ float  UT[8][3][64];
    int b, c, hg;
    scan_decode(blockIdx.x, b, c, hg);
    int h0 = hg * 8;
    int t = threadIdx.x;
    int row0 = b * L_ + c * SCAN_CL;

    if (t < 256) {   // B tile (coalesced)
        int j = t >> 2, q = t & 3;
        const float* r = xBCs + (size_t)(row0 + j) * CONV_DIM;
        float4 bv = *(const float4*)(r + D_INNER + q * 4);
        BsT[q*4+0][j] = bv.x; BsT[q*4+1][j] = bv.y;
        BsT[q*4+2][j] = bv.z; BsT[q*4+3][j] = bv.w;
    }
    {   // Pk staging: one entry per thread; fused softplus; SoA writes
        int hh = t & 7, j = t >> 3;
        float v = zx[(size_t)(row0 + j) * D_IN_PROJ + DT_START + h0 + hh]
                  + dt_bias[h0 + hh];
        float dtv = (v > 20.f) ? v : log1pf(expf(v));
        dtb[(size_t)(row0 + j) * NHEADS + h0 + hh] = dtv;   // spill for scan_final2
        const float* xr = xBCs + (size_t)(row0 + j) * CONV_DIM + (h0 + hh) * 3;
        Pk0[hh][j] = dtv * xr[0];
        Pk1[hh][j] = dtv * xr[1];
        Pk2[hh][j] = dtv * xr[2];
        Pkw[hh][j] = dtv;
    }
    __syncthreads();

    int wv = t >> 6, lane = t & 63;
    int hh = wv;
    int h = h0 + hh;
    int p = lane >> 4, n = lane & 15;
    int pc = (p < 3) ? p : 2;

    float pkx = Pk0[hh][lane], pky = Pk1[hh][lane], pkz = Pk2[hh][lane];
    float pkw = Pkw[hh][lane];
    float A = -__expf(A_log[h]);
    float cum = pkw * A;
    #pragma unroll
    for (int off = 1; off < 64; off <<= 1) {
        float sv = __shfl_up(cum, off);
        if (lane >= off) cum += sv;
    }
    float cum63 = __shfl(cum, 63);
    float wf = __expf(cum63 - cum);
    UT[hh][0][lane] = wf * pkx;
    UT[hh][1][lane] = wf * pky;
    UT[hh][2][lane] = wf * pkz;
    float state = 0.f;
    #pragma unroll
    for (int q = 0; q < 16; ++q) {
        float4 Bv = *(const float4*)&BsT[n][q * 4];
        float4 Uv = *(const float4*)&UT[hh][pc][q * 4];
        state = fmaf(Uv.x, Bv.x, state);
        state = fmaf(Uv.y, Bv.y, state);
        state = fmaf(Uv.z, Bv.z, state);
        state = fmaf(Uv.w, Bv.w, state);
    }
    size_t bh = (size_t)(b * NHEADS + h);
    if (p < 3) Sloc[(bh * SCAN_NC + c) * 48 + p * 16 + n] = state;
    if (lane == 0) prodA[bh * SCAN_NC + c] = __expf(cum63);
}

// ---------------------------------------------------------------------------
// K5b: sequential prefix over chunks, in place on Sloc
// ---------------------------------------------------------------------------
__global__ __launch_bounds__(256) void scan_prefix_kernel(
    float* __restrict__ Sloc, const float* __restrict__ prodA)
{
    int wv   = blockIdx.x * 4 + (threadIdx.x >> 6);
    int lane = threadIdx.x & 63;
    int p = lane >> 4, n = lane & 15;
    bool act = (p < 3);
    int l48 = ((p < 3) ? p : 2) * 16 + n;
    size_t base = (size_t)wv * SCAN_NC;

    float cur = 0.f;
    for (int c = 0; c < SCAN_NC; ++c) {
        float s  = Sloc[(base + c) * 48 + l48];
        float pa = prodA[base + c];
        if (act) Sloc[(base + c) * 48 + l48] = cur;
        cur = fmaf(pa, cur, s);
    }
}

// ---------------------------------------------------------------------------
// K5c: chunk-matmul final scan. 512 threads = 8 waves; ONE head per wave.
// G staged in LDS once per block; Pk in SoA (stride 66); reads pre-computed
// dtv from dtb (written by scan_local2) -- keeps staging short.
// ---------------------------------------------------------------------------
__global__ __launch_bounds__(512) void scan_final2(
    const float* __restrict__ xBCs, const float* __restrict__ dtb,
    const float* __restrict__ A_log, const float* __restrict__ Dp,
    const float* __restrict__ Sinit, const float* __restrict__ G,
    float* __restrict__ y)
{
    __shared__ float  Pk0[8][66], Pk1[8][66], Pk2[8][66], Pkw[8][66];
    __shared__ float4 XW[8][64];
    __shared__ float  Sin[8][48];
    __shared__ float  CsT[16][66];          // [n][row]
    __shared__ float  ysr[64][25];          // [row][24 ch] padded (stride 25)
    __shared__ float  Gs[64][65];           // G tile, odd stride
    int b, c, hg;
    scan_decode(blockIdx.x, b, c, hg);
    int h0 = hg * 8;
    int t = threadIdx.x;
    int row0 = b * L_ + c * SCAN_CL;

    if (t < 256) {   // C tile (coalesced)
        int j = t >> 2, q = t & 3;
        const float* r = xBCs + (size_t)(row0 + j) * CONV_DIM + D_INNER + D_STATE;
        float4 cv = *(const float4*)(r + q * 4);
        CsT[q*4+0][j] = cv.x; CsT[q*4+1][j] = cv.y;
        CsT[q*4+2][j] = cv.z; CsT[q*4+3][j] = cv.w;
    }
    {   // Pk staging: one entry per thread; dtv from dtb; SoA writes
        int hh = t & 7, j = t >> 3;
        float dtv = dtb[(size_t)(row0 + j) * NHEADS + h0 + hh];
        const float* xr = xBCs + (size_t)(row0 + j) * CONV_DIM + (h0 + hh) * 3;
        Pk0[hh][j] = dtv * xr[0];
        Pk1[hh][j] = dtv * xr[1];
        Pk2[hh][j] = dtv * xr[2];
        Pkw[hh][j] = dtv;
    }
    if (t < 384) {   // Sin staging: 8 heads x 48
        int hh = t / 48, k = t % 48;
        Sin[hh][k] = Sinit[((size_t)(b * NHEADS + h0 + hh) * SCAN_NC + c) * 48 + k];
    }
    {   // G staging: 4096 floats, coalesced float4 global reads
        const float* Gsrc = G + (size_t)(b * SCAN_NC + c) * 4096;
        #pragma unroll
        for (int e = 0; e < 2; ++e) {
            int idx = e * 512 + t;              // float4 index 0..1023
            int row = idx >> 4, cq = (idx & 15) * 4;
            float4 gv = *(const float4*)(Gsrc + (size_t)idx * 4);
            Gs[row][cq + 0] = gv.x;
            Gs[row][cq + 1] = gv.y;
            Gs[row][cq + 2] = gv.z;
            Gs[row][cq + 3] = gv.w;
        }
    }
    __syncthreads();

    int wv = t >> 6, lane = t & 63;
    int hh = wv;
    int h = h0 + hh;
    int I = lane >> 4;

    float pkx = Pk0[hh][lane], pky = Pk1[hh][lane], pkz = Pk2[hh][lane];
    float pkw = Pkw[hh][lane];
    float A = -__expf(A_log[h]);
    float cum = pkw * A;
    #pragma unroll
    for (int off = 1; off < 64; off <<= 1) {
        float sv = __shfl_up(cum, off);
        if (lane >= off) cum += sv;
    }
    float e0 = __shfl(cum, 15);
    float e1 = __shfl(cum, 31);
    float e2 = __shfl(cum, 47);
    float e3 = __shfl(cum, 63);
    int ia = (I << 4) - 1;
    float AIr = __shfl(cum, ia < 0 ? 0 : ia);
    float AI = (I == 0) ? 0.f : AIr;
    float ri = __expf(cum - AI);
    float Eo = (I == 0) ? e0 : (I == 1) ? e1 : (I == 2) ? e2 : e3;
    float wj = __expf(Eo - cum);
    XW[hh][lane] = make_float4(wj * pkx, wj * pky, wj * pkz, 0.f);
    Pkw[hh][lane] = cum;                    // publish cum_j (wave-local)
    float S0 = (I > 0) ? __expf(AI - e0) : 0.f;
    float S1 = (I > 1) ? __expf(AI - e1) : 0.f;
    float S2 = (I > 2) ? __expf(AI - e2) : 0.f;
    float ecum = __expf(cum);

    float acc0 = 0.f, acc1 = 0.f, acc2 = 0.f;
    #pragma unroll
    for (int J = 0; J < 3; ++J) {
        float SJ = (J == 0) ? S0 : (J == 1) ? S1 : S2;
        float t0 = 0.f, t1 = 0.f, t2 = 0.f;
        #pragma unroll
        for (int kk = 0; kk < 16; ++kk) {
            float gk = Gs[lane][J * 16 + kk];
            float4 u = XW[hh][J * 16 + kk];
            t0 = fmaf(gk, u.x, t0);
            t1 = fmaf(gk, u.y, t1);
            t2 = fmaf(gk, u.z, t2);
        }
        acc0 = fmaf(SJ, t0, acc0);
        acc1 = fmaf(SJ, t1, acc1);
        acc2 = fmaf(SJ, t2, acc2);
    }

    float d0 = 0.f, d1 = 0.f, d2 = 0.f;
    #pragma unroll
    for (int kk = 0; kk < 16; ++kk) {
        int j = (I << 4) + kk;
        float gk = Gs[lane][j];
        float e = __expf(cum - Pkw[hh][j]);
        float m = (j <= lane) ? e : 0.f;
        float mg = m * gk;
        d0 = fmaf(mg, Pk0[hh][j], d0);
        d1 = fmaf(mg, Pk1[hh][j], d1);
        d2 = fmaf(mg, Pk2[hh][j], d2);
    }

    float s0 = 0.f, s1 = 0.f, s2 = 0.f;
    #pragma unroll
    for (int nq = 0; nq < 16; ++nq) {
        float Cv = CsT[nq][lane];
        s0 = fmaf(Cv, Sin[hh][nq],      s0);
        s1 = fmaf(Cv, Sin[hh][16 + nq], s1);
        s2 = fmaf(Cv, Sin[hh][32 + nq], s2);
    }

    float rdt = 1.0f / pkw;
    float Dh = Dp[h];
    float* yr = &ysr[lane][hh * 3];
    yr[0] = fmaf(ri, acc0, d0) + fmaf(ecum, s0, Dh * (pkx * rdt));
    yr[1] = fmaf(ri, acc1, d1) + fmaf(ecum, s1, Dh * (pky * rdt));
    yr[2] = fmaf(ri, acc2, d2) + fmaf(ecum, s2, Dh * (pkz * rdt));
    __syncthreads();

    {   // coalesced epilogue: 24 contiguous channels per row
        int i2 = t >> 3, q2 = t & 7;
        float* dst = y + (size_t)(row0 + i2) * D_INNER + hg * 24 + q2 * 3;
        dst[0] = ysr[i2][q2 * 3 + 0];
        dst[1] = ysr[i2][q2 * 3 + 1];
        dst[2] = ysr[i2][q2 * 3 + 2];
    }
}

// ---------------------------------------------------------------------------
// K6: y = y * silu(z); RMSNorm over 768; * norm_w.  Writes plain bf16 output.
// ---------------------------------------------------------------------------
__global__ __launch_bounds__(256) void gate_norm_kernel(
    const float* __restrict__ zx, const float* __restrict__ norm_w,
    const float* __restrict__ y, unsigned short* __restrict__ yh)
{
    int bl = blockIdx.x;
    int t  = threadIdx.x;
    const float* zrow = zx + (size_t)bl * D_IN_PROJ;
    const float* yrow = y + (size_t)bl * D_INNER;

    float v[3];
    float ss = 0.f;
    #pragma unroll
    for (int j = 0; j < 3; ++j) {
        int i = t + j * 256;
        float z = zrow[i];
        float s = z / (1.f + expf(-z));
        float val = yrow[i] * s;
        v[j] = val;
        ss += val * val;
    }
    ss += __shfl_xor(ss, 32);
    ss += __shfl_xor(ss, 16);
    ss += __shfl_xor(ss, 8);
    ss += __shfl_xor(ss, 4);
    ss += __shfl_xor(ss, 2);
    ss += __shfl_xor(ss, 1);
    __shared__ float red[4];
    int lane = t & 63, wid = t >> 6;
    if (lane == 0) red[wid] = ss;
    __syncthreads();
    float tot = red[0] + red[1] + red[2] + red[3];
    float rs = rsqrtf(tot * (1.f / D_INNER) + 1e-5f);
    #pragma unroll
    for (int j = 0; j < 3; ++j) {
        int i = t + j * 256;
        float o = v[j] * rs * norm_w[i];
        yh[(size_t)bl * D_INNER + i] = f2bf(o);
    }
}

// ---------------------------------------------------------------------------
extern "C" void kernel_launch(void* const* d_in, const int* in_sizes, int n_in,
                              void* d_out, int out_size, void* d_ws, size_t ws_size,
                              hipStream_t stream)
{
    const float* x           = (const float*)d_in[0];
    const float* conv_w      = (const float*)d_in[1];
    const float* conv_b      = (const float*)d_in[2];
    const float* in_proj_w   = (const float*)d_in[3];
    const float* dw_conv_w   = (const float*)d_in[4];
    const float* dw_conv_b   = (const float*)d_in[5];
    const float* dt_bias     = (const float*)d_in[6];
    const float* A_log       = (const float*)d_in[7];
    const float* Dp          = (const float*)d_in[8];
    const float* norm_w      = (const float*)d_in[9];
    const float* mamba_out_w = (const float*)d_in[10];
    const float* out_conv_w  = (const float*)d_in[11];
    float* out = (float*)d_out;
    float* ws  = (float*)d_ws;

    // ---- workspace layout (floats) ----
    float* S0   = ws;                        //  2,097,152  Gbuf+Sloc / late: cow
    float* zx   = S0 + 2097152;              // 14,942,208  early: xT+cw / late: tmpP+mow
    float* xBCs = zx + 14942208;             //  6,553,600  early: ipw / late: yb
    float* dtb  = xBCs + 6553600;            //  2,097,152  dtv spill (local2 -> final2)
    float* ybuf = dtb + 2097152;             //  6,291,456  early: prodA+u

    float* Gbuf = S0;                        // 524,288
    float* Sloc = S0 + 524288;               // 1,572,864
    unsigned short* cow_hi = (unsigned short*)S0;              // late, 131,072 ush

    unsigned short* xT_hi = (unsigned short*)zx;
    unsigned short* xT_lo = (unsigned short*)(zx + 525056);
    unsigned short* cw_hi = (unsigned short*)(zx + 1050112);
    unsigned short* cw_lo = (unsigned short*)(zx + 1115648);
    unsigned short* tmpP_hi = (unsigned short*)zx;             // late, 2,100,224 ush
    unsigned short* mow_hi  = (unsigned short*)(zx + 2100224); // 196,608 ush
    unsigned short* mow_lo  = (unsigned short*)(zx + 2198528); // written, unused

    unsigned short* ipw_hi = (unsigned short*)xBCs;
    unsigned short* ipw_lo = (unsigned short*)(xBCs + 233472);
    unsigned short* yb_hi  = (unsigned short*)xBCs;            // after scan_final

    float* prodA = ybuf;
    unsigned short* u_hi = (unsigned short*)(ybuf + 32768);
    unsigned short* u_lo = (unsigned short*)(ybuf + 32768 + 1048576);

    // ---- 1. conv_in as GEMM ----
    prep_early_kernel<<<518, 256, 0, stream>>>(xT_hi, xT_lo, conv_w, cw_hi, cw_lo);
    transpose_x_kernel<<<dim3(L_ / 32, IN_DIM / 32, B_), 256, 0, stream>>>(
        x, xT_hi, xT_lo);
    gemm_ci_kernel<<<dim3(2, (B_ * L_) / 128), 256, 0, stream>>>(
        xT_hi, xT_lo, cw_hi, cw_lo, conv_b, u_hi, u_lo);

    // ---- 2. in_proj GEMM (selective precision: split only for dt tiles) ----
    tconv_kernel<<<dim3(D_IN_PROJ / 32, D_MODEL / 32), 256, 0, stream>>>(
        in_proj_w, ipw_hi, ipw_lo, D_MODEL, D_IN_PROJ);
    gemm_ip2_kernel<<<dim3((D_IN_PROJ + 127) / 128, (B_ * L_) / 128), 256, 0, stream>>>(
        u_hi, u_lo, ipw_hi, ipw_lo, zx, B_ * L_, D_IN_PROJ, D_MODEL);

    // ---- 3. elementwise + scan (dt-softplus in local2, spilled to final2) ----
    dwconv_kernel<<<(B_ * (L_ / 8) * CONV_DIM) / 256, 256, 0, stream>>>(
        zx, dw_conv_w, dw_conv_b, xBCs);
    gmat_kernel<<<B_ * SCAN_NC, 256, 0, stream>>>(xBCs, Gbuf);
    scan_local2<<<B_ * SCAN_NC * (NHEADS / 8), 512, 0, stream>>>(
        xBCs, zx, dt_bias, A_log, Sloc, prodA, dtb);
    scan_prefix_kernel<<<(B_ * NHEADS) / 4, 256, 0, stream>>>(Sloc, prodA);
    scan_final2<<<B_ * SCAN_NC * (NHEADS / 8), 512, 0, stream>>>(
        xBCs, dtb, A_log, Dp, Sloc, Gbuf, ybuf);

    // ---- 4. gate + norm (reads zx z-cols; last use of zx) -> bf16 yb ----
    gate_norm_kernel<<<B_ * L_, 256, 0, stream>>>(zx, norm_w, ybuf, yb_hi);

    // ---- 5. mamba_out GEMM (pure bf16) -> padded bf16 tmpP ----
    prep_late_kernel<<<524, 256, 0, stream>>>(out_conv_w, cow_hi, tmpP_hi);
    tconv_kernel<<<dim3(D_MODEL / 32, D_INNER / 32), 256, 0, stream>>>(
        mamba_out_w, mow_hi, mow_lo, D_INNER, D_MODEL);
    gemm_mo_kernel<<<dim3(2, (B_ * L_) / 128), 256, 0, stream>>>(
        yb_hi, mow_hi, tmpP_hi);

    // ---- 6. conv_out as full-K GEMM (pure bf16, regular stores) ----
    gemm_co_kernel<<<dim3(1, (B_ * L_) / 128), 256, 0, stream>>>(
        tmpP_hi, cow_hi, out);
}